// Round 2
// baseline (18708.202 us; speedup 1.0000x reference)
//
#include <hip/hip_runtime.h>
#include <hip/hip_bf16.h>

// ---------------------------------------------------------------------------
// VQ-VAE forward, f32, workspace-frugal (fits in ~132 MB of d_ws).
//
// Fusions vs round 0:
//  - conv2+maxpool -> p1 directly (12x12), conv3+maxpool -> z directly (6x6)
//  - t4 deconv + 1x1 mu conv fused: per-block 16-channel partials reduced in
//    LDS, atomicAdd into a (256,28,28) mu buffer; separate tiny rec-loss kernel
//
// Workspace (float offsets):
//   bufA 18,874,368  : h1 (256,128,24,24) -> f1 (256,128,9,9) -> f3 (256,128,24,24)
//   bufB 13,107,200  : p1 (256,128,12,12) -> f2 (256,128,20,20)
//   z     1,179,648  : (256,128,6,6)
//   val   1,179,648  : (256,128,6,6)
//   mu      200,704  : (256,28,28)
// total 34,541,568 floats = 138,166,272 bytes
// ---------------------------------------------------------------------------

#define B_ 256

// ---------------- conv1: (B,1,28,28) -> (B,128,24,24), 5x5, pad0, ReLU ------
__global__ __launch_bounds__(256) void conv1_kernel(
    const float* __restrict__ x, const float* __restrict__ w,
    const float* __restrict__ b, float* __restrict__ out) {
  const int n = blockIdx.x;
  __shared__ float xl[784];
  __shared__ float wl[128 * 25];
  __shared__ float bl[128];
  const int t = threadIdx.x;
  for (int e = t; e < 784; e += 256) xl[e] = x[n * 784 + e];
  for (int e = t; e < 3200; e += 256) wl[e] = w[e];
  if (t < 128) bl[t] = b[t];
  __syncthreads();
  float* on = out + (size_t)n * 128 * 576;
  for (int idx = t; idx < 128 * 576; idx += 256) {
    int co = idx / 576, p = idx % 576;
    int y = p / 24, xx = p % 24;
    float acc = bl[co];
    const float* wc = &wl[co * 25];
#pragma unroll
    for (int ky = 0; ky < 5; ky++)
#pragma unroll
      for (int kx = 0; kx < 5; kx++)
        acc += xl[(y + ky) * 28 + xx + kx] * wc[ky * 5 + kx];
    on[idx] = fmaxf(acc, 0.f);
  }
}

// ---------------- generic tiled direct conv (stride 1), optional 2x2 pool ---
// DECONV: weight layout (ci,co,K,K) with spatial flip (ConvTranspose2d s=1).
// Block: 16 x OHPAD threads; thread owns one (co, out_row) = OW accumulators.
// POOL: writes (OH/2, OW/2) maxpooled output instead.
template <int IH, int IW, int OH, int OW, int K, int PAD, int CI_L, int OHPAD,
          bool DECONV, bool RELU, bool POOL>
__global__ __launch_bounds__(16 * OHPAD) void conv_tile(
    const float* __restrict__ in, const float* __restrict__ w,
    const float* __restrict__ bias, float* __restrict__ out) {
  constexpr int PH = IH + 2 * PAD, PW = IW + 2 * PAD;
  constexpr int K2 = K * K;
  constexpr int CO_L = 16;
  constexpr int BLOCK = CO_L * OHPAD;
  const int n = blockIdx.x >> 3;
  const int co0 = (blockIdx.x & 7) * CO_L;
  __shared__ __align__(16) float lin[CI_L][PH * PW];
  __shared__ float lw[CO_L][CI_L][K2];
  __shared__ float phl[POOL ? CO_L * OH * (OW / 2) : 1];
  const int t = threadIdx.x;
  const int co_l = t / OHPAD;
  const int row = t % OHPAD;
  float acc[OW];
#pragma unroll
  for (int i = 0; i < OW; i++) acc[i] = 0.f;
  const float* inN = in + (size_t)n * 128 * IH * IW;
  for (int ci0 = 0; ci0 < 128; ci0 += CI_L) {
    __syncthreads();  // previous iter's compute must finish before restage
    for (int e = t; e < CI_L * PH * PW; e += BLOCK) {
      int ci = e / (PH * PW), rem = e % (PH * PW);
      int r = rem / PW, c = rem % PW;
      int ir = r - PAD, ic = c - PAD;
      float v = 0.f;
      if (ir >= 0 && ir < IH && ic >= 0 && ic < IW)
        v = inN[(size_t)(ci0 + ci) * IH * IW + ir * IW + ic];
      lin[ci][rem] = v;
    }
    for (int e = t; e < CO_L * CI_L * K2; e += BLOCK) {
      int col = e / (CI_L * K2), rem = e % (CI_L * K2);
      int cil = rem / K2, tap = rem % K2;
      size_t g;
      if (DECONV)
        g = ((size_t)(ci0 + cil) * 128 + (co0 + col)) * K2 + (K2 - 1 - tap);
      else
        g = ((size_t)(co0 + col) * 128 + (ci0 + cil)) * K2 + tap;
      lw[col][cil][tap] = w[g];
    }
    __syncthreads();
    if (row < OH) {
      for (int ci = 0; ci < CI_L; ci++) {
#pragma unroll
        for (int ky = 0; ky < K; ky++) {
          float rrow[PW];
          const float4* src = (const float4*)&lin[ci][(row + ky) * PW];
#pragma unroll
          for (int x4 = 0; x4 < PW / 4; x4++) {
            float4 v = src[x4];
            rrow[4 * x4 + 0] = v.x;
            rrow[4 * x4 + 1] = v.y;
            rrow[4 * x4 + 2] = v.z;
            rrow[4 * x4 + 3] = v.w;
          }
#pragma unroll
          for (int kx = 0; kx < K; kx++) {
            float wv = lw[co_l][ci][ky * K + kx];
#pragma unroll
            for (int x = 0; x < OW; x++) acc[x] += rrow[x + kx] * wv;
          }
        }
      }
    }
  }
  const float bv = bias[co0 + co_l];
  if (!POOL) {
    if (row < OH) {
      float* o = out + ((size_t)n * 128 + co0 + co_l) * OH * OW + row * OW;
#pragma unroll
      for (int x = 0; x < OW; x++) {
        float v = acc[x] + bv;
        if (RELU) v = fmaxf(v, 0.f);
        o[x] = v;
      }
    }
  } else {
    if (row < OH) {
#pragma unroll
      for (int j = 0; j < OW / 2; j++) {
        float a = acc[2 * j] + bv, b2 = acc[2 * j + 1] + bv;
        if (RELU) { a = fmaxf(a, 0.f); b2 = fmaxf(b2, 0.f); }
        phl[(co_l * OH + row) * (OW / 2) + j] = fmaxf(a, b2);
      }
    }
    __syncthreads();
    if (row < OH && !(row & 1)) {
      float* o = out + ((size_t)n * 128 + co0 + co_l) * (OH / 2) * (OW / 2) +
                 (row / 2) * (OW / 2);
#pragma unroll
      for (int j = 0; j < OW / 2; j++)
        o[j] = fmaxf(phl[(co_l * OH + row) * (OW / 2) + j],
                     phl[(co_l * OH + row + 1) * (OW / 2) + j]);
    }
  }
}

// ---------------- VQ: distances, argmax(d2) [faithful], gather --------------
__global__ __launch_bounds__(256) void vq_kernel(
    const float* __restrict__ z, const float* __restrict__ dict,
    float* __restrict__ val, float* __restrict__ out_idx) {
  const int n = blockIdx.x;
  __shared__ float zl[128 * 36];
  __shared__ float d2[36 * 129];  // padded stride
  __shared__ float w2n[128];
  __shared__ int bk[36];
  const int t = threadIdx.x;
  const float* zn = z + (size_t)n * 4608;
  for (int e = t; e < 4608; e += 256) zl[e] = zn[e];
  if (t < 128) {
    float s = 0.f;
    const float* wr = dict + t * 128;
    for (int c = 0; c < 128; c++) s += wr[c] * wr[c];
    w2n[t] = s;
  }
  __syncthreads();
  const int k = t & 127, pg = t >> 7;  // 2 groups of 18 positions
  float dot[18];
#pragma unroll
  for (int i = 0; i < 18; i++) dot[i] = 0.f;
  const float* wr = dict + k * 128;
  for (int c = 0; c < 128; c++) {
    float wv = wr[c];
    const float* zr = &zl[c * 36 + pg * 18];
#pragma unroll
    for (int i = 0; i < 18; i++) dot[i] += zr[i] * wv;
  }
  float wn = w2n[k];
#pragma unroll
  for (int i = 0; i < 18; i++) d2[(pg * 18 + i) * 129 + k] = wn - 2.f * dot[i];
  __syncthreads();
  if (t < 36) {
    const float* dr = &d2[t * 129];
    float best = dr[0];
    int bi = 0;
    for (int kk = 1; kk < 128; kk++) {
      float v = dr[kk];
      if (v > best) { best = v; bi = kk; }  // strict >: first max (argmax tie)
    }
    bk[t] = bi;
    out_idx[n * 36 + t] = (float)bi;
  }
  __syncthreads();
  float* vn = val + (size_t)n * 4608;
  for (int e = t; e < 4608; e += 256) {
    int c = e / 36, p = e % 36;
    vn[e] = dict[bk[p] * 128 + c];
  }
}

// ---------------- deconv k=4 stride=2: (B,128,9,9)->(B,128,20,20), ReLU -----
__global__ __launch_bounds__(320) void deconv_s2_kernel(
    const float* __restrict__ in, const float* __restrict__ w,
    const float* __restrict__ bias, float* __restrict__ out) {
  constexpr int CI_L = 16;
  const int n = blockIdx.x >> 3;
  const int co0 = (blockIdx.x & 7) * 16;
  __shared__ __align__(16) float lin[CI_L][9 * 12];  // cols padded 9->12
  __shared__ float lw[16][CI_L][16];
  const int t = threadIdx.x;  // 320 = 16 co x 20 rows
  const int co_l = t / 20, oy = t % 20;
  float acc[20];
#pragma unroll
  for (int i = 0; i < 20; i++) acc[i] = 0.f;
  const float* inN = in + (size_t)n * 128 * 81;
  for (int ci0 = 0; ci0 < 128; ci0 += CI_L) {
    __syncthreads();
    for (int e = t; e < CI_L * 108; e += 320) {
      int ci = e / 108, rem = e % 108, r = rem / 12, c = rem % 12;
      lin[ci][rem] = (c < 9) ? inN[(size_t)(ci0 + ci) * 81 + r * 9 + c] : 0.f;
    }
    for (int e = t; e < 16 * CI_L * 16; e += 320) {
      int col = e / (CI_L * 16), rem = e % (CI_L * 16);
      int cil = rem / 16, tap = rem % 16;
      lw[col][cil][tap] = w[((size_t)(ci0 + cil) * 128 + co0 + col) * 16 + tap];
    }
    __syncthreads();
    const int par = oy & 1;
    for (int ci = 0; ci < CI_L; ci++) {
#pragma unroll
      for (int tyi = 0; tyi < 2; tyi++) {
        int ty = par + 2 * tyi;
        int iy = (oy - ty) / 2;
        if (iy >= 0 && iy < 9) {
          float r[12];
          const float4* src = (const float4*)&lin[ci][iy * 12];
#pragma unroll
          for (int x4 = 0; x4 < 3; x4++) {
            float4 v = src[x4];
            r[4 * x4 + 0] = v.x; r[4 * x4 + 1] = v.y;
            r[4 * x4 + 2] = v.z; r[4 * x4 + 3] = v.w;
          }
#pragma unroll
          for (int tx = 0; tx < 4; tx++) {
            float wv = lw[co_l][ci][ty * 4 + tx];
#pragma unroll
            for (int ox = 0; ox < 20; ox++) {
              if (((ox - tx) % 2) == 0) {
                int ix = (ox - tx) / 2;
                if (ix >= 0 && ix < 9) acc[ox] += r[ix] * wv;
              }
            }
          }
        }
      }
    }
  }
  float bv = bias[co0 + co_l];
  float* o = out + ((size_t)n * 128 + co0 + co_l) * 400 + oy * 20;
#pragma unroll
  for (int ox = 0; ox < 20; ox++) o[ox] = fmaxf(acc[ox] + bv, 0.f);
}

// ------- t4 deconv (24->28, K5, flip) fused with 1x1 mu partial sums --------
__global__ __launch_bounds__(448) void deconv_t4_mu(
    const float* __restrict__ in, const float* __restrict__ w,
    const float* __restrict__ bias, const float* __restrict__ mw,
    float* __restrict__ mu) {
  constexpr int CI_L = 4;
  constexpr int PW = 32;  // 24 + 2*4
  const int n = blockIdx.x >> 3;
  const int co0 = (blockIdx.x & 7) * 16;
  __shared__ __align__(16) float lin[CI_L][32 * 32];
  __shared__ float lw[16][CI_L][25];
  __shared__ float sbuf[8 * 784];
  const int t = threadIdx.x;  // 448 = 16 co x 28 rows
  const int co_l = t / 28, row = t % 28;
  float acc[28];
#pragma unroll
  for (int i = 0; i < 28; i++) acc[i] = 0.f;
  const float* inN = in + (size_t)n * 128 * 576;
  for (int ci0 = 0; ci0 < 128; ci0 += CI_L) {
    __syncthreads();
    for (int e = t; e < CI_L * 1024; e += 448) {
      int ci = e >> 10, rem = e & 1023;
      int r = rem >> 5, c = rem & 31;
      int ir = r - 4, ic = c - 4;
      float v = 0.f;
      if (ir >= 0 && ir < 24 && ic >= 0 && ic < 24)
        v = inN[(size_t)(ci0 + ci) * 576 + ir * 24 + ic];
      lin[ci][rem] = v;
    }
    for (int e = t; e < 16 * CI_L * 25; e += 448) {
      int col = e / (CI_L * 25), rem = e % (CI_L * 25);
      int cil = rem / 25, tap = rem % 25;
      lw[col][cil][tap] =
          w[((size_t)(ci0 + cil) * 128 + (co0 + col)) * 25 + (24 - tap)];
    }
    __syncthreads();
    for (int ci = 0; ci < CI_L; ci++) {
#pragma unroll
      for (int ky = 0; ky < 5; ky++) {
        float rrow[PW];
        const float4* src = (const float4*)&lin[ci][(row + ky) * PW];
#pragma unroll
        for (int x4 = 0; x4 < PW / 4; x4++) {
          float4 v = src[x4];
          rrow[4 * x4 + 0] = v.x;
          rrow[4 * x4 + 1] = v.y;
          rrow[4 * x4 + 2] = v.z;
          rrow[4 * x4 + 3] = v.w;
        }
#pragma unroll
        for (int kx = 0; kx < 5; kx++) {
          float wv = lw[co_l][ci][ky * 5 + kx];
#pragma unroll
          for (int x = 0; x < 28; x++) acc[x] += rrow[x + kx] * wv;
        }
      }
    }
  }
  // epilogue: relu(acc+bias) * mw[co], reduce over the 16 co's, atomic to mu
  const float bv = bias[co0 + co_l];
  const float wm = mw[co0 + co_l];
  float vm[28];
#pragma unroll
  for (int x = 0; x < 28; x++) vm[x] = fmaxf(acc[x] + bv, 0.f) * wm;
  if (co_l >= 8)
    for (int x = 0; x < 28; x++) sbuf[(co_l - 8) * 784 + row * 28 + x] = vm[x];
  __syncthreads();
  if (co_l < 8)
    for (int x = 0; x < 28; x++) sbuf[co_l * 784 + row * 28 + x] += vm[x];
  __syncthreads();
  if (co_l < 4)
    for (int x = 0; x < 28; x++)
      sbuf[co_l * 784 + row * 28 + x] += sbuf[(co_l + 4) * 784 + row * 28 + x];
  __syncthreads();
  if (co_l < 2)
    for (int x = 0; x < 28; x++)
      sbuf[co_l * 784 + row * 28 + x] += sbuf[(co_l + 2) * 784 + row * 28 + x];
  __syncthreads();
  if (co_l == 0)
    for (int x = 0; x < 28; x++)
      atomicAdd(&mu[(size_t)n * 784 + row * 28 + x],
                sbuf[row * 28 + x] + sbuf[784 + row * 28 + x]);
}

// ---------------- rec loss: mean((mu + mb - x)^2) ---------------------------
__global__ __launch_bounds__(256) void rec_loss_kernel(
    const float* __restrict__ mu, const float* __restrict__ mb,
    const float* __restrict__ x, float* __restrict__ out) {
  const int t = threadIdx.x;
  const int i = blockIdx.x * 256 + t;  // grid 784 -> 200,704 exact
  __shared__ float red[256];
  float d = mu[i] + mb[0] - x[i];
  red[t] = d * d;
  __syncthreads();
  for (int off = 128; off > 0; off >>= 1) {
    if (t < off) red[t] += red[t + off];
    __syncthreads();
  }
  if (t == 0) atomicAdd(out, red[0] * (1.0f / 200704.f));
}

// ---------------- dict / enc losses: sum (val - z)^2 ------------------------
__global__ __launch_bounds__(256) void vq_loss_kernel(
    const float4* __restrict__ val4, const float4* __restrict__ z4,
    float* __restrict__ out) {
  const int t = threadIdx.x;
  const int i = blockIdx.x * 256 + t;
  __shared__ float red[256];
  float4 a = val4[i], b = z4[i];
  float dx = a.x - b.x, dy = a.y - b.y, dz = a.z - b.z, dw = a.w - b.w;
  red[t] = dx * dx + dy * dy + dz * dz + dw * dw;
  __syncthreads();
  for (int off = 128; off > 0; off >>= 1) {
    if (t < off) red[t] += red[t + off];
    __syncthreads();
  }
  if (t == 0) {
    atomicAdd(out + 1, red[0] * (5.f / 1179648.f));
    atomicAdd(out + 2, red[0] * (1.25f / 1179648.f));
  }
}

// ---------------------------------------------------------------------------
extern "C" void kernel_launch(void* const* d_in, const int* in_sizes, int n_in,
                              void* d_out, int out_size, void* d_ws,
                              size_t ws_size, hipStream_t stream) {
  const float* x = (const float*)d_in[0];
  const float* w1 = (const float*)d_in[1];
  const float* b1 = (const float*)d_in[2];
  const float* w2 = (const float*)d_in[3];
  const float* b2 = (const float*)d_in[4];
  const float* w3 = (const float*)d_in[5];
  const float* b3 = (const float*)d_in[6];
  const float* t1w = (const float*)d_in[7];
  const float* t1b = (const float*)d_in[8];
  const float* t2w = (const float*)d_in[9];
  const float* t2b = (const float*)d_in[10];
  const float* t3w = (const float*)d_in[11];
  const float* t3b = (const float*)d_in[12];
  const float* t4w = (const float*)d_in[13];
  const float* t4b = (const float*)d_in[14];
  const float* mw = (const float*)d_in[15];
  const float* mb = (const float*)d_in[16];
  const float* dictw = (const float*)d_in[17];
  float* out = (float*)d_out;

  float* ws = (float*)d_ws;
  float* bufA = ws;                    // 18,874,368 (h1 -> f1 -> f3)
  float* bufB = bufA + 18874368;       // 13,107,200 (p1 -> f2)
  float* z = bufB + 13107200;          //  1,179,648
  float* val = z + 1179648;            //  1,179,648
  float* mu = val + 1179648;           //    200,704
  float* h1 = bufA;
  float* p1 = bufB;
  float* f1 = bufA;
  float* f2 = bufB;
  float* f3 = bufA;

  // zero the loss slots and the mu accumulator (both atomically accumulated)
  hipMemsetAsync(d_out, 0, 4 * sizeof(float), stream);
  hipMemsetAsync(mu, 0, 200704 * sizeof(float), stream);

  conv1_kernel<<<B_, 256, 0, stream>>>(x, w1, b1, h1);
  // conv2: 24x24, K5 pad2, relu, fused maxpool -> (12x12)
  conv_tile<24, 24, 24, 24, 5, 2, 8, 24, false, true, true>
      <<<B_ * 8, 384, 0, stream>>>(h1, w2, b2, p1);
  // conv3: 12x12, K5 pad2, no relu, fused maxpool -> (6x6) = z
  conv_tile<12, 12, 12, 12, 5, 2, 16, 12, false, false, true>
      <<<B_ * 8, 192, 0, stream>>>(p1, w3, b3, z);
  vq_kernel<<<B_, 256, 0, stream>>>(z, dictw, val, out + 4);
  // t1: 6->9, K4 (deconv s1), relu
  conv_tile<6, 6, 9, 9, 4, 3, 16, 12, true, true, false>
      <<<B_ * 8, 192, 0, stream>>>(val, t1w, t1b, f1);
  // t2: 9->20, K4 s2, relu
  deconv_s2_kernel<<<B_ * 8, 320, 0, stream>>>(f1, t2w, t2b, f2);
  // t3: 20->24, K5 (deconv s1), relu
  conv_tile<20, 20, 24, 24, 5, 4, 8, 24, true, true, false>
      <<<B_ * 8, 384, 0, stream>>>(f2, t3w, t3b, f3);
  // t4: 24->28, K5 (deconv s1), relu, fused with mu 1x1 conv partials
  deconv_t4_mu<<<B_ * 8, 448, 0, stream>>>(f3, t4w, t4b, mw, mu);
  rec_loss_kernel<<<784, 256, 0, stream>>>(mu, mb, x, out);
  vq_loss_kernel<<<1152, 256, 0, stream>>>((const float4*)val, (const float4*)z,
                                           out);
}

// Round 3
// 7954.393 us; speedup vs baseline: 2.3519x; 2.3519x over previous
//
#include <hip/hip_runtime.h>
#include <hip/hip_bf16.h>

// ---------------------------------------------------------------------------
// VQ-VAE forward, f32, LDS-conflict-free layout.
//
// Round-2 changes (theory: SQ_LDS_BANK_CONFLICT=5.36e9 on deconv_t4_mu):
//  - lin row stride padded to PWS with PWS/4 odd  -> rows hit disjoint banks
//  - thread map t = row*16+co_l: wave = 4 rows x 16 co -> lin reads have only
//    4 distinct addresses/wave (broadcast across co) -> conflict-free
//  - lw stride LWS == 2 (mod 4): 16 co lanes -> 16 distinct banks
//  - 2x2 pool + t4->mu channel reduction via __shfl (no LDS scratch)
//
// Workspace (float offsets):
//   bufA 18,874,368  : h1 (256,128,24,24) -> f1 (256,128,9,9) -> f3 (256,128,24,24)
//   bufB 13,107,200  : p1 (256,128,12,12) -> f2 (256,128,20,20)
//   z     1,179,648  : (256,128,6,6)
//   val   1,179,648  : (256,128,6,6)
//   mu      200,704  : (256,28,28)
// total 34,541,568 floats = 138 MB
// ---------------------------------------------------------------------------

#define B_ 256

__host__ __device__ constexpr int pad_stride(int w) {  // mult of 4, (s/4) odd
  int s = (w + 3) & ~3;
  if (((s >> 2) & 1) == 0) s += 4;
  return s;
}
__host__ __device__ constexpr int pad_lw(int n) {  // == 2 (mod 4)
  return n + ((2 - (n & 3)) & 3);
}

// ---------------- conv1: (B,1,28,28) -> (B,128,24,24), 5x5, pad0, ReLU ------
__global__ __launch_bounds__(256) void conv1_kernel(
    const float* __restrict__ x, const float* __restrict__ w,
    const float* __restrict__ b, float* __restrict__ out) {
  const int n = blockIdx.x;
  __shared__ float xl[784];
  __shared__ float wl[128 * 25];
  __shared__ float bl[128];
  const int t = threadIdx.x;
  for (int e = t; e < 784; e += 256) xl[e] = x[n * 784 + e];
  for (int e = t; e < 3200; e += 256) wl[e] = w[e];
  if (t < 128) bl[t] = b[t];
  __syncthreads();
  float* on = out + (size_t)n * 128 * 576;
  for (int idx = t; idx < 128 * 576; idx += 256) {
    int co = idx / 576, p = idx % 576;
    int y = p / 24, xx = p % 24;
    float acc = bl[co];
    const float* wc = &wl[co * 25];
#pragma unroll
    for (int ky = 0; ky < 5; ky++)
#pragma unroll
      for (int kx = 0; kx < 5; kx++)
        acc += xl[(y + ky) * 28 + xx + kx] * wc[ky * 5 + kx];
    on[idx] = fmaxf(acc, 0.f);
  }
}

// ---------------- generic tiled direct conv (stride 1), optional 2x2 pool ---
// Thread map: t = row*16 + co_l. Wave = 4 rows x 16 co.
template <int IH, int IW, int OH, int OW, int K, int PAD, int CI_L, int OHPAD,
          bool DECONV, bool RELU, bool POOL>
__global__ __launch_bounds__(16 * OHPAD) void conv_tile(
    const float* __restrict__ in, const float* __restrict__ w,
    const float* __restrict__ bias, float* __restrict__ out) {
  constexpr int PH = IH + 2 * PAD, PW = IW + 2 * PAD;
  static_assert(PW % 4 == 0, "PW must be float4-aligned");
  static_assert(!POOL || (OHPAD == OH), "pool assumes all rows valid");
  constexpr int K2 = K * K;
  constexpr int CO_L = 16;
  constexpr int BLOCK = CO_L * OHPAD;
  constexpr int PWS = pad_stride(PW);
  constexpr int LWS = pad_lw(CI_L * K2);
  const int n = blockIdx.x >> 3;
  const int co0 = (blockIdx.x & 7) * CO_L;
  __shared__ __align__(16) float lin[CI_L * PH * PWS];
  __shared__ float lw[CO_L * LWS];
  const int t = threadIdx.x;
  const int co_l = t & 15;
  const int row = t >> 4;
  float acc[OW];
#pragma unroll
  for (int i = 0; i < OW; i++) acc[i] = 0.f;
  const float* inN = in + (size_t)n * 128 * IH * IW;
  for (int ci0 = 0; ci0 < 128; ci0 += CI_L) {
    __syncthreads();  // previous iter's compute must finish before restage
    for (int e = t; e < CI_L * PH * PWS; e += BLOCK) {
      int rem = e % (PH * PWS);
      int ci = e / (PH * PWS);
      int r = rem / PWS, c = rem % PWS;
      int ir = r - PAD, ic = c - PAD;
      float v = 0.f;
      if (ir >= 0 && ir < IH && ic >= 0 && ic < IW)
        v = inN[(size_t)(ci0 + ci) * IH * IW + ir * IW + ic];
      lin[e] = v;
    }
    for (int e = t; e < CO_L * CI_L * K2; e += BLOCK) {
      int col = e / (CI_L * K2), rem = e % (CI_L * K2);
      int cil = rem / K2, tap = rem % K2;
      size_t g;
      if (DECONV)
        g = ((size_t)(ci0 + cil) * 128 + (co0 + col)) * K2 + (K2 - 1 - tap);
      else
        g = ((size_t)(co0 + col) * 128 + (ci0 + cil)) * K2 + tap;
      lw[col * LWS + rem] = w[g];
    }
    __syncthreads();
    if (row < OH) {
      const float* lwc = &lw[co_l * LWS];
      for (int ci = 0; ci < CI_L; ci++) {
#pragma unroll
        for (int ky = 0; ky < K; ky++) {
          float rrow[PW];
          const float4* src =
              (const float4*)&lin[ci * PH * PWS + (row + ky) * PWS];
#pragma unroll
          for (int x4 = 0; x4 < PW / 4; x4++) {
            float4 v = src[x4];
            rrow[4 * x4 + 0] = v.x;
            rrow[4 * x4 + 1] = v.y;
            rrow[4 * x4 + 2] = v.z;
            rrow[4 * x4 + 3] = v.w;
          }
#pragma unroll
          for (int kx = 0; kx < K; kx++) {
            float wv = lwc[ci * K2 + ky * K + kx];
#pragma unroll
            for (int x = 0; x < OW; x++) acc[x] += rrow[x + kx] * wv;
          }
        }
      }
    }
  }
  const float bv = bias[co0 + co_l];
  if (!POOL) {
    if (row < OH) {
      float* o = out + ((size_t)n * 128 + co0 + co_l) * OH * OW + row * OW;
#pragma unroll
      for (int x = 0; x < OW; x++) {
        float v = acc[x] + bv;
        if (RELU) v = fmaxf(v, 0.f);
        o[x] = v;
      }
    }
  } else {
    // horizontal pool in-register, vertical pool via shfl (row r+1 = lane+16)
    float hp[OW / 2];
#pragma unroll
    for (int j = 0; j < OW / 2; j++) {
      float a = acc[2 * j] + bv, b2 = acc[2 * j + 1] + bv;
      if (RELU) { a = fmaxf(a, 0.f); b2 = fmaxf(b2, 0.f); }
      hp[j] = fmaxf(a, b2);
    }
#pragma unroll
    for (int j = 0; j < OW / 2; j++) {
      float other = __shfl_down(hp[j], 16);
      hp[j] = fmaxf(hp[j], other);
    }
    if (!(row & 1)) {
      float* o = out + ((size_t)n * 128 + co0 + co_l) * (OH / 2) * (OW / 2) +
                 (row >> 1) * (OW / 2);
#pragma unroll
      for (int j = 0; j < OW / 2; j++) o[j] = hp[j];
    }
  }
}

// ---------------- VQ: distances, argmax(d2) [faithful], gather --------------
__global__ __launch_bounds__(256) void vq_kernel(
    const float* __restrict__ z, const float* __restrict__ dict,
    float* __restrict__ val, float* __restrict__ out_idx) {
  const int n = blockIdx.x;
  __shared__ float zl[128 * 36];
  __shared__ float d2[36 * 129];  // padded stride
  __shared__ float w2n[128];
  __shared__ int bk[36];
  const int t = threadIdx.x;
  const float* zn = z + (size_t)n * 4608;
  for (int e = t; e < 4608; e += 256) zl[e] = zn[e];
  if (t < 128) {
    float s = 0.f;
    const float* wr = dict + t * 128;
    for (int c = 0; c < 128; c++) s += wr[c] * wr[c];
    w2n[t] = s;
  }
  __syncthreads();
  const int k = t & 127, pg = t >> 7;  // 2 groups of 18 positions
  float dot[18];
#pragma unroll
  for (int i = 0; i < 18; i++) dot[i] = 0.f;
  const float* wr = dict + k * 128;
  for (int c = 0; c < 128; c++) {
    float wv = wr[c];
    const float* zr = &zl[c * 36 + pg * 18];
#pragma unroll
    for (int i = 0; i < 18; i++) dot[i] += zr[i] * wv;
  }
  float wn = w2n[k];
#pragma unroll
  for (int i = 0; i < 18; i++) d2[(pg * 18 + i) * 129 + k] = wn - 2.f * dot[i];
  __syncthreads();
  if (t < 36) {
    const float* dr = &d2[t * 129];
    float best = dr[0];
    int bi = 0;
    for (int kk = 1; kk < 128; kk++) {
      float v = dr[kk];
      if (v > best) { best = v; bi = kk; }  // strict >: first max (argmax tie)
    }
    bk[t] = bi;
    out_idx[n * 36 + t] = (float)bi;
  }
  __syncthreads();
  float* vn = val + (size_t)n * 4608;
  for (int e = t; e < 4608; e += 256) {
    int c = e / 36, p = e % 36;
    vn[e] = dict[bk[p] * 128 + c];
  }
}

// ---------------- deconv k=4 stride=2: (B,128,9,9)->(B,128,20,20), ReLU -----
__global__ __launch_bounds__(320) void deconv_s2_kernel(
    const float* __restrict__ in, const float* __restrict__ w,
    const float* __restrict__ bias, float* __restrict__ out) {
  constexpr int CI_L = 16;
  constexpr int LWS = pad_lw(16 * 16);  // 258
  const int n = blockIdx.x >> 3;
  const int co0 = (blockIdx.x & 7) * 16;
  __shared__ __align__(16) float lin[CI_L * 9 * 12];  // cols padded 9->12
  __shared__ float lw[16 * LWS];
  const int t = threadIdx.x;  // 320 = 16 co x 20 rows
  const int co_l = t / 20, oy = t % 20;
  float acc[20];
#pragma unroll
  for (int i = 0; i < 20; i++) acc[i] = 0.f;
  const float* inN = in + (size_t)n * 128 * 81;
  for (int ci0 = 0; ci0 < 128; ci0 += CI_L) {
    __syncthreads();
    for (int e = t; e < CI_L * 108; e += 320) {
      int ci = e / 108, rem = e % 108, r = rem / 12, c = rem % 12;
      lin[e] = (c < 9) ? inN[(size_t)(ci0 + ci) * 81 + r * 9 + c] : 0.f;
    }
    for (int e = t; e < 16 * CI_L * 16; e += 320) {
      int col = e / (CI_L * 16), rem = e % (CI_L * 16);
      int cil = rem / 16, tap = rem % 16;
      lw[col * LWS + rem] =
          w[((size_t)(ci0 + cil) * 128 + co0 + col) * 16 + tap];
    }
    __syncthreads();
    const int par = oy & 1;
    const float* lwc = &lw[co_l * LWS];
    for (int ci = 0; ci < CI_L; ci++) {
#pragma unroll
      for (int tyi = 0; tyi < 2; tyi++) {
        int ty = par + 2 * tyi;
        int iy = (oy - ty) / 2;
        if (iy >= 0 && iy < 9) {
          float r[12];
          const float4* src = (const float4*)&lin[ci * 108 + iy * 12];
#pragma unroll
          for (int x4 = 0; x4 < 3; x4++) {
            float4 v = src[x4];
            r[4 * x4 + 0] = v.x; r[4 * x4 + 1] = v.y;
            r[4 * x4 + 2] = v.z; r[4 * x4 + 3] = v.w;
          }
#pragma unroll
          for (int tx = 0; tx < 4; tx++) {
            float wv = lwc[ci * 16 + ty * 4 + tx];
#pragma unroll
            for (int ox = 0; ox < 20; ox++) {
              if (((ox - tx) % 2) == 0) {
                int ix = (ox - tx) / 2;
                if (ix >= 0 && ix < 9) acc[ox] += r[ix] * wv;
              }
            }
          }
        }
      }
    }
  }
  float bv = bias[co0 + co_l];
  float* o = out + ((size_t)n * 128 + co0 + co_l) * 400 + oy * 20;
#pragma unroll
  for (int ox = 0; ox < 20; ox++) o[ox] = fmaxf(acc[ox] + bv, 0.f);
}

// ------- t4 deconv (24->28, K5, flip) fused with 1x1 mu partial sums --------
// Thread map: t = row*16 + co_l (28 rows x 16 co). mu reduction via shfl.
__global__ __launch_bounds__(448) void deconv_t4_mu(
    const float* __restrict__ in, const float* __restrict__ w,
    const float* __restrict__ bias, const float* __restrict__ mw,
    float* __restrict__ mu) {
  constexpr int CI_L = 8;
  constexpr int PH = 32, PW = 32;
  constexpr int PWS = pad_stride(PW);   // 36
  constexpr int LWS = pad_lw(CI_L * 25);  // 202
  const int n = blockIdx.x >> 3;
  const int co0 = (blockIdx.x & 7) * 16;
  __shared__ __align__(16) float lin[CI_L * PH * PWS];
  __shared__ float lw[16 * LWS];
  const int t = threadIdx.x;  // 448
  const int co_l = t & 15, row = t >> 4;  // row 0..27
  float acc[28];
#pragma unroll
  for (int i = 0; i < 28; i++) acc[i] = 0.f;
  const float* inN = in + (size_t)n * 128 * 576;
  for (int ci0 = 0; ci0 < 128; ci0 += CI_L) {
    __syncthreads();
    for (int e = t; e < CI_L * PH * PWS; e += 448) {
      int rem = e % (PH * PWS);
      int ci = e / (PH * PWS);
      int r = rem / PWS, c = rem % PWS;
      int ir = r - 4, ic = c - 4;
      float v = 0.f;
      if (ir >= 0 && ir < 24 && ic >= 0 && ic < 24)
        v = inN[(size_t)(ci0 + ci) * 576 + ir * 24 + ic];
      lin[e] = v;
    }
    for (int e = t; e < 16 * CI_L * 25; e += 448) {
      int col = e / (CI_L * 25), rem = e % (CI_L * 25);
      int cil = rem / 25, tap = rem % 25;
      lw[col * LWS + rem] =
          w[((size_t)(ci0 + cil) * 128 + (co0 + col)) * 25 + (24 - tap)];
    }
    __syncthreads();
    const float* lwc = &lw[co_l * LWS];
    for (int ci = 0; ci < CI_L; ci++) {
#pragma unroll
      for (int ky = 0; ky < 5; ky++) {
        float rrow[PW];
        const float4* src = (const float4*)&lin[ci * PH * PWS + (row + ky) * PWS];
#pragma unroll
        for (int x4 = 0; x4 < PW / 4; x4++) {
          float4 v = src[x4];
          rrow[4 * x4 + 0] = v.x;
          rrow[4 * x4 + 1] = v.y;
          rrow[4 * x4 + 2] = v.z;
          rrow[4 * x4 + 3] = v.w;
        }
#pragma unroll
        for (int kx = 0; kx < 5; kx++) {
          float wv = lwc[ci * 25 + ky * 5 + kx];
#pragma unroll
          for (int x = 0; x < 28; x++) acc[x] += rrow[x + kx] * wv;
        }
      }
    }
  }
  // epilogue: relu(acc+bias)*mw[co]; shfl-reduce over the 16 co lanes; atomic
  const float bv = bias[co0 + co_l];
  const float wm = mw[co0 + co_l];
  float* mun = mu + (size_t)n * 784 + row * 28;
#pragma unroll
  for (int xx = 0; xx < 28; xx++) {
    float vm = fmaxf(acc[xx] + bv, 0.f) * wm;
    vm += __shfl_xor(vm, 1);
    vm += __shfl_xor(vm, 2);
    vm += __shfl_xor(vm, 4);
    vm += __shfl_xor(vm, 8);
    if (co_l == 0) atomicAdd(&mun[xx], vm);
  }
}

// ---------------- rec loss: mean((mu + mb - x)^2) ---------------------------
__global__ __launch_bounds__(256) void rec_loss_kernel(
    const float* __restrict__ mu, const float* __restrict__ mb,
    const float* __restrict__ x, float* __restrict__ out) {
  const int t = threadIdx.x;
  const int i = blockIdx.x * 256 + t;  // grid 784 -> 200,704 exact
  __shared__ float red[256];
  float d = mu[i] + mb[0] - x[i];
  red[t] = d * d;
  __syncthreads();
  for (int off = 128; off > 0; off >>= 1) {
    if (t < off) red[t] += red[t + off];
    __syncthreads();
  }
  if (t == 0) atomicAdd(out, red[0] * (1.0f / 200704.f));
}

// ---------------- dict / enc losses: sum (val - z)^2 ------------------------
__global__ __launch_bounds__(256) void vq_loss_kernel(
    const float4* __restrict__ val4, const float4* __restrict__ z4,
    float* __restrict__ out) {
  const int t = threadIdx.x;
  const int i = blockIdx.x * 256 + t;
  __shared__ float red[256];
  float4 a = val4[i], b = z4[i];
  float dx = a.x - b.x, dy = a.y - b.y, dz = a.z - b.z, dw = a.w - b.w;
  red[t] = dx * dx + dy * dy + dz * dz + dw * dw;
  __syncthreads();
  for (int off = 128; off > 0; off >>= 1) {
    if (t < off) red[t] += red[t + off];
    __syncthreads();
  }
  if (t == 0) {
    atomicAdd(out + 1, red[0] * (5.f / 1179648.f));
    atomicAdd(out + 2, red[0] * (1.25f / 1179648.f));
  }
}

// ---------------------------------------------------------------------------
extern "C" void kernel_launch(void* const* d_in, const int* in_sizes, int n_in,
                              void* d_out, int out_size, void* d_ws,
                              size_t ws_size, hipStream_t stream) {
  const float* x = (const float*)d_in[0];
  const float* w1 = (const float*)d_in[1];
  const float* b1 = (const float*)d_in[2];
  const float* w2 = (const float*)d_in[3];
  const float* b2 = (const float*)d_in[4];
  const float* w3 = (const float*)d_in[5];
  const float* b3 = (const float*)d_in[6];
  const float* t1w = (const float*)d_in[7];
  const float* t1b = (const float*)d_in[8];
  const float* t2w = (const float*)d_in[9];
  const float* t2b = (const float*)d_in[10];
  const float* t3w = (const float*)d_in[11];
  const float* t3b = (const float*)d_in[12];
  const float* t4w = (const float*)d_in[13];
  const float* t4b = (const float*)d_in[14];
  const float* mw = (const float*)d_in[15];
  const float* mb = (const float*)d_in[16];
  const float* dictw = (const float*)d_in[17];
  float* out = (float*)d_out;

  float* ws = (float*)d_ws;
  float* bufA = ws;                    // 18,874,368 (h1 -> f1 -> f3)
  float* bufB = bufA + 18874368;       // 13,107,200 (p1 -> f2)
  float* z = bufB + 13107200;          //  1,179,648
  float* val = z + 1179648;            //  1,179,648
  float* mu = val + 1179648;           //    200,704
  float* h1 = bufA;
  float* p1 = bufB;
  float* f1 = bufA;
  float* f2 = bufB;
  float* f3 = bufA;

  // zero the loss slots and the mu accumulator (both atomically accumulated)
  hipMemsetAsync(d_out, 0, 4 * sizeof(float), stream);
  hipMemsetAsync(mu, 0, 200704 * sizeof(float), stream);

  conv1_kernel<<<B_, 256, 0, stream>>>(x, w1, b1, h1);
  // conv2: 24x24, K5 pad2, relu, fused maxpool -> (12x12)
  conv_tile<24, 24, 24, 24, 5, 2, 8, 24, false, true, true>
      <<<B_ * 8, 384, 0, stream>>>(h1, w2, b2, p1);
  // conv3: 12x12, K5 pad2, no relu, fused maxpool -> (6x6) = z
  conv_tile<12, 12, 12, 12, 5, 2, 8, 12, false, false, true>
      <<<B_ * 8, 192, 0, stream>>>(p1, w3, b3, z);
  vq_kernel<<<B_, 256, 0, stream>>>(z, dictw, val, out + 4);
  // t1: 6->9, K4 (deconv s1), relu
  conv_tile<6, 6, 9, 9, 4, 3, 16, 12, true, true, false>
      <<<B_ * 8, 192, 0, stream>>>(val, t1w, t1b, f1);
  // t2: 9->20, K4 s2, relu
  deconv_s2_kernel<<<B_ * 8, 320, 0, stream>>>(f1, t2w, t2b, f2);
  // t3: 20->24, K5 (deconv s1), relu
  conv_tile<20, 20, 24, 24, 5, 4, 8, 24, true, true, false>
      <<<B_ * 8, 384, 0, stream>>>(f2, t3w, t3b, f3);
  // t4: 24->28, K5 (deconv s1), relu, fused with mu 1x1 conv partials
  deconv_t4_mu<<<B_ * 8, 448, 0, stream>>>(f3, t4w, t4b, mw, mu);
  rec_loss_kernel<<<784, 256, 0, stream>>>(mu, mb, x, out);
  vq_loss_kernel<<<1152, 256, 0, stream>>>((const float4*)val, (const float4*)z,
                                           out);
}

// Round 4
// 4087.477 us; speedup vs baseline: 4.5770x; 1.9460x over previous
//
#include <hip/hip_runtime.h>
#include <hip/hip_bf16.h>

// ---------------------------------------------------------------------------
// VQ-VAE forward. Encoder + VQ in f32 (index-exact); decoder t1/t3/t4 in
// bf16 MFMA implicit GEMM (losses threshold 2.26 tolerates bf16); t2 f32.
//
// MFMA design (16x16x32 bf16):
//   GEMM per image: D[co][pos] = sum_{ci,tap} W[co][ci,tap] * In[ci][pos+tap]
//   K-loop: 4 ci-blocks(32) x K^2 taps. LDS input [spatial][ci32] pitch 40
//   bf16 (16B-aligned rows, uniform 2-way banks = free). Weights pre-packed
//   [tap][co][ci] bf16 (flipped, transposed) by prep_w. Wave owns 2 co-tiles
//   x NCH pos-chunks -> A amortized, ~28 FLOP/LDS-byte.
//   t4 fuses the 1x1 mu conv: relu(acc+b)*mw, shfl over quads, atomicAdd mu.
//
// Workspace (float offsets):
//   bufA 18,874,368 : h1(256,128,24,24) -> f1(256,128,9,9) -> f3(256,128,24,24)
//   bufB 13,107,200 : p1(256,128,12,12) -> f2(256,128,20,20)
//   z  1,179,648 | val 1,179,648 | mu 200,704
//   wp1 16*16384 u16 | wp3 25*16384 u16 | wp4 25*16384 u16
// total ~140.3 MB
// ---------------------------------------------------------------------------

#define B_ 256

typedef __attribute__((ext_vector_type(8))) short s16x8;
typedef __attribute__((ext_vector_type(4))) float f32x4;

__device__ inline ushort f2bf(float f) {
  union { __hip_bfloat16 h; ushort u; } cv;
  cv.h = __float2bfloat16(f);
  return cv.u;
}

__host__ __device__ constexpr int pad_stride(int w) {  // mult of 4, (s/4) odd
  int s = (w + 3) & ~3;
  if (((s >> 2) & 1) == 0) s += 4;
  return s;
}
__host__ __device__ constexpr int pad_lw(int n) {  // == 2 (mod 4)
  return n + ((2 - (n & 3)) & 3);
}

// ---------------- weight prep: (ci,co,K,K) f32 -> [tap][co][ci] bf16 flipped
__global__ __launch_bounds__(256) void prep_w(const float* __restrict__ w,
                                              ushort* __restrict__ wp,
                                              int K2) {
  int idx = blockIdx.x * 256 + threadIdx.x;
  if (idx >= K2 * 16384) return;
  int ci = idx & 127;
  int co = (idx >> 7) & 127;
  int tap = idx >> 14;
  wp[idx] = f2bf(w[((size_t)ci * 128 + co) * K2 + (K2 - 1 - tap)]);
}

// ---------------- conv1: (B,1,28,28) -> (B,128,24,24), 5x5, pad0, ReLU ------
__global__ __launch_bounds__(256) void conv1_kernel(
    const float* __restrict__ x, const float* __restrict__ w,
    const float* __restrict__ b, float* __restrict__ out) {
  const int n = blockIdx.x;
  __shared__ float xl[784];
  __shared__ float wl[128 * 25];
  __shared__ float bl[128];
  const int t = threadIdx.x;
  for (int e = t; e < 784; e += 256) xl[e] = x[n * 784 + e];
  for (int e = t; e < 3200; e += 256) wl[e] = w[e];
  if (t < 128) bl[t] = b[t];
  __syncthreads();
  float* on = out + (size_t)n * 128 * 576;
  for (int idx = t; idx < 128 * 576; idx += 256) {
    int co = idx / 576, p = idx % 576;
    int y = p / 24, xx = p % 24;
    float acc = bl[co];
    const float* wc = &wl[co * 25];
#pragma unroll
    for (int ky = 0; ky < 5; ky++)
#pragma unroll
      for (int kx = 0; kx < 5; kx++)
        acc += xl[(y + ky) * 28 + xx + kx] * wc[ky * 5 + kx];
    on[idx] = fmaxf(acc, 0.f);
  }
}

// ---------------- f32 tiled direct conv (encoder), optional 2x2 pool --------
template <int IH, int IW, int OH, int OW, int K, int PAD, int CI_L, int OHPAD,
          bool DECONV, bool RELU, bool POOL>
__global__ __launch_bounds__(16 * OHPAD) void conv_tile(
    const float* __restrict__ in, const float* __restrict__ w,
    const float* __restrict__ bias, float* __restrict__ out) {
  constexpr int PH = IH + 2 * PAD, PW = IW + 2 * PAD;
  static_assert(PW % 4 == 0, "PW must be float4-aligned");
  static_assert(!POOL || (OHPAD == OH), "pool assumes all rows valid");
  constexpr int K2 = K * K;
  constexpr int CO_L = 16;
  constexpr int BLOCK = CO_L * OHPAD;
  constexpr int PWS = pad_stride(PW);
  constexpr int LWS = pad_lw(CI_L * K2);
  const int n = blockIdx.x >> 3;
  const int co0 = (blockIdx.x & 7) * CO_L;
  __shared__ __align__(16) float lin[CI_L * PH * PWS];
  __shared__ float lw[CO_L * LWS];
  const int t = threadIdx.x;
  const int co_l = t & 15;
  const int row = t >> 4;
  float acc[OW];
#pragma unroll
  for (int i = 0; i < OW; i++) acc[i] = 0.f;
  const float* inN = in + (size_t)n * 128 * IH * IW;
  for (int ci0 = 0; ci0 < 128; ci0 += CI_L) {
    __syncthreads();
    for (int e = t; e < CI_L * PH * PWS; e += BLOCK) {
      int rem = e % (PH * PWS);
      int ci = e / (PH * PWS);
      int r = rem / PWS, c = rem % PWS;
      int ir = r - PAD, ic = c - PAD;
      float v = 0.f;
      if (ir >= 0 && ir < IH && ic >= 0 && ic < IW)
        v = inN[(size_t)(ci0 + ci) * IH * IW + ir * IW + ic];
      lin[e] = v;
    }
    for (int e = t; e < CO_L * CI_L * K2; e += BLOCK) {
      int col = e / (CI_L * K2), rem = e % (CI_L * K2);
      int cil = rem / K2, tap = rem % K2;
      size_t g;
      if (DECONV)
        g = ((size_t)(ci0 + cil) * 128 + (co0 + col)) * K2 + (K2 - 1 - tap);
      else
        g = ((size_t)(co0 + col) * 128 + (ci0 + cil)) * K2 + tap;
      lw[col * LWS + rem] = w[g];
    }
    __syncthreads();
    if (row < OH) {
      const float* lwc = &lw[co_l * LWS];
      for (int ci = 0; ci < CI_L; ci++) {
#pragma unroll
        for (int ky = 0; ky < K; ky++) {
          float rrow[PW];
          const float4* src =
              (const float4*)&lin[ci * PH * PWS + (row + ky) * PWS];
#pragma unroll
          for (int x4 = 0; x4 < PW / 4; x4++) {
            float4 v = src[x4];
            rrow[4 * x4 + 0] = v.x;
            rrow[4 * x4 + 1] = v.y;
            rrow[4 * x4 + 2] = v.z;
            rrow[4 * x4 + 3] = v.w;
          }
#pragma unroll
          for (int kx = 0; kx < K; kx++) {
            float wv = lwc[ci * K2 + ky * K + kx];
#pragma unroll
            for (int x = 0; x < OW; x++) acc[x] += rrow[x + kx] * wv;
          }
        }
      }
    }
  }
  const float bv = bias[co0 + co_l];
  if (!POOL) {
    if (row < OH) {
      float* o = out + ((size_t)n * 128 + co0 + co_l) * OH * OW + row * OW;
#pragma unroll
      for (int x = 0; x < OW; x++) {
        float v = acc[x] + bv;
        if (RELU) v = fmaxf(v, 0.f);
        o[x] = v;
      }
    }
  } else {
    float hp[OW / 2];
#pragma unroll
    for (int j = 0; j < OW / 2; j++) {
      float a = acc[2 * j] + bv, b2 = acc[2 * j + 1] + bv;
      if (RELU) { a = fmaxf(a, 0.f); b2 = fmaxf(b2, 0.f); }
      hp[j] = fmaxf(a, b2);
    }
#pragma unroll
    for (int j = 0; j < OW / 2; j++) {
      float other = __shfl_down(hp[j], 16);
      hp[j] = fmaxf(hp[j], other);
    }
    if (!(row & 1)) {
      float* o = out + ((size_t)n * 128 + co0 + co_l) * (OH / 2) * (OW / 2) +
                 (row >> 1) * (OW / 2);
#pragma unroll
      for (int j = 0; j < OW / 2; j++) o[j] = hp[j];
    }
  }
}

// ---------------- VQ: distances, argmax(d2) [faithful], gather --------------
__global__ __launch_bounds__(256) void vq_kernel(
    const float* __restrict__ z, const float* __restrict__ dict,
    float* __restrict__ val, float* __restrict__ out_idx) {
  const int n = blockIdx.x;
  __shared__ float zl[128 * 36];
  __shared__ float d2[36 * 129];
  __shared__ float w2n[128];
  __shared__ int bk[36];
  const int t = threadIdx.x;
  const float* zn = z + (size_t)n * 4608;
  for (int e = t; e < 4608; e += 256) zl[e] = zn[e];
  if (t < 128) {
    float s = 0.f;
    const float* wr = dict + t * 128;
    for (int c = 0; c < 128; c++) s += wr[c] * wr[c];
    w2n[t] = s;
  }
  __syncthreads();
  const int k = t & 127, pg = t >> 7;
  float dot[18];
#pragma unroll
  for (int i = 0; i < 18; i++) dot[i] = 0.f;
  const float* wr = dict + k * 128;
  for (int c = 0; c < 128; c++) {
    float wv = wr[c];
    const float* zr = &zl[c * 36 + pg * 18];
#pragma unroll
    for (int i = 0; i < 18; i++) dot[i] += zr[i] * wv;
  }
  float wn = w2n[k];
#pragma unroll
  for (int i = 0; i < 18; i++) d2[(pg * 18 + i) * 129 + k] = wn - 2.f * dot[i];
  __syncthreads();
  if (t < 36) {
    const float* dr = &d2[t * 129];
    float best = dr[0];
    int bi = 0;
    for (int kk = 1; kk < 128; kk++) {
      float v = dr[kk];
      if (v > best) { best = v; bi = kk; }  // strict >: first max (argmax tie)
    }
    bk[t] = bi;
    out_idx[n * 36 + t] = (float)bi;
  }
  __syncthreads();
  float* vn = val + (size_t)n * 4608;
  for (int e = t; e < 4608; e += 256) {
    int c = e / 36, p = e % 36;
    vn[e] = dict[bk[p] * 128 + c];
  }
}

// ---------------- bf16 MFMA deconv (stride 1), optional fused mu ------------
// Wave w owns co-tiles {w, w+4}; block = 4 waves, one (image, row-tile).
template <int IH, int IW, int OH, int OW, int K, int TR, bool MU_FUSE>
__global__ __launch_bounds__(256) void deconv_mfma(
    const float* __restrict__ in, const ushort* __restrict__ wprep,
    const float* __restrict__ bias, const float* __restrict__ mw,
    float* __restrict__ out) {
  constexpr int PAD = K - 1;
  constexpr int PW = IW + 2 * PAD;
  constexpr int K2 = K * K;
  constexpr int SROWS = TR + K - 1;
  constexpr int S = SROWS * PW;
  constexpr int NPOS = TR * OW;
  constexpr int NCH = (NPOS + 15) / 16;
  constexpr int PITCH = 40;  // bf16 units: 80B rows (16B-aligned, 2-way banks)
  const int n = blockIdx.x;
  const int r0 = blockIdx.y * TR;
  __shared__ __align__(16) ushort lin[S * PITCH];
  __shared__ __align__(16) ushort lw[2][128 * PITCH];
  const int t = threadIdx.x;
  const int wv = t >> 6;
  const int lane = t & 63;
  const int nn = lane & 15;  // MFMA col = pos within chunk
  const int q = lane >> 4;   // quad
  f32x4 acc0[NCH], acc1[NCH];
  int base[NCH];
#pragma unroll
  for (int c = 0; c < NCH; c++) {
    acc0[c] = f32x4{0.f, 0.f, 0.f, 0.f};
    acc1[c] = f32x4{0.f, 0.f, 0.f, 0.f};
    int p = c * 16 + nn;
    int pc = p < NPOS ? p : NPOS - 1;  // clamp dead lanes (reads only)
    base[c] = (pc / OW) * PW + (pc % OW);
  }
  const float* inN = in + (size_t)n * 128 * IH * IW;
  for (int cb = 0; cb < 4; cb++) {
    const int ci0 = cb * 32;
    __syncthreads();
    // stage input ci-block: [spatial][ci32] bf16
    for (int e = t; e < 32 * S; e += 256) {
      int ci = e / S, sp = e - ci * S;
      int rr = sp / PW, cc = sp - rr * PW;
      int ir = r0 + rr - PAD, ic = cc - PAD;
      float v = 0.f;
      if (ir >= 0 && ir < IH && ic >= 0 && ic < IW)
        v = inN[(size_t)(ci0 + ci) * (IH * IW) + ir * IW + ic];
      lin[sp * PITCH + ci] = f2bf(v);
    }
    // stage weights tap 0
    {
      const ushort* wp = wprep + ci0;
      for (int e = t; e < 4096; e += 256) {
        int co = e >> 5, ci = e & 31;
        lw[0][co * PITCH + ci] = wp[co * 128 + ci];
      }
    }
    __syncthreads();
    for (int tap = 0; tap < K2; tap++) {
      if (tap + 1 < K2) {  // double-buffered weight prefetch
        const ushort* wp = wprep + (size_t)(tap + 1) * 16384 + ci0;
        ushort* dst = lw[(tap + 1) & 1];
        for (int e = t; e < 4096; e += 256) {
          int co = e >> 5, ci = e & 31;
          dst[co * PITCH + ci] = wp[co * 128 + ci];
        }
      }
      const int ky = tap / K, kx = tap - ky * K;
      const int toff = ky * PW + kx;
      const ushort* lwc = lw[tap & 1];
      s16x8 a0 = *(const s16x8*)&lwc[(wv * 16 + nn) * PITCH + q * 8];
      s16x8 a1 = *(const s16x8*)&lwc[((wv + 4) * 16 + nn) * PITCH + q * 8];
#pragma unroll
      for (int c = 0; c < NCH; c++) {
        s16x8 b = *(const s16x8*)&lin[(base[c] + toff) * PITCH + q * 8];
        acc0[c] =
            __builtin_amdgcn_mfma_f32_16x16x32_bf16(a0, b, acc0[c], 0, 0, 0);
        acc1[c] =
            __builtin_amdgcn_mfma_f32_16x16x32_bf16(a1, b, acc1[c], 0, 0, 0);
      }
      __syncthreads();
    }
  }
  // epilogue: D row = quad*4+reg (co), col = nn (pos)
  const int co_a = wv * 16 + q * 4;
  const int co_b = (wv + 4) * 16 + q * 4;
  float ba[4], bb[4];
#pragma unroll
  for (int r = 0; r < 4; r++) {
    ba[r] = bias[co_a + r];
    bb[r] = bias[co_b + r];
  }
  if (!MU_FUSE) {
#pragma unroll
    for (int c = 0; c < NCH; c++) {
      int p = c * 16 + nn;
      if (p < NPOS) {
        float* oa = out + ((size_t)n * 128 + co_a) * (OH * OW) + r0 * OW + p;
        float* ob = out + ((size_t)n * 128 + co_b) * (OH * OW) + r0 * OW + p;
#pragma unroll
        for (int r = 0; r < 4; r++) {
          oa[(size_t)r * OH * OW] = fmaxf(acc0[c][r] + ba[r], 0.f);
          ob[(size_t)r * OH * OW] = fmaxf(acc1[c][r] + bb[r], 0.f);
        }
      }
    }
  } else {
    float wa[4], wb[4];
#pragma unroll
    for (int r = 0; r < 4; r++) {
      wa[r] = mw[co_a + r];
      wb[r] = mw[co_b + r];
    }
#pragma unroll
    for (int c = 0; c < NCH; c++) {
      int p = c * 16 + nn;
      float s = 0.f;
#pragma unroll
      for (int r = 0; r < 4; r++) {
        s += fmaxf(acc0[c][r] + ba[r], 0.f) * wa[r];
        s += fmaxf(acc1[c][r] + bb[r], 0.f) * wb[r];
      }
      s += __shfl_xor(s, 16);  // sum quads -> 32 co per wave
      s += __shfl_xor(s, 32);
      if (q == 0 && p < NPOS)
        atomicAdd(&out[(size_t)n * (OH * OW) + r0 * OW + p], s);
    }
  }
}

// ---------------- deconv k=4 stride=2: (B,128,9,9)->(B,128,20,20), ReLU -----
__global__ __launch_bounds__(320) void deconv_s2_kernel(
    const float* __restrict__ in, const float* __restrict__ w,
    const float* __restrict__ bias, float* __restrict__ out) {
  constexpr int CI_L = 16;
  constexpr int LWS = pad_lw(16 * 16);  // 258
  const int n = blockIdx.x >> 3;
  const int co0 = (blockIdx.x & 7) * 16;
  __shared__ __align__(16) float lin[CI_L * 9 * 12];
  __shared__ float lw[16 * LWS];
  const int t = threadIdx.x;  // 320 = 16 co x 20 rows
  const int co_l = t / 20, oy = t % 20;
  float acc[20];
#pragma unroll
  for (int i = 0; i < 20; i++) acc[i] = 0.f;
  const float* inN = in + (size_t)n * 128 * 81;
  for (int ci0 = 0; ci0 < 128; ci0 += CI_L) {
    __syncthreads();
    for (int e = t; e < CI_L * 108; e += 320) {
      int ci = e / 108, rem = e % 108, r = rem / 12, c = rem % 12;
      lin[e] = (c < 9) ? inN[(size_t)(ci0 + ci) * 81 + r * 9 + c] : 0.f;
    }
    for (int e = t; e < 16 * CI_L * 16; e += 320) {
      int col = e / (CI_L * 16), rem = e % (CI_L * 16);
      int cil = rem / 16, tap = rem % 16;
      lw[col * LWS + rem] =
          w[((size_t)(ci0 + cil) * 128 + co0 + col) * 16 + tap];
    }
    __syncthreads();
    const int par = oy & 1;
    const float* lwc = &lw[co_l * LWS];
    for (int ci = 0; ci < CI_L; ci++) {
#pragma unroll
      for (int tyi = 0; tyi < 2; tyi++) {
        int ty = par + 2 * tyi;
        int iy = (oy - ty) / 2;
        if (iy >= 0 && iy < 9) {
          float r[12];
          const float4* src = (const float4*)&lin[ci * 108 + iy * 12];
#pragma unroll
          for (int x4 = 0; x4 < 3; x4++) {
            float4 v = src[x4];
            r[4 * x4 + 0] = v.x; r[4 * x4 + 1] = v.y;
            r[4 * x4 + 2] = v.z; r[4 * x4 + 3] = v.w;
          }
#pragma unroll
          for (int tx = 0; tx < 4; tx++) {
            float wv = lwc[ci * 16 + ty * 4 + tx];
#pragma unroll
            for (int ox = 0; ox < 20; ox++) {
              if (((ox - tx) % 2) == 0) {
                int ix = (ox - tx) / 2;
                if (ix >= 0 && ix < 9) acc[ox] += r[ix] * wv;
              }
            }
          }
        }
      }
    }
  }
  float bv = bias[co0 + co_l];
  float* o = out + ((size_t)n * 128 + co0 + co_l) * 400 + oy * 20;
#pragma unroll
  for (int ox = 0; ox < 20; ox++) o[ox] = fmaxf(acc[ox] + bv, 0.f);
}

// ---------------- rec loss: mean((mu + mb - x)^2) ---------------------------
__global__ __launch_bounds__(256) void rec_loss_kernel(
    const float* __restrict__ mu, const float* __restrict__ mb,
    const float* __restrict__ x, float* __restrict__ out) {
  const int t = threadIdx.x;
  const int i = blockIdx.x * 256 + t;
  __shared__ float red[256];
  float d = mu[i] + mb[0] - x[i];
  red[t] = d * d;
  __syncthreads();
  for (int off = 128; off > 0; off >>= 1) {
    if (t < off) red[t] += red[t + off];
    __syncthreads();
  }
  if (t == 0) atomicAdd(out, red[0] * (1.0f / 200704.f));
}

// ---------------- dict / enc losses: sum (val - z)^2 ------------------------
__global__ __launch_bounds__(256) void vq_loss_kernel(
    const float4* __restrict__ val4, const float4* __restrict__ z4,
    float* __restrict__ out) {
  const int t = threadIdx.x;
  const int i = blockIdx.x * 256 + t;
  __shared__ float red[256];
  float4 a = val4[i], b = z4[i];
  float dx = a.x - b.x, dy = a.y - b.y, dz = a.z - b.z, dw = a.w - b.w;
  red[t] = dx * dx + dy * dy + dz * dz + dw * dw;
  __syncthreads();
  for (int off = 128; off > 0; off >>= 1) {
    if (t < off) red[t] += red[t + off];
    __syncthreads();
  }
  if (t == 0) {
    atomicAdd(out + 1, red[0] * (5.f / 1179648.f));
    atomicAdd(out + 2, red[0] * (1.25f / 1179648.f));
  }
}

// ---------------------------------------------------------------------------
extern "C" void kernel_launch(void* const* d_in, const int* in_sizes, int n_in,
                              void* d_out, int out_size, void* d_ws,
                              size_t ws_size, hipStream_t stream) {
  const float* x = (const float*)d_in[0];
  const float* w1 = (const float*)d_in[1];
  const float* b1 = (const float*)d_in[2];
  const float* w2 = (const float*)d_in[3];
  const float* b2 = (const float*)d_in[4];
  const float* w3 = (const float*)d_in[5];
  const float* b3 = (const float*)d_in[6];
  const float* t1w = (const float*)d_in[7];
  const float* t1b = (const float*)d_in[8];
  const float* t2w = (const float*)d_in[9];
  const float* t2b = (const float*)d_in[10];
  const float* t3w = (const float*)d_in[11];
  const float* t3b = (const float*)d_in[12];
  const float* t4w = (const float*)d_in[13];
  const float* t4b = (const float*)d_in[14];
  const float* mw = (const float*)d_in[15];
  const float* mb = (const float*)d_in[16];
  const float* dictw = (const float*)d_in[17];
  float* out = (float*)d_out;

  float* ws = (float*)d_ws;
  float* bufA = ws;               // h1 -> f1 -> f3
  float* bufB = bufA + 18874368;  // p1 -> f2
  float* z = bufB + 13107200;
  float* val = z + 1179648;
  float* mu = val + 1179648;  // 200,704
  ushort* wp1 = (ushort*)(mu + 200704);
  ushort* wp3 = wp1 + 16 * 16384;
  ushort* wp4 = wp3 + 25 * 16384;
  float* h1 = bufA;
  float* p1 = bufB;
  float* f1 = bufA;
  float* f2 = bufB;
  float* f3 = bufA;

  hipMemsetAsync(d_out, 0, 4 * sizeof(float), stream);
  hipMemsetAsync(mu, 0, 200704 * sizeof(float), stream);

  // decoder weight prep (bf16, flipped, [tap][co][ci])
  prep_w<<<16 * 64, 256, 0, stream>>>(t1w, wp1, 16);
  prep_w<<<25 * 64, 256, 0, stream>>>(t3w, wp3, 25);
  prep_w<<<25 * 64, 256, 0, stream>>>(t4w, wp4, 25);

  conv1_kernel<<<B_, 256, 0, stream>>>(x, w1, b1, h1);
  // conv2: 24x24, K5 pad2, relu, fused maxpool -> (12x12)
  conv_tile<24, 24, 24, 24, 5, 2, 8, 24, false, true, true>
      <<<B_ * 8, 384, 0, stream>>>(h1, w2, b2, p1);
  // conv3: 12x12, K5 pad2, no relu, fused maxpool -> (6x6) = z
  conv_tile<12, 12, 12, 12, 5, 2, 8, 12, false, false, true>
      <<<B_ * 8, 192, 0, stream>>>(p1, w3, b3, z);
  vq_kernel<<<B_, 256, 0, stream>>>(z, dictw, val, out + 4);
  // t1: 6->9, K4 (deconv s1), relu  [bf16 MFMA]
  deconv_mfma<6, 6, 9, 9, 4, 9, false>
      <<<dim3(B_, 1), 256, 0, stream>>>(val, wp1, t1b, nullptr, f1);
  // t2: 9->20, K4 s2, relu  [f32]
  deconv_s2_kernel<<<B_ * 8, 320, 0, stream>>>(f1, t2w, t2b, f2);
  // t3: 20->24, K5 (deconv s1), relu  [bf16 MFMA, 3 row-tiles of 8]
  deconv_mfma<20, 20, 24, 24, 5, 8, false>
      <<<dim3(B_, 3), 256, 0, stream>>>(f2, wp3, t3b, nullptr, f3);
  // t4: 24->28, K5 (deconv s1), relu + fused 1x1 mu  [bf16 MFMA, 4 tiles of 7]
  deconv_mfma<24, 24, 28, 28, 5, 7, true>
      <<<dim3(B_, 4), 256, 0, stream>>>(f3, wp4, t4b, mw, mu);
  rec_loss_kernel<<<784, 256, 0, stream>>>(mu, mb, x, out);
  vq_loss_kernel<<<1152, 256, 0, stream>>>((const float4*)val, (const float4*)z,
                                           out);
}

// Round 5
// 2540.067 us; speedup vs baseline: 7.3652x; 1.6092x over previous
//
#include <hip/hip_runtime.h>
#include <hip/hip_bf16.h>

// ---------------------------------------------------------------------------
// VQ-VAE forward.
//  - conv1 f32 (tiny), conv2/conv3: SPLIT-FP16 MFMA implicit GEMM (hi/lo
//    decomposition, 3 MFMAs per product, ~2^-22 relative error => index-exact)
//    with fused bias(+relu)+2x2 maxpool epilogue.
//  - VQ argmax faithful f32.
//  - decoder t1/t3/t4 bf16 MFMA (losses tolerate bf16); t2 f32 direct.
//  - t4 fused with 1x1 mu conv (shfl reduce + atomicAdd).
//
// Workspace (float offsets):
//   bufA 18,874,368 : h1(256,128,24,24) -> f1(256,128,9,9) -> f3(256,128,24,24)
//   bufB 13,107,200 : p1(256,128,12,12) -> f2(256,128,20,20)
//   z 1,179,648 | val 1,179,648 | mu 200,704
//   wp1/wp3/wp4 bf16 decoder weights; w2h/l, w3h/l fp16 split encoder weights
// total ~145 MB
// ---------------------------------------------------------------------------

#define B_ 256

typedef __attribute__((ext_vector_type(8))) short s16x8;
typedef __attribute__((ext_vector_type(8))) _Float16 f16x8;
typedef __attribute__((ext_vector_type(4))) float f32x4;

__device__ inline ushort f2bf(float f) {
  union { __hip_bfloat16 h; ushort u; } cv;
  cv.h = __float2bfloat16(f);
  return cv.u;
}

__host__ __device__ constexpr int pad_lw(int n) {  // == 2 (mod 4)
  return n + ((2 - (n & 3)) & 3);
}

// ------- decoder weight prep: (ci,co,K,K) f32 -> [tap][co][ci] bf16 flipped -
__global__ __launch_bounds__(256) void prep_w(const float* __restrict__ w,
                                              ushort* __restrict__ wp,
                                              int K2) {
  int idx = blockIdx.x * 256 + threadIdx.x;
  if (idx >= K2 * 16384) return;
  int ci = idx & 127;
  int co = (idx >> 7) & 127;
  int tap = idx >> 14;
  wp[idx] = f2bf(w[((size_t)ci * 128 + co) * K2 + (K2 - 1 - tap)]);
}

// ------- encoder weight prep: (co,ci,K,K) f32 -> [tap][co][ci] fp16 hi/lo ---
__global__ __launch_bounds__(256) void prep_w_split(const float* __restrict__ w,
                                                    _Float16* __restrict__ wh,
                                                    _Float16* __restrict__ wl,
                                                    int K2) {
  int idx = blockIdx.x * 256 + threadIdx.x;
  if (idx >= K2 * 16384) return;
  int ci = idx & 127;
  int co = (idx >> 7) & 127;
  int tap = idx >> 14;
  float v = w[((size_t)co * 128 + ci) * K2 + tap];
  _Float16 h = (_Float16)v;
  wh[idx] = h;
  wl[idx] = (_Float16)(v - (float)h);
}

// ---------------- conv1: (B,1,28,28) -> (B,128,24,24), 5x5, pad0, ReLU ------
__global__ __launch_bounds__(256) void conv1_kernel(
    const float* __restrict__ x, const float* __restrict__ w,
    const float* __restrict__ b, float* __restrict__ out) {
  const int n = blockIdx.x;
  __shared__ float xl[784];
  __shared__ float wl[128 * 25];
  __shared__ float bl[128];
  const int t = threadIdx.x;
  for (int e = t; e < 784; e += 256) xl[e] = x[n * 784 + e];
  for (int e = t; e < 3200; e += 256) wl[e] = w[e];
  if (t < 128) bl[t] = b[t];
  __syncthreads();
  float* on = out + (size_t)n * 128 * 576;
  for (int idx = t; idx < 128 * 576; idx += 256) {
    int co = idx / 576, p = idx % 576;
    int y = p / 24, xx = p % 24;
    float acc = bl[co];
    const float* wc = &wl[co * 25];
#pragma unroll
    for (int ky = 0; ky < 5; ky++)
#pragma unroll
      for (int kx = 0; kx < 5; kx++)
        acc += xl[(y + ky) * 28 + xx + kx] * wc[ky * 5 + kx];
    on[idx] = fmaxf(acc, 0.f);
  }
}

// ---------------- split-fp16 MFMA conv + bias(+relu) + 2x2 maxpool ----------
// Square IHxIW, pad=PAD, same-size conv, pooled output (IW/2 x IW/2).
// Block 256 thr = 4 waves; wave owns ALL 8 co-tiles x TCH pos-chunks
// (TCH*16 pos = whole output rows => pooling stays inside the wave).
template <int IW, int K, int PAD, int TR, int TCH, bool RELU>
__global__ __launch_bounds__(256, 1) void conv_mfma_pool(
    const float* __restrict__ in, const _Float16* __restrict__ wph,
    const _Float16* __restrict__ wpl, const float* __restrict__ bias,
    float* __restrict__ out) {
  constexpr int IH = IW, OW = IW, OH = IW;
  constexpr int PW = IW + 2 * PAD;
  constexpr int SROWS = TR + K - 1;
  constexpr int S = SROWS * PW;
  constexpr int NPOS = TR * OW;
  constexpr int NCH = NPOS / 16;
  constexpr int K2 = K * K;
  constexpr int PITCH = 40;      // f16 units; 80B rows, b128-aligned at q*8
  constexpr int NR = 48 / OW;    // output rows per wave (even)
  constexpr int PROWS = NR / 2;  // pooled rows per wave
  constexpr int OCW = OW / 2;
  static_assert(NPOS % 16 == 0, "");
  static_assert((TCH * 16) % OW == 0, "wave must own whole rows");
  static_assert(16 * PROWS * OCW == 192, "epilogue assumes 192 outs/tile");
  const int n = blockIdx.x;
  const int r0 = blockIdx.y * TR;
  __shared__ _Float16 linh[S * PITCH];
  __shared__ _Float16 linl[S * PITCH];
  __shared__ _Float16 lwh[2][128 * PITCH];
  __shared__ _Float16 lwl[2][128 * PITCH];
  __shared__ float scr[4][16 * 49];
  const int t = threadIdx.x;
  const int wv = t >> 6;
  const int lane = t & 63;
  const int nn = lane & 15;
  const int q = lane >> 4;
  const int c0 = wv * TCH;
  const bool active = c0 < NCH;  // wave-uniform
  f32x4 acc[8][TCH];
#pragma unroll
  for (int j = 0; j < 8; j++)
#pragma unroll
    for (int i = 0; i < TCH; i++) acc[j][i] = f32x4{0.f, 0.f, 0.f, 0.f};
  int base[TCH];
#pragma unroll
  for (int i = 0; i < TCH; i++) {
    int p = (c0 + i) * 16 + nn;
    if (p >= NPOS) p = NPOS - 1;  // inactive-wave safety (reads only)
    base[i] = (p / OW) * PW + (p % OW);
  }
  const float* inN = in + (size_t)n * 128 * IH * IW;
  for (int cb = 0; cb < 4; cb++) {
    const int ci0 = cb * 32;
    __syncthreads();
    // stage input ci-block as fp16 hi/lo: [spatial][ci32]
    for (int e = t; e < 32 * S; e += 256) {
      int ci = e / S, sp = e - ci * S;
      int r = sp / PW, c = sp - r * PW;
      int ir = r0 + r - PAD, ic = c - PAD;
      float v = 0.f;
      if (ir >= 0 && ir < IH && ic >= 0 && ic < IW)
        v = inN[(size_t)(ci0 + ci) * (IH * IW) + ir * IW + ic];
      _Float16 h = (_Float16)v;
      linh[sp * PITCH + ci] = h;
      linl[sp * PITCH + ci] = (_Float16)(v - (float)h);
    }
    // stage weights tap 0
    for (int e = t; e < 4096; e += 256) {
      int co = e >> 5, ci = e & 31;
      size_t g = (size_t)co * 128 + ci0 + ci;
      lwh[0][co * PITCH + ci] = wph[g];
      lwl[0][co * PITCH + ci] = wpl[g];
    }
    __syncthreads();
    for (int tap = 0; tap < K2; tap++) {
      if (tap + 1 < K2) {  // double-buffered weight prefetch
        const _Float16* sh = wph + (size_t)(tap + 1) * 16384 + ci0;
        const _Float16* sl = wpl + (size_t)(tap + 1) * 16384 + ci0;
        _Float16* dh = lwh[(tap + 1) & 1];
        _Float16* dl = lwl[(tap + 1) & 1];
        for (int e = t; e < 4096; e += 256) {
          int co = e >> 5, ci = e & 31;
          dh[co * PITCH + ci] = sh[co * 128 + ci];
          dl[co * PITCH + ci] = sl[co * 128 + ci];
        }
      }
      if (active) {
        const int ky = tap / K, kx = tap - ky * K;
        const int toff = ky * PW + kx;
        const _Float16* ch = lwh[tap & 1];
        const _Float16* cl = lwl[tap & 1];
        f16x8 ah[8], al[8];
#pragma unroll
        for (int j = 0; j < 8; j++) {
          ah[j] = *(const f16x8*)&ch[(j * 16 + nn) * PITCH + q * 8];
          al[j] = *(const f16x8*)&cl[(j * 16 + nn) * PITCH + q * 8];
        }
#pragma unroll
        for (int i = 0; i < TCH; i++) {
          f16x8 bh = *(const f16x8*)&linh[(base[i] + toff) * PITCH + q * 8];
          f16x8 bl = *(const f16x8*)&linl[(base[i] + toff) * PITCH + q * 8];
#pragma unroll
          for (int j = 0; j < 8; j++) {
            acc[j][i] = __builtin_amdgcn_mfma_f32_16x16x32_f16(ah[j], bh,
                                                               acc[j][i], 0, 0, 0);
            acc[j][i] = __builtin_amdgcn_mfma_f32_16x16x32_f16(ah[j], bl,
                                                               acc[j][i], 0, 0, 0);
            acc[j][i] = __builtin_amdgcn_mfma_f32_16x16x32_f16(al[j], bh,
                                                               acc[j][i], 0, 0, 0);
          }
        }
      }
      __syncthreads();
    }
  }
  // epilogue per co-tile: bias(+relu) -> wave scratch -> 2x2 pool -> global
  for (int j = 0; j < 8; j++) {
    if (active) {
#pragma unroll
      for (int i = 0; i < TCH; i++)
#pragma unroll
        for (int r = 0; r < 4; r++) {
          float v = acc[j][i][r] + bias[j * 16 + q * 4 + r];
          if (RELU) v = fmaxf(v, 0.f);
          scr[wv][(q * 4 + r) * 49 + (c0 + i - c0) * 16 + i * 0 + i * 16 + nn - i * 16] = v;  // placeholder
        }
    }
    __syncthreads();
    if (active) {
#pragma unroll
      for (int k = 0; k < 3; k++) {
        int o = lane + 64 * k;  // 0..191
        int co_l = o / (PROWS * OCW);
        int rem = o - co_l * (PROWS * OCW);
        int pr = rem / OCW, oc = rem - pr * OCW;
        const float* s = &scr[wv][co_l * 49];
        int lp = (2 * pr) * OW + 2 * oc;
        float m = fmaxf(fmaxf(s[lp], s[lp + 1]), fmaxf(s[lp + OW], s[lp + OW + 1]));
        int gr = r0 / 2 + wv * PROWS + pr;
        out[((size_t)n * 128 + j * 16 + co_l) * (OH / 2) * (OW / 2) +
            gr * (OW / 2) + oc] = m;
      }
    }
    __syncthreads();
  }
}

// fix for the scr-store index (kept simple & correct): local pos = i*16+nn
// (the expression above reduces to exactly that; see write below)
// NOTE: the placeholder arithmetic in conv_mfma_pool's scr store evaluates to
// (q*4+r)*49 + i*16 + nn, which is the intended index.

// ---------------- VQ: distances, argmax(d2) [faithful], gather --------------
__global__ __launch_bounds__(256) void vq_kernel(
    const float* __restrict__ z, const float* __restrict__ dict,
    float* __restrict__ val, float* __restrict__ out_idx) {
  const int n = blockIdx.x;
  __shared__ float zl[128 * 36];
  __shared__ float d2[36 * 129];
  __shared__ float w2n[128];
  __shared__ int bk[36];
  const int t = threadIdx.x;
  const float* zn = z + (size_t)n * 4608;
  for (int e = t; e < 4608; e += 256) zl[e] = zn[e];
  if (t < 128) {
    float s = 0.f;
    const float* wr = dict + t * 128;
    for (int c = 0; c < 128; c++) s += wr[c] * wr[c];
    w2n[t] = s;
  }
  __syncthreads();
  const int k = t & 127, pg = t >> 7;
  float dot[18];
#pragma unroll
  for (int i = 0; i < 18; i++) dot[i] = 0.f;
  const float* wr = dict + k * 128;
  for (int c = 0; c < 128; c++) {
    float wv = wr[c];
    const float* zr = &zl[c * 36 + pg * 18];
#pragma unroll
    for (int i = 0; i < 18; i++) dot[i] += zr[i] * wv;
  }
  float wn = w2n[k];
#pragma unroll
  for (int i = 0; i < 18; i++) d2[(pg * 18 + i) * 129 + k] = wn - 2.f * dot[i];
  __syncthreads();
  if (t < 36) {
    const float* dr = &d2[t * 129];
    float best = dr[0];
    int bi = 0;
    for (int kk = 1; kk < 128; kk++) {
      float v = dr[kk];
      if (v > best) { best = v; bi = kk; }  // strict >: first max (argmax tie)
    }
    bk[t] = bi;
    out_idx[n * 36 + t] = (float)bi;
  }
  __syncthreads();
  float* vn = val + (size_t)n * 4608;
  for (int e = t; e < 4608; e += 256) {
    int c = e / 36, p = e % 36;
    vn[e] = dict[bk[p] * 128 + c];
  }
}

// ---------------- bf16 MFMA deconv (stride 1), optional fused mu ------------
template <int IH, int IW, int OH, int OW, int K, int TR, bool MU_FUSE>
__global__ __launch_bounds__(256) void deconv_mfma(
    const float* __restrict__ in, const ushort* __restrict__ wprep,
    const float* __restrict__ bias, const float* __restrict__ mw,
    float* __restrict__ out) {
  constexpr int PAD = K - 1;
  constexpr int PW = IW + 2 * PAD;
  constexpr int K2 = K * K;
  constexpr int SROWS = TR + K - 1;
  constexpr int S = SROWS * PW;
  constexpr int NPOS = TR * OW;
  constexpr int NCH = (NPOS + 15) / 16;
  constexpr int PITCH = 40;
  const int n = blockIdx.x;
  const int r0 = blockIdx.y * TR;
  __shared__ __align__(16) ushort lin[S * PITCH];
  __shared__ __align__(16) ushort lw[2][128 * PITCH];
  const int t = threadIdx.x;
  const int wv = t >> 6;
  const int lane = t & 63;
  const int nn = lane & 15;
  const int q = lane >> 4;
  f32x4 acc0[NCH], acc1[NCH];
  int base[NCH];
#pragma unroll
  for (int c = 0; c < NCH; c++) {
    acc0[c] = f32x4{0.f, 0.f, 0.f, 0.f};
    acc1[c] = f32x4{0.f, 0.f, 0.f, 0.f};
    int p = c * 16 + nn;
    int pc = p < NPOS ? p : NPOS - 1;
    base[c] = (pc / OW) * PW + (pc % OW);
  }
  const float* inN = in + (size_t)n * 128 * IH * IW;
  for (int cb = 0; cb < 4; cb++) {
    const int ci0 = cb * 32;
    __syncthreads();
    for (int e = t; e < 32 * S; e += 256) {
      int ci = e / S, sp = e - ci * S;
      int rr = sp / PW, cc = sp - rr * PW;
      int ir = r0 + rr - PAD, ic = cc - PAD;
      float v = 0.f;
      if (ir >= 0 && ir < IH && ic >= 0 && ic < IW)
        v = inN[(size_t)(ci0 + ci) * (IH * IW) + ir * IW + ic];
      lin[sp * PITCH + ci] = f2bf(v);
    }
    {
      const ushort* wp = wprep + ci0;
      for (int e = t; e < 4096; e += 256) {
        int co = e >> 5, ci = e & 31;
        lw[0][co * PITCH + ci] = wp[co * 128 + ci];
      }
    }
    __syncthreads();
    for (int tap = 0; tap < K2; tap++) {
      if (tap + 1 < K2) {
        const ushort* wp = wprep + (size_t)(tap + 1) * 16384 + ci0;
        ushort* dst = lw[(tap + 1) & 1];
        for (int e = t; e < 4096; e += 256) {
          int co = e >> 5, ci = e & 31;
          dst[co * PITCH + ci] = wp[co * 128 + ci];
        }
      }
      const int ky = tap / K, kx = tap - ky * K;
      const int toff = ky * PW + kx;
      const ushort* lwc = lw[tap & 1];
      s16x8 a0 = *(const s16x8*)&lwc[(wv * 16 + nn) * PITCH + q * 8];
      s16x8 a1 = *(const s16x8*)&lwc[((wv + 4) * 16 + nn) * PITCH + q * 8];
#pragma unroll
      for (int c = 0; c < NCH; c++) {
        s16x8 b = *(const s16x8*)&lin[(base[c] + toff) * PITCH + q * 8];
        acc0[c] =
            __builtin_amdgcn_mfma_f32_16x16x32_bf16(a0, b, acc0[c], 0, 0, 0);
        acc1[c] =
            __builtin_amdgcn_mfma_f32_16x16x32_bf16(a1, b, acc1[c], 0, 0, 0);
      }
      __syncthreads();
    }
  }
  const int co_a = wv * 16 + q * 4;
  const int co_b = (wv + 4) * 16 + q * 4;
  float ba[4], bb[4];
#pragma unroll
  for (int r = 0; r < 4; r++) {
    ba[r] = bias[co_a + r];
    bb[r] = bias[co_b + r];
  }
  if (!MU_FUSE) {
#pragma unroll
    for (int c = 0; c < NCH; c++) {
      int p = c * 16 + nn;
      if (p < NPOS) {
        float* oa = out + ((size_t)n * 128 + co_a) * (OH * OW) + r0 * OW + p;
        float* ob = out + ((size_t)n * 128 + co_b) * (OH * OW) + r0 * OW + p;
#pragma unroll
        for (int r = 0; r < 4; r++) {
          oa[(size_t)r * OH * OW] = fmaxf(acc0[c][r] + ba[r], 0.f);
          ob[(size_t)r * OH * OW] = fmaxf(acc1[c][r] + bb[r], 0.f);
        }
      }
    }
  } else {
    float wa[4], wb[4];
#pragma unroll
    for (int r = 0; r < 4; r++) {
      wa[r] = mw[co_a + r];
      wb[r] = mw[co_b + r];
    }
#pragma unroll
    for (int c = 0; c < NCH; c++) {
      int p = c * 16 + nn;
      float s = 0.f;
#pragma unroll
      for (int r = 0; r < 4; r++) {
        s += fmaxf(acc0[c][r] + ba[r], 0.f) * wa[r];
        s += fmaxf(acc1[c][r] + bb[r], 0.f) * wb[r];
      }
      s += __shfl_xor(s, 16);
      s += __shfl_xor(s, 32);
      if (q == 0 && p < NPOS)
        atomicAdd(&out[(size_t)n * (OH * OW) + r0 * OW + p], s);
    }
  }
}

// ---------------- deconv k=4 stride=2: (B,128,9,9)->(B,128,20,20), ReLU -----
__global__ __launch_bounds__(320) void deconv_s2_kernel(
    const float* __restrict__ in, const float* __restrict__ w,
    const float* __restrict__ bias, float* __restrict__ out) {
  constexpr int CI_L = 16;
  constexpr int LWS = pad_lw(16 * 16);  // 258
  const int n = blockIdx.x >> 3;
  const int co0 = (blockIdx.x & 7) * 16;
  __shared__ __align__(16) float lin[CI_L * 9 * 12];
  __shared__ float lw[16 * LWS];
  const int t = threadIdx.x;  // 320 = 16 co x 20 rows
  const int co_l = t / 20, oy = t % 20;
  float acc[20];
#pragma unroll
  for (int i = 0; i < 20; i++) acc[i] = 0.f;
  const float* inN = in + (size_t)n * 128 * 81;
  for (int ci0 = 0; ci0 < 128; ci0 += CI_L) {
    __syncthreads();
    for (int e = t; e < CI_L * 108; e += 320) {
      int ci = e / 108, rem = e % 108, r = rem / 12, c = rem % 12;
      lin[e] = (c < 9) ? inN[(size_t)(ci0 + ci) * 81 + r * 9 + c] : 0.f;
    }
    for (int e = t; e < 16 * CI_L * 16; e += 320) {
      int col = e / (CI_L * 16), rem = e % (CI_L * 16);
      int cil = rem / 16, tap = rem % 16;
      lw[col * LWS + rem] =
          w[((size_t)(ci0 + cil) * 128 + co0 + col) * 16 + tap];
    }
    __syncthreads();
    const int par = oy & 1;
    const float* lwc = &lw[co_l * LWS];
    for (int ci = 0; ci < CI_L; ci++) {
#pragma unroll
      for (int tyi = 0; tyi < 2; tyi++) {
        int ty = par + 2 * tyi;
        int iy = (oy - ty) / 2;
        if (iy >= 0 && iy < 9) {
          float r[12];
          const float4* src = (const float4*)&lin[ci * 108 + iy * 12];
#pragma unroll
          for (int x4 = 0; x4 < 3; x4++) {
            float4 v = src[x4];
            r[4 * x4 + 0] = v.x; r[4 * x4 + 1] = v.y;
            r[4 * x4 + 2] = v.z; r[4 * x4 + 3] = v.w;
          }
#pragma unroll
          for (int tx = 0; tx < 4; tx++) {
            float wv = lwc[ci * 16 + ty * 4 + tx];
#pragma unroll
            for (int ox = 0; ox < 20; ox++) {
              if (((ox - tx) % 2) == 0) {
                int ix = (ox - tx) / 2;
                if (ix >= 0 && ix < 9) acc[ox] += r[ix] * wv;
              }
            }
          }
        }
      }
    }
  }
  float bv = bias[co0 + co_l];
  float* o = out + ((size_t)n * 128 + co0 + co_l) * 400 + oy * 20;
#pragma unroll
  for (int ox = 0; ox < 20; ox++) o[ox] = fmaxf(acc[ox] + bv, 0.f);
}

// ---------------- rec loss: mean((mu + mb - x)^2) ---------------------------
__global__ __launch_bounds__(256) void rec_loss_kernel(
    const float* __restrict__ mu, const float* __restrict__ mb,
    const float* __restrict__ x, float* __restrict__ out) {
  const int t = threadIdx.x;
  const int i = blockIdx.x * 256 + t;
  __shared__ float red[256];
  float d = mu[i] + mb[0] - x[i];
  red[t] = d * d;
  __syncthreads();
  for (int off = 128; off > 0; off >>= 1) {
    if (t < off) red[t] += red[t + off];
    __syncthreads();
  }
  if (t == 0) atomicAdd(out, red[0] * (1.0f / 200704.f));
}

// ---------------- dict / enc losses: sum (val - z)^2 ------------------------
__global__ __launch_bounds__(256) void vq_loss_kernel(
    const float4* __restrict__ val4, const float4* __restrict__ z4,
    float* __restrict__ out) {
  const int t = threadIdx.x;
  const int i = blockIdx.x * 256 + t;
  __shared__ float red[256];
  float4 a = val4[i], b = z4[i];
  float dx = a.x - b.x, dy = a.y - b.y, dz = a.z - b.z, dw = a.w - b.w;
  red[t] = dx * dx + dy * dy + dz * dz + dw * dw;
  __syncthreads();
  for (int off = 128; off > 0; off >>= 1) {
    if (t < off) red[t] += red[t + off];
    __syncthreads();
  }
  if (t == 0) {
    atomicAdd(out + 1, red[0] * (5.f / 1179648.f));
    atomicAdd(out + 2, red[0] * (1.25f / 1179648.f));
  }
}

// ---------------------------------------------------------------------------
extern "C" void kernel_launch(void* const* d_in, const int* in_sizes, int n_in,
                              void* d_out, int out_size, void* d_ws,
                              size_t ws_size, hipStream_t stream) {
  const float* x = (const float*)d_in[0];
  const float* w1 = (const float*)d_in[1];
  const float* b1 = (const float*)d_in[2];
  const float* w2 = (const float*)d_in[3];
  const float* b2 = (const float*)d_in[4];
  const float* w3 = (const float*)d_in[5];
  const float* b3 = (const float*)d_in[6];
  const float* t1w = (const float*)d_in[7];
  const float* t1b = (const float*)d_in[8];
  const float* t2w = (const float*)d_in[9];
  const float* t2b = (const float*)d_in[10];
  const float* t3w = (const float*)d_in[11];
  const float* t3b = (const float*)d_in[12];
  const float* t4w = (const float*)d_in[13];
  const float* t4b = (const float*)d_in[14];
  const float* mw = (const float*)d_in[15];
  const float* mb = (const float*)d_in[16];
  const float* dictw = (const float*)d_in[17];
  float* out = (float*)d_out;

  float* ws = (float*)d_ws;
  float* bufA = ws;               // h1 -> f1 -> f3
  float* bufB = bufA + 18874368;  // p1 -> f2
  float* z = bufB + 13107200;
  float* val = z + 1179648;
  float* mu = val + 1179648;  // 200,704
  ushort* wp1 = (ushort*)(mu + 200704);
  ushort* wp3 = wp1 + 16 * 16384;
  ushort* wp4 = wp3 + 25 * 16384;
  _Float16* w2h = (_Float16*)(wp4 + 25 * 16384);
  _Float16* w2l = w2h + 25 * 16384;
  _Float16* w3h = w2l + 25 * 16384;
  _Float16* w3l = w3h + 25 * 16384;
  float* h1 = bufA;
  float* p1 = bufB;
  float* f1 = bufA;
  float* f2 = bufB;
  float* f3 = bufA;

  hipMemsetAsync(d_out, 0, 4 * sizeof(float), stream);
  hipMemsetAsync(mu, 0, 200704 * sizeof(float), stream);

  // weight prep
  prep_w<<<16 * 64, 256, 0, stream>>>(t1w, wp1, 16);
  prep_w<<<25 * 64, 256, 0, stream>>>(t3w, wp3, 25);
  prep_w<<<25 * 64, 256, 0, stream>>>(t4w, wp4, 25);
  prep_w_split<<<25 * 64, 256, 0, stream>>>(w2, w2h, w2l, 25);
  prep_w_split<<<25 * 64, 256, 0, stream>>>(w3, w3h, w3l, 25);

  conv1_kernel<<<B_, 256, 0, stream>>>(x, w1, b1, h1);
  // conv2: 24x24 K5 pad2 relu + pool -> p1 (12x12)  [split-fp16 MFMA]
  conv_mfma_pool<24, 5, 2, 8, 3, true>
      <<<dim3(B_, 3), 256, 0, stream>>>(h1, w2h, w2l, b2, p1);
  // conv3: 12x12 K5 pad2 + pool -> z (6x6)  [split-fp16 MFMA]
  conv_mfma_pool<12, 5, 2, 12, 3, false>
      <<<dim3(B_, 1), 256, 0, stream>>>(p1, w3h, w3l, b3, z);
  vq_kernel<<<B_, 256, 0, stream>>>(z, dictw, val, out + 4);
  // t1: 6->9, K4 (deconv s1), relu  [bf16 MFMA]
  deconv_mfma<6, 6, 9, 9, 4, 9, false>
      <<<dim3(B_, 1), 256, 0, stream>>>(val, wp1, t1b, nullptr, f1);
  // t2: 9->20, K4 s2, relu  [f32]
  deconv_s2_kernel<<<B_ * 8, 320, 0, stream>>>(f1, t2w, t2b, f2);
  // t3: 20->24, K5 (deconv s1), relu  [bf16 MFMA]
  deconv_mfma<20, 20, 24, 24, 5, 8, false>
      <<<dim3(B_, 3), 256, 0, stream>>>(f2, wp3, t3b, nullptr, f3);
  // t4: 24->28, K5 (deconv s1), relu + fused 1x1 mu  [bf16 MFMA]
  deconv_mfma<24, 24, 28, 28, 5, 7, true>
      <<<dim3(B_, 4), 256, 0, stream>>>(f3, wp4, t4b, mw, mu);
  rec_loss_kernel<<<784, 256, 0, stream>>>(mu, mb, x, out);
  vq_loss_kernel<<<1152, 256, 0, stream>>>((const float4*)val, (const float4*)z,
                                           out);
}

// Round 6
// 1926.078 us; speedup vs baseline: 9.7131x; 1.3188x over previous
//
#include <hip/hip_runtime.h>
#include <hip/hip_bf16.h>

// ---------------------------------------------------------------------------
// VQ-VAE forward.
//  - conv1 f32 (tiny); conv2/conv3 split-fp16 MFMA (hi/lo, 3 MFMAs/product,
//    ~2^-22 rel err => index-exact) + fused bias(+relu)+2x2 maxpool.
//  - Weights are NOT staged in LDS: A-fragments load directly from global
//    ([tap][co][ci] packed, b128/lane, L2-resident) -> no per-tap barriers,
//    LDS = input only -> 2 blocks/CU (was 1) for conv, 3+ for deconv.
//  - VQ argmax faithful f32.
//  - decoder t1/t3/t4 bf16 MFMA; t2 f32 direct; t4 fused with 1x1 mu conv.
// ---------------------------------------------------------------------------

#define B_ 256

typedef __attribute__((ext_vector_type(8))) short s16x8;
typedef __attribute__((ext_vector_type(8))) _Float16 f16x8;
typedef __attribute__((ext_vector_type(4))) float f32x4;

__device__ inline ushort f2bf(float f) {
  union { __hip_bfloat16 h; ushort u; } cv;
  cv.h = __float2bfloat16(f);
  return cv.u;
}

__host__ __device__ constexpr int pad_lw(int n) {  // == 2 (mod 4)
  return n + ((2 - (n & 3)) & 3);
}

// ------- decoder weight prep: (ci,co,K,K) f32 -> [tap][co][ci] bf16 flipped -
__global__ __launch_bounds__(256) void prep_w(const float* __restrict__ w,
                                              ushort* __restrict__ wp,
                                              int K2) {
  int idx = blockIdx.x * 256 + threadIdx.x;
  if (idx >= K2 * 16384) return;
  int ci = idx & 127;
  int co = (idx >> 7) & 127;
  int tap = idx >> 14;
  wp[idx] = f2bf(w[((size_t)ci * 128 + co) * K2 + (K2 - 1 - tap)]);
}

// ------- encoder weight prep: (co,ci,K,K) f32 -> [tap][co][ci] fp16 hi/lo ---
__global__ __launch_bounds__(256) void prep_w_split(const float* __restrict__ w,
                                                    _Float16* __restrict__ wh,
                                                    _Float16* __restrict__ wl,
                                                    int K2) {
  int idx = blockIdx.x * 256 + threadIdx.x;
  if (idx >= K2 * 16384) return;
  int ci = idx & 127;
  int co = (idx >> 7) & 127;
  int tap = idx >> 14;
  float v = w[((size_t)co * 128 + ci) * K2 + tap];
  _Float16 h = (_Float16)v;
  wh[idx] = h;
  wl[idx] = (_Float16)(v - (float)h);
}

// ---------------- conv1: (B,1,28,28) -> (B,128,24,24), 5x5, pad0, ReLU ------
__global__ __launch_bounds__(256) void conv1_kernel(
    const float* __restrict__ x, const float* __restrict__ w,
    const float* __restrict__ b, float* __restrict__ out) {
  const int n = blockIdx.x;
  __shared__ float xl[784];
  __shared__ float wl[128 * 25];
  __shared__ float bl[128];
  const int t = threadIdx.x;
  for (int e = t; e < 784; e += 256) xl[e] = x[n * 784 + e];
  for (int e = t; e < 3200; e += 256) wl[e] = w[e];
  if (t < 128) bl[t] = b[t];
  __syncthreads();
  float* on = out + (size_t)n * 128 * 576;
  for (int idx = t; idx < 128 * 576; idx += 256) {
    int co = idx / 576, p = idx % 576;
    int y = p / 24, xx = p % 24;
    float acc = bl[co];
    const float* wc = &wl[co * 25];
#pragma unroll
    for (int ky = 0; ky < 5; ky++)
#pragma unroll
      for (int kx = 0; kx < 5; kx++)
        acc += xl[(y + ky) * 28 + xx + kx] * wc[ky * 5 + kx];
    on[idx] = fmaxf(acc, 0.f);
  }
}

// ---------------- split-fp16 MFMA conv + bias(+relu) + 2x2 maxpool ----------
// Block 256 thr = 4 waves; wave owns ALL 8 co-tiles x TCH pos-chunks.
// Weights read per-tap directly from global (L2-hot), b128 per lane.
template <int IW, int K, int PAD, int TR, int TCH, bool RELU>
__global__ __launch_bounds__(256, 2) void conv_mfma_pool(
    const float* __restrict__ in, const _Float16* __restrict__ wph,
    const _Float16* __restrict__ wpl, const float* __restrict__ bias,
    float* __restrict__ out) {
  constexpr int IH = IW, OW = IW, OH = IW;
  constexpr int PW = IW + 2 * PAD;
  constexpr int SROWS = TR + K - 1;
  constexpr int S = SROWS * PW;
  constexpr int NPOS = TR * OW;
  constexpr int NCH = NPOS / 16;
  constexpr int K2 = K * K;
  constexpr int PITCH = 40;      // f16 units; 80B rows, b128-aligned at q*8
  constexpr int NR = 48 / OW;    // output rows per wave (even)
  constexpr int PROWS = NR / 2;  // pooled rows per wave
  constexpr int OCW = OW / 2;
  static_assert(NPOS % 16 == 0, "");
  static_assert((TCH * 16) % OW == 0, "wave must own whole rows");
  static_assert(16 * PROWS * OCW == 192, "epilogue assumes 192 outs/tile");
  const int n = blockIdx.x;
  const int r0 = blockIdx.y * TR;
  __shared__ _Float16 linh[S * PITCH];
  __shared__ _Float16 linl[S * PITCH];
  __shared__ float scr[4][16 * 49];
  const int t = threadIdx.x;
  const int wv = t >> 6;
  const int lane = t & 63;
  const int nn = lane & 15;
  const int q = lane >> 4;
  const int c0 = wv * TCH;
  const bool active = c0 < NCH;  // wave-uniform
  f32x4 acc[8][TCH];
#pragma unroll
  for (int j = 0; j < 8; j++)
#pragma unroll
    for (int i = 0; i < TCH; i++) acc[j][i] = f32x4{0.f, 0.f, 0.f, 0.f};
  int base[TCH];
#pragma unroll
  for (int i = 0; i < TCH; i++) {
    int p = (c0 + i) * 16 + nn;
    if (p >= NPOS) p = NPOS - 1;  // inactive-wave safety (reads only)
    base[i] = (p / OW) * PW + (p % OW);
  }
  const float* inN = in + (size_t)n * 128 * IH * IW;
  for (int cb = 0; cb < 4; cb++) {
    const int ci0 = cb * 32;
    __syncthreads();  // all waves done reading previous ci-block
    for (int e = t; e < 32 * S; e += 256) {
      int ci = e / S, sp = e - ci * S;
      int r = sp / PW, c = sp - r * PW;
      int ir = r0 + r - PAD, ic = c - PAD;
      float v = 0.f;
      if (ir >= 0 && ir < IH && ic >= 0 && ic < IW)
        v = inN[(size_t)(ci0 + ci) * (IH * IW) + ir * IW + ic];
      _Float16 h = (_Float16)v;
      linh[sp * PITCH + ci] = h;
      linl[sp * PITCH + ci] = (_Float16)(v - (float)h);
    }
    __syncthreads();
    if (active) {
      for (int tap = 0; tap < K2; tap++) {
        const int ky = tap / K, kx = tap - ky * K;
        const int toff = ky * PW + kx;
        f16x8 ah[8], al[8];
#pragma unroll
        for (int j = 0; j < 8; j++) {
          size_t g = ((size_t)tap * 128 + j * 16 + nn) * 128 + ci0 + q * 8;
          ah[j] = *(const f16x8*)&wph[g];
          al[j] = *(const f16x8*)&wpl[g];
        }
#pragma unroll
        for (int i = 0; i < TCH; i++) {
          f16x8 bh = *(const f16x8*)&linh[(base[i] + toff) * PITCH + q * 8];
          f16x8 bl = *(const f16x8*)&linl[(base[i] + toff) * PITCH + q * 8];
#pragma unroll
          for (int j = 0; j < 8; j++) {
            acc[j][i] = __builtin_amdgcn_mfma_f32_16x16x32_f16(
                ah[j], bh, acc[j][i], 0, 0, 0);
            acc[j][i] = __builtin_amdgcn_mfma_f32_16x16x32_f16(
                ah[j], bl, acc[j][i], 0, 0, 0);
            acc[j][i] = __builtin_amdgcn_mfma_f32_16x16x32_f16(
                al[j], bh, acc[j][i], 0, 0, 0);
          }
        }
      }
    }
  }
  // epilogue per co-tile: bias(+relu) -> wave scratch -> 2x2 pool -> global
  for (int j = 0; j < 8; j++) {
    if (active) {
#pragma unroll
      for (int i = 0; i < TCH; i++)
#pragma unroll
        for (int r = 0; r < 4; r++) {
          float v = acc[j][i][r] + bias[j * 16 + q * 4 + r];
          if (RELU) v = fmaxf(v, 0.f);
          scr[wv][(q * 4 + r) * 49 + i * 16 + nn] = v;
        }
    }
    __syncthreads();
    if (active) {
#pragma unroll
      for (int k = 0; k < 3; k++) {
        int o = lane + 64 * k;  // 0..191
        int co_l = o / (PROWS * OCW);
        int rem = o - co_l * (PROWS * OCW);
        int pr = rem / OCW, oc = rem - pr * OCW;
        const float* s = &scr[wv][co_l * 49];
        int lp = (2 * pr) * OW + 2 * oc;
        float m =
            fmaxf(fmaxf(s[lp], s[lp + 1]), fmaxf(s[lp + OW], s[lp + OW + 1]));
        int gr = r0 / 2 + wv * PROWS + pr;
        out[((size_t)n * 128 + j * 16 + co_l) * (OH / 2) * (OW / 2) +
            gr * (OW / 2) + oc] = m;
      }
    }
    __syncthreads();
  }
}

// ---------------- VQ: distances, argmax(d2) [faithful], gather --------------
__global__ __launch_bounds__(256) void vq_kernel(
    const float* __restrict__ z, const float* __restrict__ dict,
    float* __restrict__ val, float* __restrict__ out_idx) {
  const int n = blockIdx.x;
  __shared__ float zl[128 * 36];
  __shared__ float d2[36 * 129];
  __shared__ float w2n[128];
  __shared__ int bk[36];
  const int t = threadIdx.x;
  const float* zn = z + (size_t)n * 4608;
  for (int e = t; e < 4608; e += 256) zl[e] = zn[e];
  if (t < 128) {
    float s = 0.f;
    const float* wr = dict + t * 128;
    for (int c = 0; c < 128; c++) s += wr[c] * wr[c];
    w2n[t] = s;
  }
  __syncthreads();
  const int k = t & 127, pg = t >> 7;
  float dot[18];
#pragma unroll
  for (int i = 0; i < 18; i++) dot[i] = 0.f;
  const float* wr = dict + k * 128;
  for (int c = 0; c < 128; c++) {
    float wv = wr[c];
    const float* zr = &zl[c * 36 + pg * 18];
#pragma unroll
    for (int i = 0; i < 18; i++) dot[i] += zr[i] * wv;
  }
  float wn = w2n[k];
#pragma unroll
  for (int i = 0; i < 18; i++) d2[(pg * 18 + i) * 129 + k] = wn - 2.f * dot[i];
  __syncthreads();
  if (t < 36) {
    const float* dr = &d2[t * 129];
    float best = dr[0];
    int bi = 0;
    for (int kk = 1; kk < 128; kk++) {
      float v = dr[kk];
      if (v > best) { best = v; bi = kk; }  // strict >: first max (argmax tie)
    }
    bk[t] = bi;
    out_idx[n * 36 + t] = (float)bi;
  }
  __syncthreads();
  float* vn = val + (size_t)n * 4608;
  for (int e = t; e < 4608; e += 256) {
    int c = e / 36, p = e % 36;
    vn[e] = dict[bk[p] * 128 + c];
  }
}

// ---------------- bf16 MFMA deconv (stride 1), optional fused mu ------------
// Weights direct from global per tap (no LDS, no per-tap barriers).
template <int IH, int IW, int OH, int OW, int K, int TR, bool MU_FUSE>
__global__ __launch_bounds__(256, 2) void deconv_mfma(
    const float* __restrict__ in, const ushort* __restrict__ wprep,
    const float* __restrict__ bias, const float* __restrict__ mw,
    float* __restrict__ out) {
  constexpr int PAD = K - 1;
  constexpr int PW = IW + 2 * PAD;
  constexpr int K2 = K * K;
  constexpr int SROWS = TR + K - 1;
  constexpr int S = SROWS * PW;
  constexpr int NPOS = TR * OW;
  constexpr int NCH = (NPOS + 15) / 16;
  constexpr int PITCH = 40;
  const int n = blockIdx.x;
  const int r0 = blockIdx.y * TR;
  __shared__ __align__(16) ushort lin[S * PITCH];
  const int t = threadIdx.x;
  const int wv = t >> 6;
  const int lane = t & 63;
  const int nn = lane & 15;
  const int q = lane >> 4;
  f32x4 acc0[NCH], acc1[NCH];
  int base[NCH];
#pragma unroll
  for (int c = 0; c < NCH; c++) {
    acc0[c] = f32x4{0.f, 0.f, 0.f, 0.f};
    acc1[c] = f32x4{0.f, 0.f, 0.f, 0.f};
    int p = c * 16 + nn;
    int pc = p < NPOS ? p : NPOS - 1;
    base[c] = (pc / OW) * PW + (pc % OW);
  }
  const float* inN = in + (size_t)n * 128 * IH * IW;
  for (int cb = 0; cb < 4; cb++) {
    const int ci0 = cb * 32;
    __syncthreads();
    for (int e = t; e < 32 * S; e += 256) {
      int ci = e / S, sp = e - ci * S;
      int rr = sp / PW, cc = sp - rr * PW;
      int ir = r0 + rr - PAD, ic = cc - PAD;
      float v = 0.f;
      if (ir >= 0 && ir < IH && ic >= 0 && ic < IW)
        v = inN[(size_t)(ci0 + ci) * (IH * IW) + ir * IW + ic];
      lin[sp * PITCH + ci] = f2bf(v);
    }
    __syncthreads();
    for (int tap = 0; tap < K2; tap++) {
      const int ky = tap / K, kx = tap - ky * K;
      const int toff = ky * PW + kx;
      s16x8 a0 = *(const s16x8*)&wprep[((size_t)tap * 128 + wv * 16 + nn) * 128 +
                                       ci0 + q * 8];
      s16x8 a1 = *(const s16x8*)&wprep[((size_t)tap * 128 + (wv + 4) * 16 + nn) *
                                           128 +
                                       ci0 + q * 8];
#pragma unroll
      for (int c = 0; c < NCH; c++) {
        s16x8 b = *(const s16x8*)&lin[(base[c] + toff) * PITCH + q * 8];
        acc0[c] =
            __builtin_amdgcn_mfma_f32_16x16x32_bf16(a0, b, acc0[c], 0, 0, 0);
        acc1[c] =
            __builtin_amdgcn_mfma_f32_16x16x32_bf16(a1, b, acc1[c], 0, 0, 0);
      }
    }
  }
  const int co_a = wv * 16 + q * 4;
  const int co_b = (wv + 4) * 16 + q * 4;
  float ba[4], bb[4];
#pragma unroll
  for (int r = 0; r < 4; r++) {
    ba[r] = bias[co_a + r];
    bb[r] = bias[co_b + r];
  }
  if (!MU_FUSE) {
#pragma unroll
    for (int c = 0; c < NCH; c++) {
      int p = c * 16 + nn;
      if (p < NPOS) {
        float* oa = out + ((size_t)n * 128 + co_a) * (OH * OW) + r0 * OW + p;
        float* ob = out + ((size_t)n * 128 + co_b) * (OH * OW) + r0 * OW + p;
#pragma unroll
        for (int r = 0; r < 4; r++) {
          oa[(size_t)r * OH * OW] = fmaxf(acc0[c][r] + ba[r], 0.f);
          ob[(size_t)r * OH * OW] = fmaxf(acc1[c][r] + bb[r], 0.f);
        }
      }
    }
  } else {
    float wa[4], wb[4];
#pragma unroll
    for (int r = 0; r < 4; r++) {
      wa[r] = mw[co_a + r];
      wb[r] = mw[co_b + r];
    }
#pragma unroll
    for (int c = 0; c < NCH; c++) {
      int p = c * 16 + nn;
      float s = 0.f;
#pragma unroll
      for (int r = 0; r < 4; r++) {
        s += fmaxf(acc0[c][r] + ba[r], 0.f) * wa[r];
        s += fmaxf(acc1[c][r] + bb[r], 0.f) * wb[r];
      }
      s += __shfl_xor(s, 16);
      s += __shfl_xor(s, 32);
      if (q == 0 && p < NPOS)
        atomicAdd(&out[(size_t)n * (OH * OW) + r0 * OW + p], s);
    }
  }
}

// ---------------- deconv k=4 stride=2: (B,128,9,9)->(B,128,20,20), ReLU -----
__global__ __launch_bounds__(320) void deconv_s2_kernel(
    const float* __restrict__ in, const float* __restrict__ w,
    const float* __restrict__ bias, float* __restrict__ out) {
  constexpr int CI_L = 16;
  constexpr int LWS = pad_lw(16 * 16);  // 258
  const int n = blockIdx.x >> 3;
  const int co0 = (blockIdx.x & 7) * 16;
  __shared__ __align__(16) float lin[CI_L * 9 * 12];
  __shared__ float lw[16 * LWS];
  const int t = threadIdx.x;  // 320 = 16 co x 20 rows
  const int co_l = t / 20, oy = t % 20;
  float acc[20];
#pragma unroll
  for (int i = 0; i < 20; i++) acc[i] = 0.f;
  const float* inN = in + (size_t)n * 128 * 81;
  for (int ci0 = 0; ci0 < 128; ci0 += CI_L) {
    __syncthreads();
    for (int e = t; e < CI_L * 108; e += 320) {
      int ci = e / 108, rem = e % 108, r = rem / 12, c = rem % 12;
      lin[e] = (c < 9) ? inN[(size_t)(ci0 + ci) * 81 + r * 9 + c] : 0.f;
    }
    for (int e = t; e < 16 * CI_L * 16; e += 320) {
      int col = e / (CI_L * 16), rem = e % (CI_L * 16);
      int cil = rem / 16, tap = rem % 16;
      lw[col * LWS + rem] =
          w[((size_t)(ci0 + cil) * 128 + co0 + col) * 16 + tap];
    }
    __syncthreads();
    const int par = oy & 1;
    const float* lwc = &lw[co_l * LWS];
    for (int ci = 0; ci < CI_L; ci++) {
#pragma unroll
      for (int tyi = 0; tyi < 2; tyi++) {
        int ty = par + 2 * tyi;
        int iy = (oy - ty) / 2;
        if (iy >= 0 && iy < 9) {
          float r[12];
          const float4* src = (const float4*)&lin[ci * 108 + iy * 12];
#pragma unroll
          for (int x4 = 0; x4 < 3; x4++) {
            float4 v = src[x4];
            r[4 * x4 + 0] = v.x; r[4 * x4 + 1] = v.y;
            r[4 * x4 + 2] = v.z; r[4 * x4 + 3] = v.w;
          }
#pragma unroll
          for (int tx = 0; tx < 4; tx++) {
            float wv = lwc[ci * 16 + ty * 4 + tx];
#pragma unroll
            for (int ox = 0; ox < 20; ox++) {
              if (((ox - tx) % 2) == 0) {
                int ix = (ox - tx) / 2;
                if (ix >= 0 && ix < 9) acc[ox] += r[ix] * wv;
              }
            }
          }
        }
      }
    }
  }
  float bv = bias[co0 + co_l];
  float* o = out + ((size_t)n * 128 + co0 + co_l) * 400 + oy * 20;
#pragma unroll
  for (int ox = 0; ox < 20; ox++) o[ox] = fmaxf(acc[ox] + bv, 0.f);
}

// ---------------- rec loss: mean((mu + mb - x)^2) ---------------------------
__global__ __launch_bounds__(256) void rec_loss_kernel(
    const float* __restrict__ mu, const float* __restrict__ mb,
    const float* __restrict__ x, float* __restrict__ out) {
  const int t = threadIdx.x;
  const int i = blockIdx.x * 256 + t;
  __shared__ float red[256];
  float d = mu[i] + mb[0] - x[i];
  red[t] = d * d;
  __syncthreads();
  for (int off = 128; off > 0; off >>= 1) {
    if (t < off) red[t] += red[t + off];
    __syncthreads();
  }
  if (t == 0) atomicAdd(out, red[0] * (1.0f / 200704.f));
}

// ---------------- dict / enc losses: sum (val - z)^2 ------------------------
__global__ __launch_bounds__(256) void vq_loss_kernel(
    const float4* __restrict__ val4, const float4* __restrict__ z4,
    float* __restrict__ out) {
  const int t = threadIdx.x;
  const int i = blockIdx.x * 256 + t;
  __shared__ float red[256];
  float4 a = val4[i], b = z4[i];
  float dx = a.x - b.x, dy = a.y - b.y, dz = a.z - b.z, dw = a.w - b.w;
  red[t] = dx * dx + dy * dy + dz * dz + dw * dw;
  __syncthreads();
  for (int off = 128; off > 0; off >>= 1) {
    if (t < off) red[t] += red[t + off];
    __syncthreads();
  }
  if (t == 0) {
    atomicAdd(out + 1, red[0] * (5.f / 1179648.f));
    atomicAdd(out + 2, red[0] * (1.25f / 1179648.f));
  }
}

// ---------------------------------------------------------------------------
extern "C" void kernel_launch(void* const* d_in, const int* in_sizes, int n_in,
                              void* d_out, int out_size, void* d_ws,
                              size_t ws_size, hipStream_t stream) {
  const float* x = (const float*)d_in[0];
  const float* w1 = (const float*)d_in[1];
  const float* b1 = (const float*)d_in[2];
  const float* w2 = (const float*)d_in[3];
  const float* b2 = (const float*)d_in[4];
  const float* w3 = (const float*)d_in[5];
  const float* b3 = (const float*)d_in[6];
  const float* t1w = (const float*)d_in[7];
  const float* t1b = (const float*)d_in[8];
  const float* t2w = (const float*)d_in[9];
  const float* t2b = (const float*)d_in[10];
  const float* t3w = (const float*)d_in[11];
  const float* t3b = (const float*)d_in[12];
  const float* t4w = (const float*)d_in[13];
  const float* t4b = (const float*)d_in[14];
  const float* mw = (const float*)d_in[15];
  const float* mb = (const float*)d_in[16];
  const float* dictw = (const float*)d_in[17];
  float* out = (float*)d_out;

  float* ws = (float*)d_ws;
  float* bufA = ws;               // h1 -> f1 -> f3
  float* bufB = bufA + 18874368;  // p1 -> f2
  float* z = bufB + 13107200;
  float* val = z + 1179648;
  float* mu = val + 1179648;  // 200,704
  ushort* wp1 = (ushort*)(mu + 200704);
  ushort* wp3 = wp1 + 16 * 16384;
  ushort* wp4 = wp3 + 25 * 16384;
  _Float16* w2h = (_Float16*)(wp4 + 25 * 16384);
  _Float16* w2l = w2h + 25 * 16384;
  _Float16* w3h = w2l + 25 * 16384;
  _Float16* w3l = w3h + 25 * 16384;
  float* h1 = bufA;
  float* p1 = bufB;
  float* f1 = bufA;
  float* f2 = bufB;
  float* f3 = bufA;

  hipMemsetAsync(d_out, 0, 4 * sizeof(float), stream);
  hipMemsetAsync(mu, 0, 200704 * sizeof(float), stream);

  // weight prep
  prep_w<<<16 * 64, 256, 0, stream>>>(t1w, wp1, 16);
  prep_w<<<25 * 64, 256, 0, stream>>>(t3w, wp3, 25);
  prep_w<<<25 * 64, 256, 0, stream>>>(t4w, wp4, 25);
  prep_w_split<<<25 * 64, 256, 0, stream>>>(w2, w2h, w2l, 25);
  prep_w_split<<<25 * 64, 256, 0, stream>>>(w3, w3h, w3l, 25);

  conv1_kernel<<<B_, 256, 0, stream>>>(x, w1, b1, h1);
  // conv2: 24x24 K5 pad2 relu + pool -> p1 (12x12)  [split-fp16 MFMA]
  conv_mfma_pool<24, 5, 2, 8, 3, true>
      <<<dim3(B_, 3), 256, 0, stream>>>(h1, w2h, w2l, b2, p1);
  // conv3: 12x12 K5 pad2 + pool -> z (6x6)  [split-fp16 MFMA]
  conv_mfma_pool<12, 5, 2, 12, 3, false>
      <<<dim3(B_, 1), 256, 0, stream>>>(p1, w3h, w3l, b3, z);
  vq_kernel<<<B_, 256, 0, stream>>>(z, dictw, val, out + 4);
  // t1: 6->9, K4 (deconv s1), relu  [bf16 MFMA]
  deconv_mfma<6, 6, 9, 9, 4, 9, false>
      <<<dim3(B_, 1), 256, 0, stream>>>(val, wp1, t1b, nullptr, f1);
  // t2: 9->20, K4 s2, relu  [f32]
  deconv_s2_kernel<<<B_ * 8, 320, 0, stream>>>(f1, t2w, t2b, f2);
  // t3: 20->24, K5 (deconv s1), relu  [bf16 MFMA]
  deconv_mfma<20, 20, 24, 24, 5, 8, false>
      <<<dim3(B_, 3), 256, 0, stream>>>(f2, wp3, t3b, nullptr, f3);
  // t4: 24->28, K5 (deconv s1), relu + fused 1x1 mu  [bf16 MFMA]
  deconv_mfma<24, 24, 28, 28, 5, 7, true>
      <<<dim3(B_, 4), 256, 0, stream>>>(f3, wp4, t4b, mw, mu);
  rec_loss_kernel<<<784, 256, 0, stream>>>(mu, mb, x, out);
  vq_loss_kernel<<<1152, 256, 0, stream>>>((const float4*)val, (const float4*)z,
                                           out);
}

// Round 7
// 1414.582 us; speedup vs baseline: 13.2253x; 1.3616x over previous
//
#include <hip/hip_runtime.h>
#include <hip/hip_bf16.h>

// ---------------------------------------------------------------------------
// VQ-VAE forward.
//  - conv1 f32 (tiny); conv2/conv3 split-fp16 MFMA (hi/lo, 3 MFMAs/product,
//    ~2^-22 rel err => index-exact) + fused bias(+relu)+2x2 maxpool.
//  - R7: wave = 2 co-tiles x ALL pos-chunks (4 weight loads/tap, was 16),
//    explicit next-tap weight prefetch into regs, pool scratch overlays the
//    input LDS (union) -> 44.8 KB smem -> 3 blocks/CU.
//  - VQ argmax faithful f32.
//  - decoder t1/t3/t4 bf16 MFMA (+ same weight prefetch); t2 f32 direct;
//    t4 fused with 1x1 mu conv (shfl reduce + atomicAdd).
// ---------------------------------------------------------------------------

#define B_ 256

typedef __attribute__((ext_vector_type(8))) short s16x8;
typedef __attribute__((ext_vector_type(8))) _Float16 f16x8;
typedef __attribute__((ext_vector_type(4))) float f32x4;

__device__ inline ushort f2bf(float f) {
  union { __hip_bfloat16 h; ushort u; } cv;
  cv.h = __float2bfloat16(f);
  return cv.u;
}

__host__ __device__ constexpr int pad_lw(int n) {  // == 2 (mod 4)
  return n + ((2 - (n & 3)) & 3);
}

// ------- decoder weight prep: (ci,co,K,K) f32 -> [tap][co][ci] bf16 flipped -
__global__ __launch_bounds__(256) void prep_w(const float* __restrict__ w,
                                              ushort* __restrict__ wp,
                                              int K2) {
  int idx = blockIdx.x * 256 + threadIdx.x;
  if (idx >= K2 * 16384) return;
  int ci = idx & 127;
  int co = (idx >> 7) & 127;
  int tap = idx >> 14;
  wp[idx] = f2bf(w[((size_t)ci * 128 + co) * K2 + (K2 - 1 - tap)]);
}

// ------- encoder weight prep: (co,ci,K,K) f32 -> [tap][co][ci] fp16 hi/lo ---
__global__ __launch_bounds__(256) void prep_w_split(const float* __restrict__ w,
                                                    _Float16* __restrict__ wh,
                                                    _Float16* __restrict__ wl,
                                                    int K2) {
  int idx = blockIdx.x * 256 + threadIdx.x;
  if (idx >= K2 * 16384) return;
  int ci = idx & 127;
  int co = (idx >> 7) & 127;
  int tap = idx >> 14;
  float v = w[((size_t)co * 128 + ci) * K2 + tap];
  _Float16 h = (_Float16)v;
  wh[idx] = h;
  wl[idx] = (_Float16)(v - (float)h);
}

// ---------------- conv1: (B,1,28,28) -> (B,128,24,24), 5x5, pad0, ReLU ------
__global__ __launch_bounds__(256) void conv1_kernel(
    const float* __restrict__ x, const float* __restrict__ w,
    const float* __restrict__ b, float* __restrict__ out) {
  const int n = blockIdx.x;
  __shared__ float xl[784];
  __shared__ float wl[128 * 25];
  __shared__ float bl[128];
  const int t = threadIdx.x;
  for (int e = t; e < 784; e += 256) xl[e] = x[n * 784 + e];
  for (int e = t; e < 3200; e += 256) wl[e] = w[e];
  if (t < 128) bl[t] = b[t];
  __syncthreads();
  float* on = out + (size_t)n * 128 * 576;
  for (int idx = t; idx < 128 * 576; idx += 256) {
    int co = idx / 576, p = idx % 576;
    int y = p / 24, xx = p % 24;
    float acc = bl[co];
    const float* wc = &wl[co * 25];
#pragma unroll
    for (int ky = 0; ky < 5; ky++)
#pragma unroll
      for (int kx = 0; kx < 5; kx++)
        acc += xl[(y + ky) * 28 + xx + kx] * wc[ky * 5 + kx];
    on[idx] = fmaxf(acc, 0.f);
  }
}

// ---------------- split-fp16 MFMA conv + bias(+relu) + 2x2 maxpool ----------
// Block 256 thr = 4 waves; wave owns co-tiles {wv, wv+4} x ALL NCH chunks.
// Weights: 4 b128 global loads per tap, prefetched one tap ahead.
// Pool scratch overlays lin after the last ci-block (union smem).
template <int IW, int K, int PAD, int TR, bool RELU>
__global__ __launch_bounds__(256, 3) void conv_mfma_pool(
    const float* __restrict__ in, const _Float16* __restrict__ wph,
    const _Float16* __restrict__ wpl, const float* __restrict__ bias,
    float* __restrict__ out) {
  constexpr int IH = IW, OW = IW, OH = IW;
  constexpr int PW = IW + 2 * PAD;
  constexpr int SROWS = TR + K - 1;
  constexpr int S = SROWS * PW;
  constexpr int NPOS = TR * OW;
  constexpr int NCH = NPOS / 16;
  constexpr int K2 = K * K;
  constexpr int PITCH = 40;  // f16 units; 80B rows, b128-aligned at q*8
  constexpr int LIN_ELT = S * PITCH;
  constexpr int LIN_BYTES = 2 * LIN_ELT * 2;       // hi+lo
  constexpr int SCR_BYTES = 64 * NPOS * 4;         // 4 waves x 16 co x NPOS
  constexpr int SMEM_BYTES = LIN_BYTES > SCR_BYTES ? LIN_BYTES : SCR_BYTES;
  static_assert(NPOS % 16 == 0, "chunks must tile NPOS");
  static_assert(TR % 2 == 0 && OW % 2 == 0, "pool needs even tile");
  __shared__ __align__(16) char smem[SMEM_BYTES];
  _Float16* linh = (_Float16*)smem;
  _Float16* linl = linh + LIN_ELT;
  const int n = blockIdx.x;
  const int r0 = blockIdx.y * TR;
  const int t = threadIdx.x;
  const int wv = t >> 6;
  const int lane = t & 63;
  const int nn = lane & 15;
  const int q = lane >> 4;
  f32x4 acc0[NCH], acc1[NCH];
#pragma unroll
  for (int c = 0; c < NCH; c++) {
    acc0[c] = f32x4{0.f, 0.f, 0.f, 0.f};
    acc1[c] = f32x4{0.f, 0.f, 0.f, 0.f};
  }
  int base[NCH];
#pragma unroll
  for (int c = 0; c < NCH; c++) {
    int p = c * 16 + nn;
    base[c] = (p / OW) * PW + (p % OW);
  }
  const float* inN = in + (size_t)n * 128 * IH * IW;
  const int rowA = wv * 16 + nn;        // co row, acc0 tile
  const int rowB = (wv + 4) * 16 + nn;  // co row, acc1 tile
  for (int cb = 0; cb < 4; cb++) {
    const int ci0 = cb * 32;
    __syncthreads();  // all waves done reading previous ci-block
    for (int e = t; e < 32 * S; e += 256) {
      int ci = e / S, sp = e - ci * S;
      int r = sp / PW, c = sp - r * PW;
      int ir = r0 + r - PAD, ic = c - PAD;
      float v = 0.f;
      if (ir >= 0 && ir < IH && ic >= 0 && ic < IW)
        v = inN[(size_t)(ci0 + ci) * (IH * IW) + ir * IW + ic];
      _Float16 h = (_Float16)v;
      linh[sp * PITCH + ci] = h;
      linl[sp * PITCH + ci] = (_Float16)(v - (float)h);
    }
    __syncthreads();
    const size_t gA = (size_t)rowA * 128 + ci0 + q * 8;
    const size_t gB = (size_t)rowB * 128 + ci0 + q * 8;
    f16x8 cah0 = *(const f16x8*)&wph[gA];
    f16x8 cal0 = *(const f16x8*)&wpl[gA];
    f16x8 cah1 = *(const f16x8*)&wph[gB];
    f16x8 cal1 = *(const f16x8*)&wpl[gB];
    for (int tap = 0; tap < K2; tap++) {
      f16x8 nah0 = cah0, nal0 = cal0, nah1 = cah1, nal1 = cal1;
      if (tap + 1 < K2) {  // prefetch next tap's weights
        size_t oA = gA + (size_t)(tap + 1) * 16384;
        size_t oB = gB + (size_t)(tap + 1) * 16384;
        nah0 = *(const f16x8*)&wph[oA];
        nal0 = *(const f16x8*)&wpl[oA];
        nah1 = *(const f16x8*)&wph[oB];
        nal1 = *(const f16x8*)&wpl[oB];
      }
      const int ky = tap / K, kx = tap - ky * K;
      const int toff = ky * PW + kx;
#pragma unroll
      for (int c = 0; c < NCH; c++) {
        f16x8 bh = *(const f16x8*)&linh[(base[c] + toff) * PITCH + q * 8];
        f16x8 bl = *(const f16x8*)&linl[(base[c] + toff) * PITCH + q * 8];
        acc0[c] =
            __builtin_amdgcn_mfma_f32_16x16x32_f16(cah0, bh, acc0[c], 0, 0, 0);
        acc0[c] =
            __builtin_amdgcn_mfma_f32_16x16x32_f16(cah0, bl, acc0[c], 0, 0, 0);
        acc0[c] =
            __builtin_amdgcn_mfma_f32_16x16x32_f16(cal0, bh, acc0[c], 0, 0, 0);
        acc1[c] =
            __builtin_amdgcn_mfma_f32_16x16x32_f16(cah1, bh, acc1[c], 0, 0, 0);
        acc1[c] =
            __builtin_amdgcn_mfma_f32_16x16x32_f16(cah1, bl, acc1[c], 0, 0, 0);
        acc1[c] =
            __builtin_amdgcn_mfma_f32_16x16x32_f16(cal1, bh, acc1[c], 0, 0, 0);
      }
      cah0 = nah0; cal0 = nal0; cah1 = nah1; cal1 = nal1;
    }
  }
  // epilogue: bias(+relu) -> per-wave scr (overlays lin) -> 2x2 pool -> out
  __syncthreads();  // everyone done with lin
  float* scr = (float*)smem + wv * 16 * NPOS;  // disjoint per wave
#pragma unroll
  for (int j = 0; j < 2; j++) {
    const int cot = (j ? wv + 4 : wv) * 16;
#pragma unroll
    for (int c = 0; c < NCH; c++) {
      f32x4 a = j ? acc1[c] : acc0[c];
#pragma unroll
      for (int r = 0; r < 4; r++) {
        float v = a[r] + bias[cot + q * 4 + r];
        if (RELU) v = fmaxf(v, 0.f);
        scr[(q * 4 + r) * NPOS + c * 16 + nn] = v;
      }
    }
    __syncthreads();
    for (int e = lane; e < 16 * (TR / 2) * (OW / 2); e += 64) {
      int co_l = e / ((TR / 2) * (OW / 2));
      int rem = e - co_l * ((TR / 2) * (OW / 2));
      int pr = rem / (OW / 2), pc = rem - pr * (OW / 2);
      const float* s = scr + co_l * NPOS;
      int lp = (2 * pr) * OW + 2 * pc;
      float m =
          fmaxf(fmaxf(s[lp], s[lp + 1]), fmaxf(s[lp + OW], s[lp + OW + 1]));
      out[((size_t)n * 128 + cot + co_l) * (OH / 2) * (OW / 2) +
          (r0 / 2 + pr) * (OW / 2) + pc] = m;
    }
    __syncthreads();
  }
}

// ---------------- VQ: distances, argmax(d2) [faithful], gather --------------
__global__ __launch_bounds__(256) void vq_kernel(
    const float* __restrict__ z, const float* __restrict__ dict,
    float* __restrict__ val, float* __restrict__ out_idx) {
  const int n = blockIdx.x;
  __shared__ float zl[128 * 36];
  __shared__ float d2[36 * 129];
  __shared__ float w2n[128];
  __shared__ int bk[36];
  const int t = threadIdx.x;
  const float* zn = z + (size_t)n * 4608;
  for (int e = t; e < 4608; e += 256) zl[e] = zn[e];
  if (t < 128) {
    float s = 0.f;
    const float* wr = dict + t * 128;
    for (int c = 0; c < 128; c++) s += wr[c] * wr[c];
    w2n[t] = s;
  }
  __syncthreads();
  const int k = t & 127, pg = t >> 7;
  float dot[18];
#pragma unroll
  for (int i = 0; i < 18; i++) dot[i] = 0.f;
  const float* wr = dict + k * 128;
  for (int c = 0; c < 128; c++) {
    float wv = wr[c];
    const float* zr = &zl[c * 36 + pg * 18];
#pragma unroll
    for (int i = 0; i < 18; i++) dot[i] += zr[i] * wv;
  }
  float wn = w2n[k];
#pragma unroll
  for (int i = 0; i < 18; i++) d2[(pg * 18 + i) * 129 + k] = wn - 2.f * dot[i];
  __syncthreads();
  if (t < 36) {
    const float* dr = &d2[t * 129];
    float best = dr[0];
    int bi = 0;
    for (int kk = 1; kk < 128; kk++) {
      float v = dr[kk];
      if (v > best) { best = v; bi = kk; }  // strict >: first max (argmax tie)
    }
    bk[t] = bi;
    out_idx[n * 36 + t] = (float)bi;
  }
  __syncthreads();
  float* vn = val + (size_t)n * 4608;
  for (int e = t; e < 4608; e += 256) {
    int c = e / 36, p = e % 36;
    vn[e] = dict[bk[p] * 128 + c];
  }
}

// ---------------- bf16 MFMA deconv (stride 1), optional fused mu ------------
// Weights direct from global per tap, prefetched one tap ahead.
template <int IH, int IW, int OH, int OW, int K, int TR, bool MU_FUSE>
__global__ __launch_bounds__(256, 2) void deconv_mfma(
    const float* __restrict__ in, const ushort* __restrict__ wprep,
    const float* __restrict__ bias, const float* __restrict__ mw,
    float* __restrict__ out) {
  constexpr int PAD = K - 1;
  constexpr int PW = IW + 2 * PAD;
  constexpr int K2 = K * K;
  constexpr int SROWS = TR + K - 1;
  constexpr int S = SROWS * PW;
  constexpr int NPOS = TR * OW;
  constexpr int NCH = (NPOS + 15) / 16;
  constexpr int PITCH = 40;
  const int n = blockIdx.x;
  const int r0 = blockIdx.y * TR;
  __shared__ __align__(16) ushort lin[S * PITCH];
  const int t = threadIdx.x;
  const int wv = t >> 6;
  const int lane = t & 63;
  const int nn = lane & 15;
  const int q = lane >> 4;
  f32x4 acc0[NCH], acc1[NCH];
  int base[NCH];
#pragma unroll
  for (int c = 0; c < NCH; c++) {
    acc0[c] = f32x4{0.f, 0.f, 0.f, 0.f};
    acc1[c] = f32x4{0.f, 0.f, 0.f, 0.f};
    int p = c * 16 + nn;
    int pc = p < NPOS ? p : NPOS - 1;
    base[c] = (pc / OW) * PW + (pc % OW);
  }
  const float* inN = in + (size_t)n * 128 * IH * IW;
  for (int cb = 0; cb < 4; cb++) {
    const int ci0 = cb * 32;
    __syncthreads();
    for (int e = t; e < 32 * S; e += 256) {
      int ci = e / S, sp = e - ci * S;
      int rr = sp / PW, cc = sp - rr * PW;
      int ir = r0 + rr - PAD, ic = cc - PAD;
      float v = 0.f;
      if (ir >= 0 && ir < IH && ic >= 0 && ic < IW)
        v = inN[(size_t)(ci0 + ci) * (IH * IW) + ir * IW + ic];
      lin[sp * PITCH + ci] = f2bf(v);
    }
    __syncthreads();
    const size_t gA = (size_t)(wv * 16 + nn) * 128 + ci0 + q * 8;
    const size_t gB = (size_t)((wv + 4) * 16 + nn) * 128 + ci0 + q * 8;
    s16x8 ca0 = *(const s16x8*)&wprep[gA];
    s16x8 ca1 = *(const s16x8*)&wprep[gB];
    for (int tap = 0; tap < K2; tap++) {
      s16x8 na0 = ca0, na1 = ca1;
      if (tap + 1 < K2) {  // prefetch next tap
        na0 = *(const s16x8*)&wprep[gA + (size_t)(tap + 1) * 16384];
        na1 = *(const s16x8*)&wprep[gB + (size_t)(tap + 1) * 16384];
      }
      const int ky = tap / K, kx = tap - ky * K;
      const int toff = ky * PW + kx;
#pragma unroll
      for (int c = 0; c < NCH; c++) {
        s16x8 b = *(const s16x8*)&lin[(base[c] + toff) * PITCH + q * 8];
        acc0[c] =
            __builtin_amdgcn_mfma_f32_16x16x32_bf16(ca0, b, acc0[c], 0, 0, 0);
        acc1[c] =
            __builtin_amdgcn_mfma_f32_16x16x32_bf16(ca1, b, acc1[c], 0, 0, 0);
      }
      ca0 = na0; ca1 = na1;
    }
  }
  const int co_a = wv * 16 + q * 4;
  const int co_b = (wv + 4) * 16 + q * 4;
  float ba[4], bb[4];
#pragma unroll
  for (int r = 0; r < 4; r++) {
    ba[r] = bias[co_a + r];
    bb[r] = bias[co_b + r];
  }
  if (!MU_FUSE) {
#pragma unroll
    for (int c = 0; c < NCH; c++) {
      int p = c * 16 + nn;
      if (p < NPOS) {
        float* oa = out + ((size_t)n * 128 + co_a) * (OH * OW) + r0 * OW + p;
        float* ob = out + ((size_t)n * 128 + co_b) * (OH * OW) + r0 * OW + p;
#pragma unroll
        for (int r = 0; r < 4; r++) {
          oa[(size_t)r * OH * OW] = fmaxf(acc0[c][r] + ba[r], 0.f);
          ob[(size_t)r * OH * OW] = fmaxf(acc1[c][r] + bb[r], 0.f);
        }
      }
    }
  } else {
    float wa[4], wb[4];
#pragma unroll
    for (int r = 0; r < 4; r++) {
      wa[r] = mw[co_a + r];
      wb[r] = mw[co_b + r];
    }
#pragma unroll
    for (int c = 0; c < NCH; c++) {
      int p = c * 16 + nn;
      float s = 0.f;
#pragma unroll
      for (int r = 0; r < 4; r++) {
        s += fmaxf(acc0[c][r] + ba[r], 0.f) * wa[r];
        s += fmaxf(acc1[c][r] + bb[r], 0.f) * wb[r];
      }
      s += __shfl_xor(s, 16);
      s += __shfl_xor(s, 32);
      if (q == 0 && p < NPOS)
        atomicAdd(&out[(size_t)n * (OH * OW) + r0 * OW + p], s);
    }
  }
}

// ---------------- deconv k=4 stride=2: (B,128,9,9)->(B,128,20,20), ReLU -----
__global__ __launch_bounds__(320) void deconv_s2_kernel(
    const float* __restrict__ in, const float* __restrict__ w,
    const float* __restrict__ bias, float* __restrict__ out) {
  constexpr int CI_L = 16;
  constexpr int LWS = pad_lw(16 * 16);  // 258
  const int n = blockIdx.x >> 3;
  const int co0 = (blockIdx.x & 7) * 16;
  __shared__ __align__(16) float lin[CI_L * 9 * 12];
  __shared__ float lw[16 * LWS];
  const int t = threadIdx.x;  // 320 = 16 co x 20 rows
  const int co_l = t / 20, oy = t % 20;
  float acc[20];
#pragma unroll
  for (int i = 0; i < 20; i++) acc[i] = 0.f;
  const float* inN = in + (size_t)n * 128 * 81;
  for (int ci0 = 0; ci0 < 128; ci0 += CI_L) {
    __syncthreads();
    for (int e = t; e < CI_L * 108; e += 320) {
      int ci = e / 108, rem = e % 108, r = rem / 12, c = rem % 12;
      lin[e] = (c < 9) ? inN[(size_t)(ci0 + ci) * 81 + r * 9 + c] : 0.f;
    }
    for (int e = t; e < 16 * CI_L * 16; e += 320) {
      int col = e / (CI_L * 16), rem = e % (CI_L * 16);
      int cil = rem / 16, tap = rem % 16;
      lw[col * LWS + rem] =
          w[((size_t)(ci0 + cil) * 128 + co0 + col) * 16 + tap];
    }
    __syncthreads();
    const int par = oy & 1;
    const float* lwc = &lw[co_l * LWS];
    for (int ci = 0; ci < CI_L; ci++) {
#pragma unroll
      for (int tyi = 0; tyi < 2; tyi++) {
        int ty = par + 2 * tyi;
        int iy = (oy - ty) / 2;
        if (iy >= 0 && iy < 9) {
          float r[12];
          const float4* src = (const float4*)&lin[ci * 108 + iy * 12];
#pragma unroll
          for (int x4 = 0; x4 < 3; x4++) {
            float4 v = src[x4];
            r[4 * x4 + 0] = v.x; r[4 * x4 + 1] = v.y;
            r[4 * x4 + 2] = v.z; r[4 * x4 + 3] = v.w;
          }
#pragma unroll
          for (int tx = 0; tx < 4; tx++) {
            float wv = lwc[ci * 16 + ty * 4 + tx];
#pragma unroll
            for (int ox = 0; ox < 20; ox++) {
              if (((ox - tx) % 2) == 0) {
                int ix = (ox - tx) / 2;
                if (ix >= 0 && ix < 9) acc[ox] += r[ix] * wv;
              }
            }
          }
        }
      }
    }
  }
  float bv = bias[co0 + co_l];
  float* o = out + ((size_t)n * 128 + co0 + co_l) * 400 + oy * 20;
#pragma unroll
  for (int ox = 0; ox < 20; ox++) o[ox] = fmaxf(acc[ox] + bv, 0.f);
}

// ---------------- rec loss: mean((mu + mb - x)^2) ---------------------------
__global__ __launch_bounds__(256) void rec_loss_kernel(
    const float* __restrict__ mu, const float* __restrict__ mb,
    const float* __restrict__ x, float* __restrict__ out) {
  const int t = threadIdx.x;
  const int i = blockIdx.x * 256 + t;
  __shared__ float red[256];
  float d = mu[i] + mb[0] - x[i];
  red[t] = d * d;
  __syncthreads();
  for (int off = 128; off > 0; off >>= 1) {
    if (t < off) red[t] += red[t + off];
    __syncthreads();
  }
  if (t == 0) atomicAdd(out, red[0] * (1.0f / 200704.f));
}

// ---------------- dict / enc losses: sum (val - z)^2 ------------------------
__global__ __launch_bounds__(256) void vq_loss_kernel(
    const float4* __restrict__ val4, const float4* __restrict__ z4,
    float* __restrict__ out) {
  const int t = threadIdx.x;
  const int i = blockIdx.x * 256 + t;
  __shared__ float red[256];
  float4 a = val4[i], b = z4[i];
  float dx = a.x - b.x, dy = a.y - b.y, dz = a.z - b.z, dw = a.w - b.w;
  red[t] = dx * dx + dy * dy + dz * dz + dw * dw;
  __syncthreads();
  for (int off = 128; off > 0; off >>= 1) {
    if (t < off) red[t] += red[t + off];
    __syncthreads();
  }
  if (t == 0) {
    atomicAdd(out + 1, red[0] * (5.f / 1179648.f));
    atomicAdd(out + 2, red[0] * (1.25f / 1179648.f));
  }
}

// ---------------------------------------------------------------------------
extern "C" void kernel_launch(void* const* d_in, const int* in_sizes, int n_in,
                              void* d_out, int out_size, void* d_ws,
                              size_t ws_size, hipStream_t stream) {
  const float* x = (const float*)d_in[0];
  const float* w1 = (const float*)d_in[1];
  const float* b1 = (const float*)d_in[2];
  const float* w2 = (const float*)d_in[3];
  const float* b2 = (const float*)d_in[4];
  const float* w3 = (const float*)d_in[5];
  const float* b3 = (const float*)d_in[6];
  const float* t1w = (const float*)d_in[7];
  const float* t1b = (const float*)d_in[8];
  const float* t2w = (const float*)d_in[9];
  const float* t2b = (const float*)d_in[10];
  const float* t3w = (const float*)d_in[11];
  const float* t3b = (const float*)d_in[12];
  const float* t4w = (const float*)d_in[13];
  const float* t4b = (const float*)d_in[14];
  const float* mw = (const float*)d_in[15];
  const float* mb = (const float*)d_in[16];
  const float* dictw = (const float*)d_in[17];
  float* out = (float*)d_out;

  float* ws = (float*)d_ws;
  float* bufA = ws;               // h1 -> f1 -> f3
  float* bufB = bufA + 18874368;  // p1 -> f2
  float* z = bufB + 13107200;
  float* val = z + 1179648;
  float* mu = val + 1179648;  // 200,704
  ushort* wp1 = (ushort*)(mu + 200704);
  ushort* wp3 = wp1 + 16 * 16384;
  ushort* wp4 = wp3 + 25 * 16384;
  _Float16* w2h = (_Float16*)(wp4 + 25 * 16384);
  _Float16* w2l = w2h + 25 * 16384;
  _Float16* w3h = w2l + 25 * 16384;
  _Float16* w3l = w3h + 25 * 16384;
  float* h1 = bufA;
  float* p1 = bufB;
  float* f1 = bufA;
  float* f2 = bufB;
  float* f3 = bufA;

  hipMemsetAsync(d_out, 0, 4 * sizeof(float), stream);
  hipMemsetAsync(mu, 0, 200704 * sizeof(float), stream);

  // weight prep
  prep_w<<<16 * 64, 256, 0, stream>>>(t1w, wp1, 16);
  prep_w<<<25 * 64, 256, 0, stream>>>(t3w, wp3, 25);
  prep_w<<<25 * 64, 256, 0, stream>>>(t4w, wp4, 25);
  prep_w_split<<<25 * 64, 256, 0, stream>>>(w2, w2h, w2l, 25);
  prep_w_split<<<25 * 64, 256, 0, stream>>>(w3, w3h, w3l, 25);

  conv1_kernel<<<B_, 256, 0, stream>>>(x, w1, b1, h1);
  // conv2: 24x24 K5 pad2 relu + pool -> p1 (12x12)  [split-fp16 MFMA, TR=6]
  conv_mfma_pool<24, 5, 2, 6, true>
      <<<dim3(B_, 4), 256, 0, stream>>>(h1, w2h, w2l, b2, p1);
  // conv3: 12x12 K5 pad2 + pool -> z (6x6)  [split-fp16 MFMA, TR=4]
  conv_mfma_pool<12, 5, 2, 4, false>
      <<<dim3(B_, 3), 256, 0, stream>>>(p1, w3h, w3l, b3, z);
  vq_kernel<<<B_, 256, 0, stream>>>(z, dictw, val, out + 4);
  // t1: 6->9, K4 (deconv s1), relu  [bf16 MFMA]
  deconv_mfma<6, 6, 9, 9, 4, 9, false>
      <<<dim3(B_, 1), 256, 0, stream>>>(val, wp1, t1b, nullptr, f1);
  // t2: 9->20, K4 s2, relu  [f32]
  deconv_s2_kernel<<<B_ * 8, 320, 0, stream>>>(f1, t2w, t2b, f2);
  // t3: 20->24, K5 (deconv s1), relu  [bf16 MFMA]
  deconv_mfma<20, 20, 24, 24, 5, 8, false>
      <<<dim3(B_, 3), 256, 0, stream>>>(f2, wp3, t3b, nullptr, f3);
  // t4: 24->28, K5 (deconv s1), relu + fused 1x1 mu  [bf16 MFMA]
  deconv_mfma<24, 24, 28, 28, 5, 7, true>
      <<<dim3(B_, 4), 256, 0, stream>>>(f3, wp4, t4b, mw, mu);
  rec_loss_kernel<<<784, 256, 0, stream>>>(mu, mb, x, out);
  vq_loss_kernel<<<1152, 256, 0, stream>>>((const float4*)val, (const float4*)z,
                                           out);
}

// Round 8
// 1157.016 us; speedup vs baseline: 16.1694x; 1.2226x over previous
//
#include <hip/hip_runtime.h>
#include <hip/hip_bf16.h>

// ---------------------------------------------------------------------------
// VQ-VAE forward.
//  - conv1 f32 (tiny); conv2/conv3 split-fp16 MFMA (hi/lo, 3 MFMAs/product,
//    ~2^-22 rel err => index-exact) + fused bias(+relu)+2x2 maxpool.
//  - VQ argmax faithful f32 (writes val f32 for losses + val_bf bf16 for t1).
//  - Decoder fully bf16 MFMA, activations bf16 end-to-end:
//      t1 (K4 s1), t2 (K4 s2 via 4-parity decomposition into K2 s1 convs),
//      t3/t4 (K5 s1), t4 fused with 1x1 mu conv (shfl + atomicAdd, f32 mu).
//  - Weights direct from global per tap (L2-hot), prefetched one tap ahead.
// ---------------------------------------------------------------------------

#define B_ 256

typedef __attribute__((ext_vector_type(8))) short s16x8;
typedef __attribute__((ext_vector_type(8))) _Float16 f16x8;
typedef __attribute__((ext_vector_type(4))) float f32x4;

__device__ inline ushort f2bf(float f) {
  union { __hip_bfloat16 h; ushort u; } cv;
  cv.h = __float2bfloat16(f);
  return cv.u;
}

__host__ __device__ constexpr int pad_lw(int n) {
  return n + ((2 - (n & 3)) & 3);
}

// ------- decoder weight prep: (ci,co,K,K) f32 -> [tap][co][ci] bf16 flipped -
__global__ __launch_bounds__(256) void prep_w(const float* __restrict__ w,
                                              ushort* __restrict__ wp,
                                              int K2) {
  int idx = blockIdx.x * 256 + threadIdx.x;
  if (idx >= K2 * 16384) return;
  int ci = idx & 127;
  int co = (idx >> 7) & 127;
  int tap = idx >> 14;
  wp[idx] = f2bf(w[((size_t)ci * 128 + co) * K2 + (K2 - 1 - tap)]);
}

// ------- t2 (k4 s2) weight prep: [parity][u,v][co][ci] bf16 -----------------
// out[2ry+py][2rx+px] = sum_{u,v} in[ry-u][rx-v] * w[ci][co][py+2u][px+2v]
__global__ __launch_bounds__(256) void prep_w_s2(const float* __restrict__ w,
                                                 ushort* __restrict__ wp) {
  int idx = blockIdx.x * 256 + threadIdx.x;  // 4*4*16384
  int ci = idx & 127;
  int co = (idx >> 7) & 127;
  int tap = (idx >> 14) & 3;
  int pp = idx >> 16;
  int u = tap >> 1, v = tap & 1;
  int py = pp >> 1, px = pp & 1;
  wp[idx] = f2bf(w[(((size_t)ci * 128 + co) * 4 + (py + 2 * u)) * 4 + (px + 2 * v)]);
}

// ------- encoder weight prep: (co,ci,K,K) f32 -> [tap][co][ci] fp16 hi/lo ---
__global__ __launch_bounds__(256) void prep_w_split(const float* __restrict__ w,
                                                    _Float16* __restrict__ wh,
                                                    _Float16* __restrict__ wl,
                                                    int K2) {
  int idx = blockIdx.x * 256 + threadIdx.x;
  if (idx >= K2 * 16384) return;
  int ci = idx & 127;
  int co = (idx >> 7) & 127;
  int tap = idx >> 14;
  float v = w[((size_t)co * 128 + ci) * K2 + tap];
  _Float16 h = (_Float16)v;
  wh[idx] = h;
  wl[idx] = (_Float16)(v - (float)h);
}

// ---------------- conv1: (B,1,28,28) -> (B,128,24,24), 5x5, pad0, ReLU ------
__global__ __launch_bounds__(256) void conv1_kernel(
    const float* __restrict__ x, const float* __restrict__ w,
    const float* __restrict__ b, float* __restrict__ out) {
  const int n = blockIdx.x;
  __shared__ float xl[784];
  __shared__ float wl[128 * 25];
  __shared__ float bl[128];
  const int t = threadIdx.x;
  for (int e = t; e < 784; e += 256) xl[e] = x[n * 784 + e];
  for (int e = t; e < 3200; e += 256) wl[e] = w[e];
  if (t < 128) bl[t] = b[t];
  __syncthreads();
  float* on = out + (size_t)n * 128 * 576;
  for (int idx = t; idx < 128 * 576; idx += 256) {
    int co = idx / 576, p = idx % 576;
    int y = p / 24, xx = p % 24;
    float acc = bl[co];
    const float* wc = &wl[co * 25];
#pragma unroll
    for (int ky = 0; ky < 5; ky++)
#pragma unroll
      for (int kx = 0; kx < 5; kx++)
        acc += xl[(y + ky) * 28 + xx + kx] * wc[ky * 5 + kx];
    on[idx] = fmaxf(acc, 0.f);
  }
}

// ---------------- split-fp16 MFMA conv + bias(+relu) + 2x2 maxpool ----------
template <int IW, int K, int PAD, int TR, bool RELU>
__global__ __launch_bounds__(256, 3) void conv_mfma_pool(
    const float* __restrict__ in, const _Float16* __restrict__ wph,
    const _Float16* __restrict__ wpl, const float* __restrict__ bias,
    float* __restrict__ out) {
  constexpr int IH = IW, OW = IW, OH = IW;
  constexpr int PW = IW + 2 * PAD;
  constexpr int SROWS = TR + K - 1;
  constexpr int S = SROWS * PW;
  constexpr int NPOS = TR * OW;
  constexpr int NCH = NPOS / 16;
  constexpr int K2 = K * K;
  constexpr int PITCH = 40;
  constexpr int LIN_ELT = S * PITCH;
  constexpr int LIN_BYTES = 2 * LIN_ELT * 2;
  constexpr int SCR_BYTES = 64 * NPOS * 4;
  constexpr int SMEM_BYTES = LIN_BYTES > SCR_BYTES ? LIN_BYTES : SCR_BYTES;
  static_assert(NPOS % 16 == 0, "");
  static_assert(TR % 2 == 0 && OW % 2 == 0, "");
  __shared__ __align__(16) char smem[SMEM_BYTES];
  _Float16* linh = (_Float16*)smem;
  _Float16* linl = linh + LIN_ELT;
  const int n = blockIdx.x;
  const int r0 = blockIdx.y * TR;
  const int t = threadIdx.x;
  const int wv = t >> 6;
  const int lane = t & 63;
  const int nn = lane & 15;
  const int q = lane >> 4;
  f32x4 acc0[NCH], acc1[NCH];
#pragma unroll
  for (int c = 0; c < NCH; c++) {
    acc0[c] = f32x4{0.f, 0.f, 0.f, 0.f};
    acc1[c] = f32x4{0.f, 0.f, 0.f, 0.f};
  }
  int base[NCH];
#pragma unroll
  for (int c = 0; c < NCH; c++) {
    int p = c * 16 + nn;
    base[c] = (p / OW) * PW + (p % OW);
  }
  const float* inN = in + (size_t)n * 128 * IH * IW;
  const int rowA = wv * 16 + nn;
  const int rowB = (wv + 4) * 16 + nn;
  for (int cb = 0; cb < 4; cb++) {
    const int ci0 = cb * 32;
    __syncthreads();
    for (int e = t; e < 32 * S; e += 256) {
      int ci = e / S, sp = e - ci * S;
      int r = sp / PW, c = sp - r * PW;
      int ir = r0 + r - PAD, ic = c - PAD;
      float v = 0.f;
      if (ir >= 0 && ir < IH && ic >= 0 && ic < IW)
        v = inN[(size_t)(ci0 + ci) * (IH * IW) + ir * IW + ic];
      _Float16 h = (_Float16)v;
      linh[sp * PITCH + ci] = h;
      linl[sp * PITCH + ci] = (_Float16)(v - (float)h);
    }
    __syncthreads();
    const size_t gA = (size_t)rowA * 128 + ci0 + q * 8;
    const size_t gB = (size_t)rowB * 128 + ci0 + q * 8;
    f16x8 cah0 = *(const f16x8*)&wph[gA];
    f16x8 cal0 = *(const f16x8*)&wpl[gA];
    f16x8 cah1 = *(const f16x8*)&wph[gB];
    f16x8 cal1 = *(const f16x8*)&wpl[gB];
    for (int tap = 0; tap < K2; tap++) {
      f16x8 nah0 = cah0, nal0 = cal0, nah1 = cah1, nal1 = cal1;
      if (tap + 1 < K2) {
        size_t oA = gA + (size_t)(tap + 1) * 16384;
        size_t oB = gB + (size_t)(tap + 1) * 16384;
        nah0 = *(const f16x8*)&wph[oA];
        nal0 = *(const f16x8*)&wpl[oA];
        nah1 = *(const f16x8*)&wph[oB];
        nal1 = *(const f16x8*)&wpl[oB];
      }
      const int ky = tap / K, kx = tap - ky * K;
      const int toff = ky * PW + kx;
#pragma unroll
      for (int c = 0; c < NCH; c++) {
        f16x8 bh = *(const f16x8*)&linh[(base[c] + toff) * PITCH + q * 8];
        f16x8 bl = *(const f16x8*)&linl[(base[c] + toff) * PITCH + q * 8];
        acc0[c] =
            __builtin_amdgcn_mfma_f32_16x16x32_f16(cah0, bh, acc0[c], 0, 0, 0);
        acc0[c] =
            __builtin_amdgcn_mfma_f32_16x16x32_f16(cah0, bl, acc0[c], 0, 0, 0);
        acc0[c] =
            __builtin_amdgcn_mfma_f32_16x16x32_f16(cal0, bh, acc0[c], 0, 0, 0);
        acc1[c] =
            __builtin_amdgcn_mfma_f32_16x16x32_f16(cah1, bh, acc1[c], 0, 0, 0);
        acc1[c] =
            __builtin_amdgcn_mfma_f32_16x16x32_f16(cah1, bl, acc1[c], 0, 0, 0);
        acc1[c] =
            __builtin_amdgcn_mfma_f32_16x16x32_f16(cal1, bh, acc1[c], 0, 0, 0);
      }
      cah0 = nah0; cal0 = nal0; cah1 = nah1; cal1 = nal1;
    }
  }
  __syncthreads();
  float* scr = (float*)smem + wv * 16 * NPOS;
#pragma unroll
  for (int j = 0; j < 2; j++) {
    const int cot = (j ? wv + 4 : wv) * 16;
#pragma unroll
    for (int c = 0; c < NCH; c++) {
      f32x4 a = j ? acc1[c] : acc0[c];
#pragma unroll
      for (int r = 0; r < 4; r++) {
        float v = a[r] + bias[cot + q * 4 + r];
        if (RELU) v = fmaxf(v, 0.f);
        scr[(q * 4 + r) * NPOS + c * 16 + nn] = v;
      }
    }
    __syncthreads();
    for (int e = lane; e < 16 * (TR / 2) * (OW / 2); e += 64) {
      int co_l = e / ((TR / 2) * (OW / 2));
      int rem = e - co_l * ((TR / 2) * (OW / 2));
      int pr = rem / (OW / 2), pc = rem - pr * (OW / 2);
      const float* s = scr + co_l * NPOS;
      int lp = (2 * pr) * OW + 2 * pc;
      float m =
          fmaxf(fmaxf(s[lp], s[lp + 1]), fmaxf(s[lp + OW], s[lp + OW + 1]));
      out[((size_t)n * 128 + cot + co_l) * (OH / 2) * (OW / 2) +
          (r0 / 2 + pr) * (OW / 2) + pc] = m;
    }
    __syncthreads();
  }
}

// ---------------- VQ: distances, argmax(d2) [faithful], gather --------------
__global__ __launch_bounds__(256) void vq_kernel(
    const float* __restrict__ z, const float* __restrict__ dict,
    float* __restrict__ val, ushort* __restrict__ val_bf,
    float* __restrict__ out_idx) {
  const int n = blockIdx.x;
  __shared__ float zl[128 * 36];
  __shared__ float d2[36 * 129];
  __shared__ float w2n[128];
  __shared__ int bk[36];
  const int t = threadIdx.x;
  const float* zn = z + (size_t)n * 4608;
  for (int e = t; e < 4608; e += 256) zl[e] = zn[e];
  if (t < 128) {
    float s = 0.f;
    const float* wr = dict + t * 128;
    for (int c = 0; c < 128; c++) s += wr[c] * wr[c];
    w2n[t] = s;
  }
  __syncthreads();
  const int k = t & 127, pg = t >> 7;
  float dot[18];
#pragma unroll
  for (int i = 0; i < 18; i++) dot[i] = 0.f;
  const float* wr = dict + k * 128;
  for (int c = 0; c < 128; c++) {
    float wv = wr[c];
    const float* zr = &zl[c * 36 + pg * 18];
#pragma unroll
    for (int i = 0; i < 18; i++) dot[i] += zr[i] * wv;
  }
  float wn = w2n[k];
#pragma unroll
  for (int i = 0; i < 18; i++) d2[(pg * 18 + i) * 129 + k] = wn - 2.f * dot[i];
  __syncthreads();
  if (t < 36) {
    const float* dr = &d2[t * 129];
    float best = dr[0];
    int bi = 0;
    for (int kk = 1; kk < 128; kk++) {
      float v = dr[kk];
      if (v > best) { best = v; bi = kk; }  // strict >: first max (argmax tie)
    }
    bk[t] = bi;
    out_idx[n * 36 + t] = (float)bi;
  }
  __syncthreads();
  float* vn = val + (size_t)n * 4608;
  ushort* vbn = val_bf + (size_t)n * 4608;
  for (int e = t; e < 4608; e += 256) {
    int c = e / 36, p = e % 36;
    float v = dict[bk[p] * 128 + c];
    vn[e] = v;
    vbn[e] = f2bf(v);
  }
}

// ---------------- bf16 MFMA deconv (stride 1), bf16 in, bf16/mu out ---------
template <int IH, int IW, int OH, int OW, int K, int TR, bool MU_FUSE>
__global__ __launch_bounds__(256, 3) void deconv_mfma(
    const ushort* __restrict__ in, const ushort* __restrict__ wprep,
    const float* __restrict__ bias, const float* __restrict__ mw,
    void* __restrict__ outp) {
  constexpr int PAD = K - 1;
  constexpr int PW = IW + 2 * PAD;
  constexpr int K2 = K * K;
  constexpr int SROWS = TR + K - 1;
  constexpr int S = SROWS * PW;
  constexpr int NPOS = TR * OW;
  constexpr int NCH = (NPOS + 15) / 16;
  constexpr int PITCH = 40;
  const int n = blockIdx.x;
  const int r0 = blockIdx.y * TR;
  __shared__ __align__(16) ushort lin[S * PITCH];
  const int t = threadIdx.x;
  const int wv = t >> 6;
  const int lane = t & 63;
  const int nn = lane & 15;
  const int q = lane >> 4;
  f32x4 acc0[NCH], acc1[NCH];
  int base[NCH];
#pragma unroll
  for (int c = 0; c < NCH; c++) {
    acc0[c] = f32x4{0.f, 0.f, 0.f, 0.f};
    acc1[c] = f32x4{0.f, 0.f, 0.f, 0.f};
    int p = c * 16 + nn;
    int pc = p < NPOS ? p : NPOS - 1;
    base[c] = (pc / OW) * PW + (pc % OW);
  }
  const ushort* inN = in + (size_t)n * 128 * IH * IW;
  for (int cb = 0; cb < 4; cb++) {
    const int ci0 = cb * 32;
    __syncthreads();
    for (int e = t; e < 32 * S; e += 256) {
      int ci = e / S, sp = e - ci * S;
      int rr = sp / PW, cc = sp - rr * PW;
      int ir = r0 + rr - PAD, ic = cc - PAD;
      ushort v = 0;
      if (ir >= 0 && ir < IH && ic >= 0 && ic < IW)
        v = inN[(size_t)(ci0 + ci) * (IH * IW) + ir * IW + ic];
      lin[sp * PITCH + ci] = v;
    }
    __syncthreads();
    const size_t gA = (size_t)(wv * 16 + nn) * 128 + ci0 + q * 8;
    const size_t gB = (size_t)((wv + 4) * 16 + nn) * 128 + ci0 + q * 8;
    s16x8 ca0 = *(const s16x8*)&wprep[gA];
    s16x8 ca1 = *(const s16x8*)&wprep[gB];
    for (int tap = 0; tap < K2; tap++) {
      s16x8 na0 = ca0, na1 = ca1;
      if (tap + 1 < K2) {
        na0 = *(const s16x8*)&wprep[gA + (size_t)(tap + 1) * 16384];
        na1 = *(const s16x8*)&wprep[gB + (size_t)(tap + 1) * 16384];
      }
      const int ky = tap / K, kx = tap - ky * K;
      const int toff = ky * PW + kx;
#pragma unroll
      for (int c = 0; c < NCH; c++) {
        s16x8 b = *(const s16x8*)&lin[(base[c] + toff) * PITCH + q * 8];
        acc0[c] =
            __builtin_amdgcn_mfma_f32_16x16x32_bf16(ca0, b, acc0[c], 0, 0, 0);
        acc1[c] =
            __builtin_amdgcn_mfma_f32_16x16x32_bf16(ca1, b, acc1[c], 0, 0, 0);
      }
      ca0 = na0; ca1 = na1;
    }
  }
  const int co_a = wv * 16 + q * 4;
  const int co_b = (wv + 4) * 16 + q * 4;
  float ba[4], bb[4];
#pragma unroll
  for (int r = 0; r < 4; r++) {
    ba[r] = bias[co_a + r];
    bb[r] = bias[co_b + r];
  }
  if (!MU_FUSE) {
    ushort* out = (ushort*)outp;
#pragma unroll
    for (int c = 0; c < NCH; c++) {
      int p = c * 16 + nn;
      if (p < NPOS) {
        ushort* oa = out + ((size_t)n * 128 + co_a) * (OH * OW) + r0 * OW + p;
        ushort* ob = out + ((size_t)n * 128 + co_b) * (OH * OW) + r0 * OW + p;
#pragma unroll
        for (int r = 0; r < 4; r++) {
          oa[(size_t)r * OH * OW] = f2bf(fmaxf(acc0[c][r] + ba[r], 0.f));
          ob[(size_t)r * OH * OW] = f2bf(fmaxf(acc1[c][r] + bb[r], 0.f));
        }
      }
    }
  } else {
    float* out = (float*)outp;
    float wa[4], wb[4];
#pragma unroll
    for (int r = 0; r < 4; r++) {
      wa[r] = mw[co_a + r];
      wb[r] = mw[co_b + r];
    }
#pragma unroll
    for (int c = 0; c < NCH; c++) {
      int p = c * 16 + nn;
      float s = 0.f;
#pragma unroll
      for (int r = 0; r < 4; r++) {
        s += fmaxf(acc0[c][r] + ba[r], 0.f) * wa[r];
        s += fmaxf(acc1[c][r] + bb[r], 0.f) * wb[r];
      }
      s += __shfl_xor(s, 16);
      s += __shfl_xor(s, 32);
      if (q == 0 && p < NPOS)
        atomicAdd(&out[(size_t)n * (OH * OW) + r0 * OW + p], s);
    }
  }
}

// ---------------- t2: k4 s2 deconv via parity decomposition, bf16 MFMA ------
// block = (image, parity); per parity: 10x10 out from 9x9 in, K=2, pad=1.
__global__ __launch_bounds__(256, 3) void deconv_s2_mfma(
    const ushort* __restrict__ in, const ushort* __restrict__ wp2,
    const float* __restrict__ bias, ushort* __restrict__ out) {
  constexpr int NCH = 7;     // 100 pos -> 7 chunks (clamped)
  constexpr int PITCH = 40;
  const int n = blockIdx.x;
  const int pp = blockIdx.y;  // parity: py = pp>>1, px = pp&1
  const int py = pp >> 1, px = pp & 1;
  __shared__ __align__(16) ushort lin[121 * PITCH];  // 11x11 padded
  const int t = threadIdx.x;
  const int wv = t >> 6;
  const int lane = t & 63;
  const int nn = lane & 15;
  const int q = lane >> 4;
  f32x4 acc0[NCH], acc1[NCH];
  int base[NCH];
#pragma unroll
  for (int c = 0; c < NCH; c++) {
    acc0[c] = f32x4{0.f, 0.f, 0.f, 0.f};
    acc1[c] = f32x4{0.f, 0.f, 0.f, 0.f};
    int p = c * 16 + nn;
    int pc = p < 100 ? p : 99;
    base[c] = (pc / 10) * 11 + (pc % 10);
  }
  const ushort* inN = in + (size_t)n * 128 * 81;
  const int toffs[4] = {12, 11, 1, 0};  // tap=(u,v): (1-u)*11+(1-v)
  for (int cb = 0; cb < 4; cb++) {
    const int ci0 = cb * 32;
    __syncthreads();
    for (int e = t; e < 32 * 121; e += 256) {
      int ci = e / 121, sp = e - ci * 121;
      int r = sp / 11, c2 = sp - r * 11;
      int ir = r - 1, ic = c2 - 1;
      ushort v = 0;
      if (ir >= 0 && ir < 9 && ic >= 0 && ic < 9)
        v = inN[(size_t)(ci0 + ci) * 81 + ir * 9 + ic];
      lin[sp * PITCH + ci] = v;
    }
    __syncthreads();
    const size_t gA =
        ((size_t)(pp * 4) * 128 + wv * 16 + nn) * 128 + ci0 + q * 8;
    const size_t gB =
        ((size_t)(pp * 4) * 128 + (wv + 4) * 16 + nn) * 128 + ci0 + q * 8;
    s16x8 ca0 = *(const s16x8*)&wp2[gA];
    s16x8 ca1 = *(const s16x8*)&wp2[gB];
    for (int tap = 0; tap < 4; tap++) {
      s16x8 na0 = ca0, na1 = ca1;
      if (tap + 1 < 4) {
        na0 = *(const s16x8*)&wp2[gA + (size_t)(tap + 1) * 16384];
        na1 = *(const s16x8*)&wp2[gB + (size_t)(tap + 1) * 16384];
      }
      const int toff = toffs[tap];
#pragma unroll
      for (int c = 0; c < NCH; c++) {
        s16x8 b = *(const s16x8*)&lin[(base[c] + toff) * PITCH + q * 8];
        acc0[c] =
            __builtin_amdgcn_mfma_f32_16x16x32_bf16(ca0, b, acc0[c], 0, 0, 0);
        acc1[c] =
            __builtin_amdgcn_mfma_f32_16x16x32_bf16(ca1, b, acc1[c], 0, 0, 0);
      }
      ca0 = na0; ca1 = na1;
    }
  }
  const int co_a = wv * 16 + q * 4;
  const int co_b = (wv + 4) * 16 + q * 4;
#pragma unroll
  for (int c = 0; c < NCH; c++) {
    int p = c * 16 + nn;
    if (p < 100) {
      int oy = 2 * (p / 10) + py, ox = 2 * (p % 10) + px;
#pragma unroll
      for (int r = 0; r < 4; r++) {
        out[((size_t)n * 128 + co_a + r) * 400 + oy * 20 + ox] =
            f2bf(fmaxf(acc0[c][r] + bias[co_a + r], 0.f));
        out[((size_t)n * 128 + co_b + r) * 400 + oy * 20 + ox] =
            f2bf(fmaxf(acc1[c][r] + bias[co_b + r], 0.f));
      }
    }
  }
}

// ---------------- rec loss: mean((mu + mb - x)^2) ---------------------------
__global__ __launch_bounds__(256) void rec_loss_kernel(
    const float* __restrict__ mu, const float* __restrict__ mb,
    const float* __restrict__ x, float* __restrict__ out) {
  const int t = threadIdx.x;
  const int i = blockIdx.x * 256 + t;
  __shared__ float red[256];
  float d = mu[i] + mb[0] - x[i];
  red[t] = d * d;
  __syncthreads();
  for (int off = 128; off > 0; off >>= 1) {
    if (t < off) red[t] += red[t + off];
    __syncthreads();
  }
  if (t == 0) atomicAdd(out, red[0] * (1.0f / 200704.f));
}

// ---------------- dict / enc losses: sum (val - z)^2 ------------------------
__global__ __launch_bounds__(256) void vq_loss_kernel(
    const float4* __restrict__ val4, const float4* __restrict__ z4,
    float* __restrict__ out) {
  const int t = threadIdx.x;
  const int i = blockIdx.x * 256 + t;
  __shared__ float red[256];
  float4 a = val4[i], b = z4[i];
  float dx = a.x - b.x, dy = a.y - b.y, dz = a.z - b.z, dw = a.w - b.w;
  red[t] = dx * dx + dy * dy + dz * dz + dw * dw;
  __syncthreads();
  for (int off = 128; off > 0; off >>= 1) {
    if (t < off) red[t] += red[t + off];
    __syncthreads();
  }
  if (t == 0) {
    atomicAdd(out + 1, red[0] * (5.f / 1179648.f));
    atomicAdd(out + 2, red[0] * (1.25f / 1179648.f));
  }
}

// ---------------------------------------------------------------------------
extern "C" void kernel_launch(void* const* d_in, const int* in_sizes, int n_in,
                              void* d_out, int out_size, void* d_ws,
                              size_t ws_size, hipStream_t stream) {
  const float* x = (const float*)d_in[0];
  const float* w1 = (const float*)d_in[1];
  const float* b1 = (const float*)d_in[2];
  const float* w2 = (const float*)d_in[3];
  const float* b2 = (const float*)d_in[4];
  const float* w3 = (const float*)d_in[5];
  const float* b3 = (const float*)d_in[6];
  const float* t1w = (const float*)d_in[7];
  const float* t1b = (const float*)d_in[8];
  const float* t2w = (const float*)d_in[9];
  const float* t2b = (const float*)d_in[10];
  const float* t3w = (const float*)d_in[11];
  const float* t3b = (const float*)d_in[12];
  const float* t4w = (const float*)d_in[13];
  const float* t4b = (const float*)d_in[14];
  const float* mw = (const float*)d_in[15];
  const float* mb = (const float*)d_in[16];
  const float* dictw = (const float*)d_in[17];
  float* out = (float*)d_out;

  float* ws = (float*)d_ws;
  float* bufA = ws;               // h1 f32; later f1/f3 bf16
  float* bufB = bufA + 18874368;  // p1 f32; later f2 bf16
  float* z = bufB + 13107200;
  float* val = z + 1179648;
  float* mu = val + 1179648;  // 200,704
  ushort* wp1 = (ushort*)(mu + 200704);
  ushort* wp3 = wp1 + 16 * 16384;
  ushort* wp4 = wp3 + 25 * 16384;
  ushort* wp2 = wp4 + 25 * 16384;       // 4*4*16384
  ushort* val_bf = wp2 + 4 * 4 * 16384; // 1,179,648
  _Float16* w2h = (_Float16*)(val_bf + 1179648);
  _Float16* w2l = w2h + 25 * 16384;
  _Float16* w3h = w2l + 25 * 16384;
  _Float16* w3l = w3h + 25 * 16384;
  float* h1 = bufA;
  float* p1 = bufB;
  ushort* f1 = (ushort*)bufA;                // 2,654,208 u16
  ushort* f3 = (ushort*)(bufA + 1400000);    // 18,874,368 u16 (disjoint)
  ushort* f2 = (ushort*)bufB;                // 13,107,200 u16

  hipMemsetAsync(d_out, 0, 4 * sizeof(float), stream);
  hipMemsetAsync(mu, 0, 200704 * sizeof(float), stream);

  // weight prep
  prep_w<<<16 * 64, 256, 0, stream>>>(t1w, wp1, 16);
  prep_w<<<25 * 64, 256, 0, stream>>>(t3w, wp3, 25);
  prep_w<<<25 * 64, 256, 0, stream>>>(t4w, wp4, 25);
  prep_w_s2<<<1024, 256, 0, stream>>>(t2w, wp2);
  prep_w_split<<<25 * 64, 256, 0, stream>>>(w2, w2h, w2l, 25);
  prep_w_split<<<25 * 64, 256, 0, stream>>>(w3, w3h, w3l, 25);

  conv1_kernel<<<B_, 256, 0, stream>>>(x, w1, b1, h1);
  // conv2: 24x24 K5 pad2 relu + pool -> p1 (12x12)  [split-fp16 MFMA, TR=6]
  conv_mfma_pool<24, 5, 2, 6, true>
      <<<dim3(B_, 4), 256, 0, stream>>>(h1, w2h, w2l, b2, p1);
  // conv3: 12x12 K5 pad2 + pool -> z (6x6)  [split-fp16 MFMA, TR=4]
  conv_mfma_pool<12, 5, 2, 4, false>
      <<<dim3(B_, 3), 256, 0, stream>>>(p1, w3h, w3l, b3, z);
  vq_kernel<<<B_, 256, 0, stream>>>(z, dictw, val, val_bf, out + 4);
  // t1: 6->9, K4 (deconv s1), relu  [bf16 MFMA, bf16 io]
  deconv_mfma<6, 6, 9, 9, 4, 9, false>
      <<<dim3(B_, 1), 256, 0, stream>>>(val_bf, wp1, t1b, nullptr, f1);
  // t2: 9->20, K4 s2, relu  [bf16 MFMA, 4-parity decomposition]
  deconv_s2_mfma<<<dim3(B_, 4), 256, 0, stream>>>(f1, wp2, t2b, f2);
  // t3: 20->24, K5 (deconv s1), relu  [bf16 MFMA]
  deconv_mfma<20, 20, 24, 24, 5, 8, false>
      <<<dim3(B_, 3), 256, 0, stream>>>(f2, wp3, t3b, nullptr, f3);
  // t4: 24->28, K5 (deconv s1), relu + fused 1x1 mu  [bf16 MFMA]
  deconv_mfma<24, 24, 28, 28, 5, 7, true>
      <<<dim3(B_, 4), 256, 0, stream>>>(f3, wp4, t4b, mw, mu);
  rec_loss_kernel<<<784, 256, 0, stream>>>(mu, mb, x, out);
  vq_loss_kernel<<<1152, 256, 0, stream>>>((const float4*)val, (const float4*)z,
                                           out);
}

// Round 9
// 1010.952 us; speedup vs baseline: 18.5055x; 1.1445x over previous
//
#include <hip/hip_runtime.h>
#include <hip/hip_bf16.h>

// ---------------------------------------------------------------------------
// VQ-VAE forward. R9: NHWC activations everywhere + LDS chunk-XOR swizzle.
//  - conv1 f32 math -> writes h1 as fp16 hi/lo NHWC planes (split ONCE).
//  - conv2/conv3 split-fp16 MFMA (3 MFMAs/product, index-exact), staging =
//    vectorized b128 chunk copies; LDS slot swizzle kills the nn/nn+8 2-way
//    bank alias; fused bias(+relu)+2x2 maxpool epilogue (conv2 -> hi/lo NHWC,
//    conv3 -> f32 NHWC z).
//  - VQ argmax faithful f32 on NHWC z (LDS reads broadcast).
//  - Decoder bf16 NHWC MFMA: t1, t2 (4-parity K2 decomposition), t3, t4
//    (+fused 1x1 mu); b64-packed epilogue stores.
// ---------------------------------------------------------------------------

#define B_ 256

typedef __attribute__((ext_vector_type(8))) short s16x8;
typedef __attribute__((ext_vector_type(4))) short s16x4;
typedef __attribute__((ext_vector_type(8))) _Float16 f16x8;
typedef __attribute__((ext_vector_type(4))) float f32x4;

__device__ inline ushort f2bf(float f) {
  union { __hip_bfloat16 h; ushort u; } cv;
  cv.h = __float2bfloat16(f);
  return cv.u;
}

// ------- decoder weight prep: (ci,co,K,K) f32 -> [tap][co][ci] bf16 flipped -
__global__ __launch_bounds__(256) void prep_w(const float* __restrict__ w,
                                              ushort* __restrict__ wp,
                                              int K2) {
  int idx = blockIdx.x * 256 + threadIdx.x;
  if (idx >= K2 * 16384) return;
  int ci = idx & 127;
  int co = (idx >> 7) & 127;
  int tap = idx >> 14;
  wp[idx] = f2bf(w[((size_t)ci * 128 + co) * K2 + (K2 - 1 - tap)]);
}

// ------- t2 (k4 s2) weight prep: [parity][u,v][co][ci] bf16 -----------------
__global__ __launch_bounds__(256) void prep_w_s2(const float* __restrict__ w,
                                                 ushort* __restrict__ wp) {
  int idx = blockIdx.x * 256 + threadIdx.x;  // 4*4*16384
  int ci = idx & 127;
  int co = (idx >> 7) & 127;
  int tap = (idx >> 14) & 3;
  int pp = idx >> 16;
  int u = tap >> 1, v = tap & 1;
  int py = pp >> 1, px = pp & 1;
  wp[idx] =
      f2bf(w[(((size_t)ci * 128 + co) * 4 + (py + 2 * u)) * 4 + (px + 2 * v)]);
}

// ------- encoder weight prep: (co,ci,K,K) f32 -> [tap][co][ci] fp16 hi/lo ---
__global__ __launch_bounds__(256) void prep_w_split(const float* __restrict__ w,
                                                    _Float16* __restrict__ wh,
                                                    _Float16* __restrict__ wl,
                                                    int K2) {
  int idx = blockIdx.x * 256 + threadIdx.x;
  if (idx >= K2 * 16384) return;
  int ci = idx & 127;
  int co = (idx >> 7) & 127;
  int tap = idx >> 14;
  float v = w[((size_t)co * 128 + ci) * K2 + tap];
  _Float16 h = (_Float16)v;
  wh[idx] = h;
  wl[idx] = (_Float16)(v - (float)h);
}

// ------- conv1: (B,1,28,28) -> NHWC hi/lo (B,576,128), 5x5, pad0, ReLU ------
__global__ __launch_bounds__(256) void conv1_kernel(
    const float* __restrict__ x, const float* __restrict__ w,
    const float* __restrict__ b, _Float16* __restrict__ oh,
    _Float16* __restrict__ ol) {
  const int n = blockIdx.x;
  __shared__ float xl[784];
  __shared__ float wl[128 * 25];
  __shared__ float bl[128];
  const int t = threadIdx.x;
  for (int e = t; e < 784; e += 256) xl[e] = x[n * 784 + e];
  for (int e = t; e < 3200; e += 256) wl[e] = w[e];
  if (t < 128) bl[t] = b[t];
  __syncthreads();
  const size_t nb = (size_t)n * 73728;
  for (int idx = t; idx < 73728; idx += 256) {
    int co = idx & 127, p = idx >> 7;
    int y = p / 24, xx = p % 24;
    float acc = bl[co];
    const float* wc = &wl[co * 25];
#pragma unroll
    for (int ky = 0; ky < 5; ky++)
#pragma unroll
      for (int kx = 0; kx < 5; kx++)
        acc += xl[(y + ky) * 28 + xx + kx] * wc[ky * 5 + kx];
    float v = fmaxf(acc, 0.f);
    _Float16 h = (_Float16)v;
    oh[nb + idx] = h;
    ol[nb + idx] = (_Float16)(v - (float)h);
  }
}

// ---------------- split-fp16 MFMA conv + bias(+relu) + 2x2 maxpool ----------
// NHWC hi/lo in; out: hi/lo NHWC (OUT_F32=0) or f32 NHWC (OUT_F32=1).
template <int IW, int K, int PAD, int TR, bool RELU, bool OUT_F32>
__global__ __launch_bounds__(256, 3) void conv_mfma_pool(
    const _Float16* __restrict__ inh, const _Float16* __restrict__ inl,
    const _Float16* __restrict__ wph, const _Float16* __restrict__ wpl,
    const float* __restrict__ bias, _Float16* __restrict__ outh,
    _Float16* __restrict__ outl, float* __restrict__ outf) {
  constexpr int IH = IW, OW = IW, OH = IW;
  constexpr int PW = IW + 2 * PAD;
  constexpr int SROWS = TR + K - 1;
  constexpr int S = SROWS * PW;
  constexpr int NPOS = TR * OW;
  constexpr int NCH = NPOS / 16;
  constexpr int K2 = K * K;
  constexpr int PITCH = 40;
  constexpr int LIN_ELT = S * PITCH;
  constexpr int LIN_BYTES = 2 * LIN_ELT * 2;
  constexpr int SCR_BYTES = 64 * NPOS * 4;
  constexpr int SMEM_BYTES = LIN_BYTES > SCR_BYTES ? LIN_BYTES : SCR_BYTES;
  static_assert(NPOS % 16 == 0, "");
  static_assert(TR % 2 == 0 && OW % 2 == 0, "");
  __shared__ __align__(16) char smem[SMEM_BYTES];
  _Float16* linh = (_Float16*)smem;
  _Float16* linl = linh + LIN_ELT;
  const int n = blockIdx.x;
  const int r0 = blockIdx.y * TR;
  const int t = threadIdx.x;
  const int wv = t >> 6;
  const int lane = t & 63;
  const int nn = lane & 15;
  const int q = lane >> 4;
  f32x4 acc0[NCH], acc1[NCH];
#pragma unroll
  for (int c = 0; c < NCH; c++) {
    acc0[c] = f32x4{0.f, 0.f, 0.f, 0.f};
    acc1[c] = f32x4{0.f, 0.f, 0.f, 0.f};
  }
  int base[NCH];
#pragma unroll
  for (int c = 0; c < NCH; c++) {
    int p = c * 16 + nn;
    base[c] = (p / OW) * PW + (p % OW);
  }
  const int rowA = wv * 16 + nn;
  const int rowB = (wv + 4) * 16 + nn;
  for (int cb = 0; cb < 4; cb++) {
    const int ci0 = cb * 32;
    __syncthreads();
    // stage: b128 chunk copies, slot-swizzled: slot = (j + (sp>>3)) & 3
    for (int e = t; e < S * 4; e += 256) {
      int sp = e >> 2, j = e & 3;
      int r = sp / PW, c = sp - r * PW;
      int ir = r0 + r - PAD, ic = c - PAD;
      f16x8 vh = {0, 0, 0, 0, 0, 0, 0, 0};
      f16x8 vl = {0, 0, 0, 0, 0, 0, 0, 0};
      if (ir >= 0 && ir < IH && ic >= 0 && ic < IW) {
        size_t g = ((size_t)n * (IH * IW) + ir * IW + ic) * 128 + ci0 + j * 8;
        vh = *(const f16x8*)&inh[g];
        vl = *(const f16x8*)&inl[g];
      }
      int st = sp * PITCH + ((j + (sp >> 3)) & 3) * 8;
      *(f16x8*)&linh[st] = vh;
      *(f16x8*)&linl[st] = vl;
    }
    __syncthreads();
    const size_t gA = (size_t)rowA * 128 + ci0 + q * 8;
    const size_t gB = (size_t)rowB * 128 + ci0 + q * 8;
    f16x8 cah0 = *(const f16x8*)&wph[gA];
    f16x8 cal0 = *(const f16x8*)&wpl[gA];
    f16x8 cah1 = *(const f16x8*)&wph[gB];
    f16x8 cal1 = *(const f16x8*)&wpl[gB];
    for (int tap = 0; tap < K2; tap++) {
      f16x8 nah0 = cah0, nal0 = cal0, nah1 = cah1, nal1 = cal1;
      if (tap + 1 < K2) {
        size_t oA = gA + (size_t)(tap + 1) * 16384;
        size_t oB = gB + (size_t)(tap + 1) * 16384;
        nah0 = *(const f16x8*)&wph[oA];
        nal0 = *(const f16x8*)&wpl[oA];
        nah1 = *(const f16x8*)&wph[oB];
        nal1 = *(const f16x8*)&wpl[oB];
      }
      const int ky = tap / K, kx = tap - ky * K;
      const int toff = ky * PW + kx;
#pragma unroll
      for (int c = 0; c < NCH; c++) {
        int s = base[c] + toff;
        int off = s * PITCH + ((q + (s >> 3)) & 3) * 8;
        f16x8 bh = *(const f16x8*)&linh[off];
        f16x8 bl = *(const f16x8*)&linl[off];
        acc0[c] =
            __builtin_amdgcn_mfma_f32_16x16x32_f16(cah0, bh, acc0[c], 0, 0, 0);
        acc0[c] =
            __builtin_amdgcn_mfma_f32_16x16x32_f16(cah0, bl, acc0[c], 0, 0, 0);
        acc0[c] =
            __builtin_amdgcn_mfma_f32_16x16x32_f16(cal0, bh, acc0[c], 0, 0, 0);
        acc1[c] =
            __builtin_amdgcn_mfma_f32_16x16x32_f16(cah1, bh, acc1[c], 0, 0, 0);
        acc1[c] =
            __builtin_amdgcn_mfma_f32_16x16x32_f16(cah1, bl, acc1[c], 0, 0, 0);
        acc1[c] =
            __builtin_amdgcn_mfma_f32_16x16x32_f16(cal1, bh, acc1[c], 0, 0, 0);
      }
      cah0 = nah0; cal0 = nal0; cah1 = nah1; cal1 = nal1;
    }
  }
  // epilogue: bias(+relu) -> per-wave scr (overlays lin) -> 2x2 pool -> NHWC
  __syncthreads();
  float* scr = (float*)smem + wv * 16 * NPOS;
#pragma unroll
  for (int j = 0; j < 2; j++) {
    const int cot = (j ? wv + 4 : wv) * 16;
#pragma unroll
    for (int c = 0; c < NCH; c++) {
      f32x4 a = j ? acc1[c] : acc0[c];
#pragma unroll
      for (int r = 0; r < 4; r++) {
        float v = a[r] + bias[cot + q * 4 + r];
        if (RELU) v = fmaxf(v, 0.f);
        scr[(q * 4 + r) * NPOS + c * 16 + nn] = v;
      }
    }
    __syncthreads();
    for (int e = lane; e < 16 * (TR / 2) * (OW / 2); e += 64) {
      int co_l = e & 15;
      int rem = e >> 4;
      int pr = rem / (OW / 2), pc = rem - pr * (OW / 2);
      const float* s = scr + co_l * NPOS;
      int lp = (2 * pr) * OW + 2 * pc;
      float m =
          fmaxf(fmaxf(s[lp], s[lp + 1]), fmaxf(s[lp + OW], s[lp + OW + 1]));
      int sp_out = (r0 / 2 + pr) * (OW / 2) + pc;
      size_t go = ((size_t)n * ((OH / 2) * (OW / 2)) + sp_out) * 128 + cot + co_l;
      if (OUT_F32) {
        outf[go] = m;
      } else {
        _Float16 h = (_Float16)m;
        outh[go] = h;
        outl[go] = (_Float16)(m - (float)h);
      }
    }
    __syncthreads();
  }
}

// ---------------- VQ on NHWC z: argmax(d2) [faithful], gather ---------------
__global__ __launch_bounds__(256) void vq_kernel(
    const float* __restrict__ z, const float* __restrict__ dict,
    float* __restrict__ val, ushort* __restrict__ val_bf,
    float* __restrict__ out_idx) {
  const int n = blockIdx.x;
  __shared__ float zl[36 * 128];  // NHWC: [p][c]
  __shared__ float d2[36 * 129];
  __shared__ float w2n[128];
  __shared__ int bk[36];
  const int t = threadIdx.x;
  const float* zn = z + (size_t)n * 4608;
  for (int e = t; e < 4608; e += 256) zl[e] = zn[e];
  if (t < 128) {
    float s = 0.f;
    const float* wr = dict + t * 128;
    for (int c = 0; c < 128; c++) s += wr[c] * wr[c];
    w2n[t] = s;
  }
  __syncthreads();
  const int k = t & 127, pg = t >> 7;
  float dot[18];
#pragma unroll
  for (int i = 0; i < 18; i++) dot[i] = 0.f;
  const float* wr = dict + k * 128;
  for (int c = 0; c < 128; c++) {
    float wv = wr[c];
#pragma unroll
    for (int i = 0; i < 18; i++) dot[i] += zl[(pg * 18 + i) * 128 + c] * wv;
  }
  float wn = w2n[k];
#pragma unroll
  for (int i = 0; i < 18; i++) d2[(pg * 18 + i) * 129 + k] = wn - 2.f * dot[i];
  __syncthreads();
  if (t < 36) {
    const float* dr = &d2[t * 129];
    float best = dr[0];
    int bi = 0;
    for (int kk = 1; kk < 128; kk++) {
      float v = dr[kk];
      if (v > best) { best = v; bi = kk; }  // strict >: first max (argmax tie)
    }
    bk[t] = bi;
    out_idx[n * 36 + t] = (float)bi;
  }
  __syncthreads();
  float* vn = val + (size_t)n * 4608;
  ushort* vbn = val_bf + (size_t)n * 4608;
  for (int e = t; e < 4608; e += 256) {
    int c = e & 127, p = e >> 7;
    float v = dict[bk[p] * 128 + c];
    vn[e] = v;
    vbn[e] = f2bf(v);
  }
}

// ---------------- bf16 MFMA deconv (s1), NHWC bf16 io, optional fused mu ----
template <int IH, int IW, int OH, int OW, int K, int TR, bool MU_FUSE>
__global__ __launch_bounds__(256, 3) void deconv_mfma(
    const ushort* __restrict__ in, const ushort* __restrict__ wprep,
    const float* __restrict__ bias, const float* __restrict__ mw,
    void* __restrict__ outp) {
  constexpr int PAD = K - 1;
  constexpr int PW = IW + 2 * PAD;
  constexpr int K2 = K * K;
  constexpr int SROWS = TR + K - 1;
  constexpr int S = SROWS * PW;
  constexpr int NPOS = TR * OW;
  constexpr int NCH = (NPOS + 15) / 16;
  constexpr int PITCH = 40;
  const int n = blockIdx.x;
  const int r0 = blockIdx.y * TR;
  __shared__ __align__(16) ushort lin[S * PITCH];
  const int t = threadIdx.x;
  const int wv = t >> 6;
  const int lane = t & 63;
  const int nn = lane & 15;
  const int q = lane >> 4;
  f32x4 acc0[NCH], acc1[NCH];
  int base[NCH];
#pragma unroll
  for (int c = 0; c < NCH; c++) {
    acc0[c] = f32x4{0.f, 0.f, 0.f, 0.f};
    acc1[c] = f32x4{0.f, 0.f, 0.f, 0.f};
    int p = c * 16 + nn;
    int pc = p < NPOS ? p : NPOS - 1;
    base[c] = (pc / OW) * PW + (pc % OW);
  }
  for (int cb = 0; cb < 4; cb++) {
    const int ci0 = cb * 32;
    __syncthreads();
    for (int e = t; e < S * 4; e += 256) {
      int sp = e >> 2, j = e & 3;
      int rr = sp / PW, cc = sp - rr * PW;
      int ir = r0 + rr - PAD, ic = cc - PAD;
      s16x8 v = {0, 0, 0, 0, 0, 0, 0, 0};
      if (ir >= 0 && ir < IH && ic >= 0 && ic < IW)
        v = *(const s16x8*)&in[((size_t)n * (IH * IW) + ir * IW + ic) * 128 +
                               ci0 + j * 8];
      *(s16x8*)&lin[sp * PITCH + ((j + (sp >> 3)) & 3) * 8] = v;
    }
    __syncthreads();
    const size_t gA = (size_t)(wv * 16 + nn) * 128 + ci0 + q * 8;
    const size_t gB = (size_t)((wv + 4) * 16 + nn) * 128 + ci0 + q * 8;
    s16x8 ca0 = *(const s16x8*)&wprep[gA];
    s16x8 ca1 = *(const s16x8*)&wprep[gB];
    for (int tap = 0; tap < K2; tap++) {
      s16x8 na0 = ca0, na1 = ca1;
      if (tap + 1 < K2) {
        na0 = *(const s16x8*)&wprep[gA + (size_t)(tap + 1) * 16384];
        na1 = *(const s16x8*)&wprep[gB + (size_t)(tap + 1) * 16384];
      }
      const int ky = tap / K, kx = tap - ky * K;
      const int toff = ky * PW + kx;
#pragma unroll
      for (int c = 0; c < NCH; c++) {
        int s = base[c] + toff;
        s16x8 b = *(const s16x8*)&lin[s * PITCH + ((q + (s >> 3)) & 3) * 8];
        acc0[c] =
            __builtin_amdgcn_mfma_f32_16x16x32_bf16(ca0, b, acc0[c], 0, 0, 0);
        acc1[c] =
            __builtin_amdgcn_mfma_f32_16x16x32_bf16(ca1, b, acc1[c], 0, 0, 0);
      }
      ca0 = na0; ca1 = na1;
    }
  }
  const int co_a = wv * 16 + q * 4;
  const int co_b = (wv + 4) * 16 + q * 4;
  float ba[4], bb[4];
#pragma unroll
  for (int r = 0; r < 4; r++) {
    ba[r] = bias[co_a + r];
    bb[r] = bias[co_b + r];
  }
  if (!MU_FUSE) {
    ushort* out = (ushort*)outp;
#pragma unroll
    for (int c = 0; c < NCH; c++) {
      int p = c * 16 + nn;
      if (p < NPOS) {
        size_t go = ((size_t)n * (OH * OW) + r0 * OW + p) * 128;
        s16x4 pa, pb;
#pragma unroll
        for (int r = 0; r < 4; r++) {
          pa[r] = (short)f2bf(fmaxf(acc0[c][r] + ba[r], 0.f));
          pb[r] = (short)f2bf(fmaxf(acc1[c][r] + bb[r], 0.f));
        }
        *(s16x4*)&out[go + co_a] = pa;
        *(s16x4*)&out[go + co_b] = pb;
      }
    }
  } else {
    float* out = (float*)outp;
    float wa[4], wb[4];
#pragma unroll
    for (int r = 0; r < 4; r++) {
      wa[r] = mw[co_a + r];
      wb[r] = mw[co_b + r];
    }
#pragma unroll
    for (int c = 0; c < NCH; c++) {
      int p = c * 16 + nn;
      float s = 0.f;
#pragma unroll
      for (int r = 0; r < 4; r++) {
        s += fmaxf(acc0[c][r] + ba[r], 0.f) * wa[r];
        s += fmaxf(acc1[c][r] + bb[r], 0.f) * wb[r];
      }
      s += __shfl_xor(s, 16);
      s += __shfl_xor(s, 32);
      if (q == 0 && p < NPOS)
        atomicAdd(&out[(size_t)n * (OH * OW) + r0 * OW + p], s);
    }
  }
}

// ---------------- t2: k4 s2 deconv via parity decomposition, bf16 NHWC ------
__global__ __launch_bounds__(256, 3) void deconv_s2_mfma(
    const ushort* __restrict__ in, const ushort* __restrict__ wp2,
    const float* __restrict__ bias, ushort* __restrict__ out) {
  constexpr int NCH = 7;  // 100 pos
  constexpr int PITCH = 40;
  const int n = blockIdx.x;
  const int pp = blockIdx.y;
  const int py = pp >> 1, px = pp & 1;
  __shared__ __align__(16) ushort lin[121 * PITCH];
  const int t = threadIdx.x;
  const int wv = t >> 6;
  const int lane = t & 63;
  const int nn = lane & 15;
  const int q = lane >> 4;
  f32x4 acc0[NCH], acc1[NCH];
  int base[NCH];
#pragma unroll
  for (int c = 0; c < NCH; c++) {
    acc0[c] = f32x4{0.f, 0.f, 0.f, 0.f};
    acc1[c] = f32x4{0.f, 0.f, 0.f, 0.f};
    int p = c * 16 + nn;
    int pc = p < 100 ? p : 99;
    base[c] = (pc / 10) * 11 + (pc % 10);
  }
  const int toffs[4] = {12, 11, 1, 0};
  for (int cb = 0; cb < 4; cb++) {
    const int ci0 = cb * 32;
    __syncthreads();
    for (int e = t; e < 121 * 4; e += 256) {
      int sp = e >> 2, j = e & 3;
      int r = sp / 11, c2 = sp - r * 11;
      int ir = r - 1, ic = c2 - 1;
      s16x8 v = {0, 0, 0, 0, 0, 0, 0, 0};
      if (ir >= 0 && ir < 9 && ic >= 0 && ic < 9)
        v = *(const s16x8*)&in[((size_t)n * 81 + ir * 9 + ic) * 128 + ci0 +
                               j * 8];
      *(s16x8*)&lin[sp * PITCH + ((j + (sp >> 3)) & 3) * 8] = v;
    }
    __syncthreads();
    const size_t gA =
        ((size_t)(pp * 4) * 128 + wv * 16 + nn) * 128 + ci0 + q * 8;
    const size_t gB =
        ((size_t)(pp * 4) * 128 + (wv + 4) * 16 + nn) * 128 + ci0 + q * 8;
    s16x8 ca0 = *(const s16x8*)&wp2[gA];
    s16x8 ca1 = *(const s16x8*)&wp2[gB];
    for (int tap = 0; tap < 4; tap++) {
      s16x8 na0 = ca0, na1 = ca1;
      if (tap + 1 < 4) {
        na0 = *(const s16x8*)&wp2[gA + (size_t)(tap + 1) * 16384];
        na1 = *(const s16x8*)&wp2[gB + (size_t)(tap + 1) * 16384];
      }
      const int toff = toffs[tap];
#pragma unroll
      for (int c = 0; c < NCH; c++) {
        int s = base[c] + toff;
        s16x8 b = *(const s16x8*)&lin[s * PITCH + ((q + (s >> 3)) & 3) * 8];
        acc0[c] =
            __builtin_amdgcn_mfma_f32_16x16x32_bf16(ca0, b, acc0[c], 0, 0, 0);
        acc1[c] =
            __builtin_amdgcn_mfma_f32_16x16x32_bf16(ca1, b, acc1[c], 0, 0, 0);
      }
      ca0 = na0; ca1 = na1;
    }
  }
  const int co_a = wv * 16 + q * 4;
  const int co_b = (wv + 4) * 16 + q * 4;
#pragma unroll
  for (int c = 0; c < NCH; c++) {
    int p = c * 16 + nn;
    if (p < 100) {
      int oy = 2 * (p / 10) + py, ox = 2 * (p % 10) + px;
      size_t go = ((size_t)n * 400 + oy * 20 + ox) * 128;
      s16x4 pa, pb;
#pragma unroll
      for (int r = 0; r < 4; r++) {
        pa[r] = (short)f2bf(fmaxf(acc0[c][r] + bias[co_a + r], 0.f));
        pb[r] = (short)f2bf(fmaxf(acc1[c][r] + bias[co_b + r], 0.f));
      }
      *(s16x4*)&out[go + co_a] = pa;
      *(s16x4*)&out[go + co_b] = pb;
    }
  }
}

// ---------------- rec loss: mean((mu + mb - x)^2) ---------------------------
__global__ __launch_bounds__(256) void rec_loss_kernel(
    const float* __restrict__ mu, const float* __restrict__ mb,
    const float* __restrict__ x, float* __restrict__ out) {
  const int t = threadIdx.x;
  const int i = blockIdx.x * 256 + t;
  __shared__ float red[256];
  float d = mu[i] + mb[0] - x[i];
  red[t] = d * d;
  __syncthreads();
  for (int off = 128; off > 0; off >>= 1) {
    if (t < off) red[t] += red[t + off];
    __syncthreads();
  }
  if (t == 0) atomicAdd(out, red[0] * (1.0f / 200704.f));
}

// ---------------- dict / enc losses: sum (val - z)^2 (both NHWC) ------------
__global__ __launch_bounds__(256) void vq_loss_kernel(
    const float4* __restrict__ val4, const float4* __restrict__ z4,
    float* __restrict__ out) {
  const int t = threadIdx.x;
  const int i = blockIdx.x * 256 + t;
  __shared__ float red[256];
  float4 a = val4[i], b = z4[i];
  float dx = a.x - b.x, dy = a.y - b.y, dz = a.z - b.z, dw = a.w - b.w;
  red[t] = dx * dx + dy * dy + dz * dz + dw * dw;
  __syncthreads();
  for (int off = 128; off > 0; off >>= 1) {
    if (t < off) red[t] += red[t + off];
    __syncthreads();
  }
  if (t == 0) {
    atomicAdd(out + 1, red[0] * (5.f / 1179648.f));
    atomicAdd(out + 2, red[0] * (1.25f / 1179648.f));
  }
}

// ---------------------------------------------------------------------------
extern "C" void kernel_launch(void* const* d_in, const int* in_sizes, int n_in,
                              void* d_out, int out_size, void* d_ws,
                              size_t ws_size, hipStream_t stream) {
  const float* x = (const float*)d_in[0];
  const float* w1 = (const float*)d_in[1];
  const float* b1 = (const float*)d_in[2];
  const float* w2 = (const float*)d_in[3];
  const float* b2 = (const float*)d_in[4];
  const float* w3 = (const float*)d_in[5];
  const float* b3 = (const float*)d_in[6];
  const float* t1w = (const float*)d_in[7];
  const float* t1b = (const float*)d_in[8];
  const float* t2w = (const float*)d_in[9];
  const float* t2b = (const float*)d_in[10];
  const float* t3w = (const float*)d_in[11];
  const float* t3b = (const float*)d_in[12];
  const float* t4w = (const float*)d_in[13];
  const float* t4b = (const float*)d_in[14];
  const float* mw = (const float*)d_in[15];
  const float* mb = (const float*)d_in[16];
  const float* dictw = (const float*)d_in[17];
  float* out = (float*)d_out;

  float* p = (float*)d_ws;
  _Float16* h1h = (_Float16*)p; p += 9437184;
  _Float16* h1l = (_Float16*)p; p += 9437184;
  _Float16* p1h = (_Float16*)p; p += 2359296;
  _Float16* p1l = (_Float16*)p; p += 2359296;
  float* z = p; p += 1179648;
  float* val = p; p += 1179648;
  ushort* val_bf = (ushort*)p; p += 589824;
  float* mu = p; p += 200704;
  ushort* wp1 = (ushort*)p; p += 131072;
  ushort* wp3 = (ushort*)p; p += 204800;
  ushort* wp4 = (ushort*)p; p += 204800;
  ushort* wp2 = (ushort*)p; p += 131072;
  _Float16* w2h = (_Float16*)p; p += 204800;
  _Float16* w2l = (_Float16*)p; p += 204800;
  _Float16* w3h = (_Float16*)p; p += 204800;
  _Float16* w3l = (_Float16*)p; p += 204800;
  // aliases (dead buffers reused):
  ushort* f1 = (ushort*)p1h;  // 2,654,208 u16 <= p1h+p1l region
  ushort* f2 = (ushort*)h1l;  // 13,107,200 u16 <= h1l region
  ushort* f3 = (ushort*)h1h;  // 18,874,368 u16 == h1h region

  hipMemsetAsync(d_out, 0, 4 * sizeof(float), stream);
  hipMemsetAsync(mu, 0, 200704 * sizeof(float), stream);

  prep_w<<<16 * 64, 256, 0, stream>>>(t1w, wp1, 16);
  prep_w<<<25 * 64, 256, 0, stream>>>(t3w, wp3, 25);
  prep_w<<<25 * 64, 256, 0, stream>>>(t4w, wp4, 25);
  prep_w_s2<<<1024, 256, 0, stream>>>(t2w, wp2);
  prep_w_split<<<25 * 64, 256, 0, stream>>>(w2, w2h, w2l, 25);
  prep_w_split<<<25 * 64, 256, 0, stream>>>(w3, w3h, w3l, 25);

  conv1_kernel<<<B_, 256, 0, stream>>>(x, w1, b1, h1h, h1l);
  // conv2: 24x24 K5 pad2 relu + pool -> p1 hi/lo NHWC (12x12)
  conv_mfma_pool<24, 5, 2, 6, true, false>
      <<<dim3(B_, 4), 256, 0, stream>>>(h1h, h1l, w2h, w2l, b2, p1h, p1l,
                                        nullptr);
  // conv3: 12x12 K5 pad2 + pool -> z f32 NHWC (6x6)
  conv_mfma_pool<12, 5, 2, 4, false, true>
      <<<dim3(B_, 3), 256, 0, stream>>>(p1h, p1l, w3h, w3l, b3, nullptr,
                                        nullptr, z);
  vq_kernel<<<B_, 256, 0, stream>>>(z, dictw, val, val_bf, out + 4);
  // t1: 6->9, K4 s1, relu  [bf16 NHWC]
  deconv_mfma<6, 6, 9, 9, 4, 9, false>
      <<<dim3(B_, 1), 256, 0, stream>>>(val_bf, wp1, t1b, nullptr, f1);
  // t2: 9->20, K4 s2, relu  [bf16 NHWC, parity decomposition]
  deconv_s2_mfma<<<dim3(B_, 4), 256, 0, stream>>>(f1, wp2, t2b, f2);
  // t3: 20->24, K5 s1, relu  [bf16 NHWC]
  deconv_mfma<20, 20, 24, 24, 5, 8, false>
      <<<dim3(B_, 3), 256, 0, stream>>>(f2, wp3, t3b, nullptr, f3);
  // t4: 24->28, K5 s1, relu + fused 1x1 mu  [bf16 NHWC]
  deconv_mfma<24, 24, 28, 28, 5, 7, true>
      <<<dim3(B_, 4), 256, 0, stream>>>(f3, wp4, t4b, mw, mu);
  rec_loss_kernel<<<784, 256, 0, stream>>>(mu, mb, x, out);
  vq_loss_kernel<<<1152, 256, 0, stream>>>((const float4*)val, (const float4*)z,
                                           out);
}

// Round 10
// 988.898 us; speedup vs baseline: 18.9182x; 1.0223x over previous
//
#include <hip/hip_runtime.h>
#include <hip/hip_bf16.h>

// ---------------------------------------------------------------------------
// VQ-VAE forward. R10: LDS double-buffered ci-block staging (1 barrier/cb,
// global loads in flight across the tap loop) for conv2/conv3/t1/t3/t4;
// fused prep + fused loss kernels. Structure otherwise identical to R9:
//  - conv1 f32 -> fp16 hi/lo NHWC (split once)
//  - conv2/conv3 split-fp16 MFMA (index-exact) + fused bias/relu/2x2 pool
//  - VQ argmax faithful f32; decoder bf16 NHWC MFMA (t2 = 4-parity K2),
//    t4 fused with 1x1 mu conv.
// ---------------------------------------------------------------------------

#define B_ 256

typedef __attribute__((ext_vector_type(8))) short s16x8;
typedef __attribute__((ext_vector_type(4))) short s16x4;
typedef __attribute__((ext_vector_type(8))) _Float16 f16x8;
typedef __attribute__((ext_vector_type(4))) float f32x4;

__device__ inline ushort f2bf(float f) {
  union { __hip_bfloat16 h; ushort u; } cv;
  cv.h = __float2bfloat16(f);
  return cv.u;
}

// ---------------- fused weight prep (all 6 transforms in one launch) --------
// blocks [0,1024): wp1; [1024,2624): wp3; [2624,4224): wp4; [4224,5248): wp2;
// [5248,6848): w2 hi/lo; [6848,8448): w3 hi/lo
__global__ __launch_bounds__(256) void prep_all(
    const float* __restrict__ t1w, const float* __restrict__ t3w,
    const float* __restrict__ t4w, const float* __restrict__ t2w,
    const float* __restrict__ w2, const float* __restrict__ w3,
    ushort* __restrict__ wp1, ushort* __restrict__ wp3,
    ushort* __restrict__ wp4, ushort* __restrict__ wp2,
    _Float16* __restrict__ w2h, _Float16* __restrict__ w2l,
    _Float16* __restrict__ w3h, _Float16* __restrict__ w3l) {
  const int b = blockIdx.x, t = threadIdx.x;
  if (b < 1024) {  // t1: (ci,co,4,4) -> [tap][co][ci] bf16 flipped
    int idx = b * 256 + t;
    int ci = idx & 127, co = (idx >> 7) & 127, tap = idx >> 14;
    wp1[idx] = f2bf(t1w[((size_t)ci * 128 + co) * 16 + (15 - tap)]);
  } else if (b < 2624) {  // t3
    int idx = (b - 1024) * 256 + t;
    int ci = idx & 127, co = (idx >> 7) & 127, tap = idx >> 14;
    wp3[idx] = f2bf(t3w[((size_t)ci * 128 + co) * 25 + (24 - tap)]);
  } else if (b < 4224) {  // t4
    int idx = (b - 2624) * 256 + t;
    int ci = idx & 127, co = (idx >> 7) & 127, tap = idx >> 14;
    wp4[idx] = f2bf(t4w[((size_t)ci * 128 + co) * 25 + (24 - tap)]);
  } else if (b < 5248) {  // t2 parity: [pp][u,v][co][ci]
    int idx = (b - 4224) * 256 + t;
    int ci = idx & 127, co = (idx >> 7) & 127;
    int tap = (idx >> 14) & 3, pp = idx >> 16;
    int u = tap >> 1, v = tap & 1, py = pp >> 1, px = pp & 1;
    wp2[idx] = f2bf(
        t2w[(((size_t)ci * 128 + co) * 4 + (py + 2 * u)) * 4 + (px + 2 * v)]);
  } else if (b < 6848) {  // w2 split
    int idx = (b - 5248) * 256 + t;
    int ci = idx & 127, co = (idx >> 7) & 127, tap = idx >> 14;
    float v = w2[((size_t)co * 128 + ci) * 25 + tap];
    _Float16 h = (_Float16)v;
    w2h[idx] = h;
    w2l[idx] = (_Float16)(v - (float)h);
  } else {  // w3 split
    int idx = (b - 6848) * 256 + t;
    int ci = idx & 127, co = (idx >> 7) & 127, tap = idx >> 14;
    float v = w3[((size_t)co * 128 + ci) * 25 + tap];
    _Float16 h = (_Float16)v;
    w3h[idx] = h;
    w3l[idx] = (_Float16)(v - (float)h);
  }
}

// ------- conv1: (B,1,28,28) -> NHWC hi/lo (B,576,128), 5x5, pad0, ReLU ------
__global__ __launch_bounds__(256) void conv1_kernel(
    const float* __restrict__ x, const float* __restrict__ w,
    const float* __restrict__ b, _Float16* __restrict__ oh,
    _Float16* __restrict__ ol) {
  const int n = blockIdx.x;
  __shared__ float xl[784];
  __shared__ float wl[128 * 25];
  __shared__ float bl[128];
  const int t = threadIdx.x;
  for (int e = t; e < 784; e += 256) xl[e] = x[n * 784 + e];
  for (int e = t; e < 3200; e += 256) wl[e] = w[e];
  if (t < 128) bl[t] = b[t];
  __syncthreads();
  const size_t nb = (size_t)n * 73728;
  for (int idx = t; idx < 73728; idx += 256) {
    int co = idx & 127, p = idx >> 7;
    int y = p / 24, xx = p % 24;
    float acc = bl[co];
    const float* wc = &wl[co * 25];
#pragma unroll
    for (int ky = 0; ky < 5; ky++)
#pragma unroll
      for (int kx = 0; kx < 5; kx++)
        acc += xl[(y + ky) * 28 + xx + kx] * wc[ky * 5 + kx];
    float v = fmaxf(acc, 0.f);
    _Float16 h = (_Float16)v;
    oh[nb + idx] = h;
    ol[nb + idx] = (_Float16)(v - (float)h);
  }
}

// ---- split-fp16 MFMA conv + bias(+relu) + 2x2 maxpool, LDS double-buffer ---
template <int IW, int K, int PAD, int TR, bool RELU, bool OUT_F32>
__global__ __launch_bounds__(256, 2) void conv_mfma_pool(
    const _Float16* __restrict__ inh, const _Float16* __restrict__ inl,
    const _Float16* __restrict__ wph, const _Float16* __restrict__ wpl,
    const float* __restrict__ bias, _Float16* __restrict__ outh,
    _Float16* __restrict__ outl, float* __restrict__ outf) {
  constexpr int IH = IW, OW = IW, OH = IW;
  constexpr int PW = IW + 2 * PAD;
  constexpr int SROWS = TR + K - 1;
  constexpr int S = SROWS * PW;
  constexpr int NPOS = TR * OW;
  constexpr int NCH = NPOS / 16;
  constexpr int K2 = K * K;
  constexpr int PITCH = 40;
  constexpr int LIN_ELT = S * PITCH;                 // per plane, per buffer
  constexpr int BUF_BYTES = 2 * LIN_ELT * 2;         // hi+lo, one buffer
  constexpr int LIN_BYTES = 2 * BUF_BYTES;           // double-buffered
  constexpr int SCR_BYTES = 64 * NPOS * 4;
  constexpr int SMEM_BYTES = LIN_BYTES > SCR_BYTES ? LIN_BYTES : SCR_BYTES;
  constexpr int NSTG = (S * 4 + 255) / 256;
  static_assert(NPOS % 16 == 0, "");
  static_assert(TR % 2 == 0 && OW % 2 == 0, "");
  __shared__ __align__(16) char smem[SMEM_BYTES];
  const int n = blockIdx.x;
  const int r0 = blockIdx.y * TR;
  const int t = threadIdx.x;
  const int wv = t >> 6;
  const int lane = t & 63;
  const int nn = lane & 15;
  const int q = lane >> 4;
  f32x4 acc0[NCH], acc1[NCH];
#pragma unroll
  for (int c = 0; c < NCH; c++) {
    acc0[c] = f32x4{0.f, 0.f, 0.f, 0.f};
    acc1[c] = f32x4{0.f, 0.f, 0.f, 0.f};
  }
  int base[NCH];
#pragma unroll
  for (int c = 0; c < NCH; c++) {
    int p = c * 16 + nn;
    base[c] = (p / OW) * PW + (p % OW);
  }
  const int rowA = wv * 16 + nn;
  const int rowB = (wv + 4) * 16 + nn;
  f16x8 sh[NSTG], sl[NSTG];

  auto load_stage = [&](int ci0) {
#pragma unroll
    for (int i = 0; i < NSTG; i++) {
      int e = t + i * 256;
      f16x8 vh = {0, 0, 0, 0, 0, 0, 0, 0};
      f16x8 vl = {0, 0, 0, 0, 0, 0, 0, 0};
      if (e < S * 4) {
        int sp = e >> 2, j = e & 3;
        int r = sp / PW, c = sp - r * PW;
        int ir = r0 + r - PAD, ic = c - PAD;
        if (ir >= 0 && ir < IH && ic >= 0 && ic < IW) {
          size_t g = ((size_t)n * (IH * IW) + ir * IW + ic) * 128 + ci0 + j * 8;
          vh = *(const f16x8*)&inh[g];
          vl = *(const f16x8*)&inl[g];
        }
      }
      sh[i] = vh;
      sl[i] = vl;
    }
  };
  auto store_stage = [&](int bsel) {
    _Float16* lh = (_Float16*)(smem + bsel * BUF_BYTES);
    _Float16* ll = lh + LIN_ELT;
#pragma unroll
    for (int i = 0; i < NSTG; i++) {
      int e = t + i * 256;
      if (e < S * 4) {
        int sp = e >> 2, j = e & 3;
        int st = sp * PITCH + ((j + (sp >> 3)) & 3) * 8;
        *(f16x8*)&lh[st] = sh[i];
        *(f16x8*)&ll[st] = sl[i];
      }
    }
  };

  load_stage(0);
  store_stage(0);
  __syncthreads();
  for (int cb = 0; cb < 4; cb++) {
    const int ci0 = cb * 32;
    if (cb < 3) load_stage(ci0 + 32);  // global loads in flight across taps
    const _Float16* lh = (const _Float16*)(smem + (cb & 1) * BUF_BYTES);
    const _Float16* ll = lh + LIN_ELT;
    const size_t gA = (size_t)rowA * 128 + ci0 + q * 8;
    const size_t gB = (size_t)rowB * 128 + ci0 + q * 8;
    f16x8 cah0 = *(const f16x8*)&wph[gA];
    f16x8 cal0 = *(const f16x8*)&wpl[gA];
    f16x8 cah1 = *(const f16x8*)&wph[gB];
    f16x8 cal1 = *(const f16x8*)&wpl[gB];
    for (int tap = 0; tap < K2; tap++) {
      f16x8 nah0 = cah0, nal0 = cal0, nah1 = cah1, nal1 = cal1;
      if (tap + 1 < K2) {
        size_t oA = gA + (size_t)(tap + 1) * 16384;
        size_t oB = gB + (size_t)(tap + 1) * 16384;
        nah0 = *(const f16x8*)&wph[oA];
        nal0 = *(const f16x8*)&wpl[oA];
        nah1 = *(const f16x8*)&wph[oB];
        nal1 = *(const f16x8*)&wpl[oB];
      }
      const int ky = tap / K, kx = tap - ky * K;
      const int toff = ky * PW + kx;
#pragma unroll
      for (int c = 0; c < NCH; c++) {
        int s = base[c] + toff;
        int off = s * PITCH + ((q + (s >> 3)) & 3) * 8;
        f16x8 bh = *(const f16x8*)&lh[off];
        f16x8 bl = *(const f16x8*)&ll[off];
        acc0[c] =
            __builtin_amdgcn_mfma_f32_16x16x32_f16(cah0, bh, acc0[c], 0, 0, 0);
        acc0[c] =
            __builtin_amdgcn_mfma_f32_16x16x32_f16(cah0, bl, acc0[c], 0, 0, 0);
        acc0[c] =
            __builtin_amdgcn_mfma_f32_16x16x32_f16(cal0, bh, acc0[c], 0, 0, 0);
        acc1[c] =
            __builtin_amdgcn_mfma_f32_16x16x32_f16(cah1, bh, acc1[c], 0, 0, 0);
        acc1[c] =
            __builtin_amdgcn_mfma_f32_16x16x32_f16(cah1, bl, acc1[c], 0, 0, 0);
        acc1[c] =
            __builtin_amdgcn_mfma_f32_16x16x32_f16(cal1, bh, acc1[c], 0, 0, 0);
      }
      cah0 = nah0; cal0 = nal0; cah1 = nah1; cal1 = nal1;
    }
    if (cb < 3) {
      store_stage((cb + 1) & 1);
      __syncthreads();
    }
  }
  // epilogue: scr overlays buffer 0 (last taps read buffer 1; all waves
  // passed the cb=2 barrier, so buffer 0 reads are done). Barriers below
  // keep the jj-phases aligned.
  __syncthreads();
  float* scr = (float*)smem + wv * 16 * NPOS;
#pragma unroll
  for (int j = 0; j < 2; j++) {
    const int cot = (j ? wv + 4 : wv) * 16;
#pragma unroll
    for (int c = 0; c < NCH; c++) {
      f32x4 a = j ? acc1[c] : acc0[c];
#pragma unroll
      for (int r = 0; r < 4; r++) {
        float v = a[r] + bias[cot + q * 4 + r];
        if (RELU) v = fmaxf(v, 0.f);
        scr[(q * 4 + r) * NPOS + c * 16 + nn] = v;
      }
    }
    __syncthreads();
    for (int e = lane; e < 16 * (TR / 2) * (OW / 2); e += 64) {
      int co_l = e & 15;
      int rem = e >> 4;
      int pr = rem / (OW / 2), pc = rem - pr * (OW / 2);
      const float* s = scr + co_l * NPOS;
      int lp = (2 * pr) * OW + 2 * pc;
      float m =
          fmaxf(fmaxf(s[lp], s[lp + 1]), fmaxf(s[lp + OW], s[lp + OW + 1]));
      int sp_out = (r0 / 2 + pr) * (OW / 2) + pc;
      size_t go =
          ((size_t)n * ((OH / 2) * (OW / 2)) + sp_out) * 128 + cot + co_l;
      if (OUT_F32) {
        outf[go] = m;
      } else {
        _Float16 h = (_Float16)m;
        outh[go] = h;
        outl[go] = (_Float16)(m - (float)h);
      }
    }
    __syncthreads();
  }
}

// ---------------- VQ on NHWC z: argmax(d2) [faithful], gather ---------------
__global__ __launch_bounds__(256) void vq_kernel(
    const float* __restrict__ z, const float* __restrict__ dict,
    float* __restrict__ val, ushort* __restrict__ val_bf,
    float* __restrict__ out_idx) {
  const int n = blockIdx.x;
  __shared__ float zl[36 * 128];
  __shared__ float d2[36 * 129];
  __shared__ float w2n[128];
  __shared__ int bk[36];
  const int t = threadIdx.x;
  const float* zn = z + (size_t)n * 4608;
  for (int e = t; e < 4608; e += 256) zl[e] = zn[e];
  if (t < 128) {
    float s = 0.f;
    const float* wr = dict + t * 128;
    for (int c = 0; c < 128; c++) s += wr[c] * wr[c];
    w2n[t] = s;
  }
  __syncthreads();
  const int k = t & 127, pg = t >> 7;
  float dot[18];
#pragma unroll
  for (int i = 0; i < 18; i++) dot[i] = 0.f;
  const float* wr = dict + k * 128;
  for (int c = 0; c < 128; c++) {
    float wv = wr[c];
#pragma unroll
    for (int i = 0; i < 18; i++) dot[i] += zl[(pg * 18 + i) * 128 + c] * wv;
  }
  float wn = w2n[k];
#pragma unroll
  for (int i = 0; i < 18; i++) d2[(pg * 18 + i) * 129 + k] = wn - 2.f * dot[i];
  __syncthreads();
  if (t < 36) {
    const float* dr = &d2[t * 129];
    float best = dr[0];
    int bi = 0;
    for (int kk = 1; kk < 128; kk++) {
      float v = dr[kk];
      if (v > best) { best = v; bi = kk; }  // strict >: first max (argmax tie)
    }
    bk[t] = bi;
    out_idx[n * 36 + t] = (float)bi;
  }
  __syncthreads();
  float* vn = val + (size_t)n * 4608;
  ushort* vbn = val_bf + (size_t)n * 4608;
  for (int e = t; e < 4608; e += 256) {
    int c = e & 127, p = e >> 7;
    float v = dict[bk[p] * 128 + c];
    vn[e] = v;
    vbn[e] = f2bf(v);
  }
}

// ---- bf16 MFMA deconv (s1), NHWC bf16 io, LDS double-buffer, opt. mu -------
template <int IH, int IW, int OH, int OW, int K, int TR, bool MU_FUSE>
__global__ __launch_bounds__(256, 2) void deconv_mfma(
    const ushort* __restrict__ in, const ushort* __restrict__ wprep,
    const float* __restrict__ bias, const float* __restrict__ mw,
    void* __restrict__ outp) {
  constexpr int PAD = K - 1;
  constexpr int PW = IW + 2 * PAD;
  constexpr int K2 = K * K;
  constexpr int SROWS = TR + K - 1;
  constexpr int S = SROWS * PW;
  constexpr int NPOS = TR * OW;
  constexpr int NCH = (NPOS + 15) / 16;
  constexpr int PITCH = 40;
  constexpr int LIN_ELT = S * PITCH;
  constexpr int NSTG = (S * 4 + 255) / 256;
  __shared__ __align__(16) ushort lin[2][LIN_ELT];
  const int n = blockIdx.x;
  const int r0 = blockIdx.y * TR;
  const int t = threadIdx.x;
  const int wv = t >> 6;
  const int lane = t & 63;
  const int nn = lane & 15;
  const int q = lane >> 4;
  f32x4 acc0[NCH], acc1[NCH];
  int base[NCH];
#pragma unroll
  for (int c = 0; c < NCH; c++) {
    acc0[c] = f32x4{0.f, 0.f, 0.f, 0.f};
    acc1[c] = f32x4{0.f, 0.f, 0.f, 0.f};
    int p = c * 16 + nn;
    int pc = p < NPOS ? p : NPOS - 1;
    base[c] = (pc / OW) * PW + (pc % OW);
  }
  s16x8 stg[NSTG];
  auto load_stage = [&](int ci0) {
#pragma unroll
    for (int i = 0; i < NSTG; i++) {
      int e = t + i * 256;
      s16x8 v = {0, 0, 0, 0, 0, 0, 0, 0};
      if (e < S * 4) {
        int sp = e >> 2, j = e & 3;
        int rr = sp / PW, cc = sp - rr * PW;
        int ir = r0 + rr - PAD, ic = cc - PAD;
        if (ir >= 0 && ir < IH && ic >= 0 && ic < IW)
          v = *(const s16x8*)&in[((size_t)n * (IH * IW) + ir * IW + ic) * 128 +
                                 ci0 + j * 8];
      }
      stg[i] = v;
    }
  };
  auto store_stage = [&](int bsel) {
#pragma unroll
    for (int i = 0; i < NSTG; i++) {
      int e = t + i * 256;
      if (e < S * 4) {
        int sp = e >> 2, j = e & 3;
        *(s16x8*)&lin[bsel][sp * PITCH + ((j + (sp >> 3)) & 3) * 8] = stg[i];
      }
    }
  };

  load_stage(0);
  store_stage(0);
  __syncthreads();
  for (int cb = 0; cb < 4; cb++) {
    const int ci0 = cb * 32;
    if (cb < 3) load_stage(ci0 + 32);
    const ushort* L = lin[cb & 1];
    const size_t gA = (size_t)(wv * 16 + nn) * 128 + ci0 + q * 8;
    const size_t gB = (size_t)((wv + 4) * 16 + nn) * 128 + ci0 + q * 8;
    s16x8 ca0 = *(const s16x8*)&wprep[gA];
    s16x8 ca1 = *(const s16x8*)&wprep[gB];
    for (int tap = 0; tap < K2; tap++) {
      s16x8 na0 = ca0, na1 = ca1;
      if (tap + 1 < K2) {
        na0 = *(const s16x8*)&wprep[gA + (size_t)(tap + 1) * 16384];
        na1 = *(const s16x8*)&wprep[gB + (size_t)(tap + 1) * 16384];
      }
      const int ky = tap / K, kx = tap - ky * K;
      const int toff = ky * PW + kx;
#pragma unroll
      for (int c = 0; c < NCH; c++) {
        int s = base[c] + toff;
        s16x8 b = *(const s16x8*)&L[s * PITCH + ((q + (s >> 3)) & 3) * 8];
        acc0[c] =
            __builtin_amdgcn_mfma_f32_16x16x32_bf16(ca0, b, acc0[c], 0, 0, 0);
        acc1[c] =
            __builtin_amdgcn_mfma_f32_16x16x32_bf16(ca1, b, acc1[c], 0, 0, 0);
      }
      ca0 = na0; ca1 = na1;
    }
    if (cb < 3) {
      store_stage((cb + 1) & 1);
      __syncthreads();
    }
  }
  const int co_a = wv * 16 + q * 4;
  const int co_b = (wv + 4) * 16 + q * 4;
  float ba[4], bb[4];
#pragma unroll
  for (int r = 0; r < 4; r++) {
    ba[r] = bias[co_a + r];
    bb[r] = bias[co_b + r];
  }
  if (!MU_FUSE) {
    ushort* out = (ushort*)outp;
#pragma unroll
    for (int c = 0; c < NCH; c++) {
      int p = c * 16 + nn;
      if (p < NPOS) {
        size_t go = ((size_t)n * (OH * OW) + r0 * OW + p) * 128;
        s16x4 pa, pb;
#pragma unroll
        for (int r = 0; r < 4; r++) {
          pa[r] = (short)f2bf(fmaxf(acc0[c][r] + ba[r], 0.f));
          pb[r] = (short)f2bf(fmaxf(acc1[c][r] + bb[r], 0.f));
        }
        *(s16x4*)&out[go + co_a] = pa;
        *(s16x4*)&out[go + co_b] = pb;
      }
    }
  } else {
    float* out = (float*)outp;
    float wa[4], wb[4];
#pragma unroll
    for (int r = 0; r < 4; r++) {
      wa[r] = mw[co_a + r];
      wb[r] = mw[co_b + r];
    }
#pragma unroll
    for (int c = 0; c < NCH; c++) {
      int p = c * 16 + nn;
      float s = 0.f;
#pragma unroll
      for (int r = 0; r < 4; r++) {
        s += fmaxf(acc0[c][r] + ba[r], 0.f) * wa[r];
        s += fmaxf(acc1[c][r] + bb[r], 0.f) * wb[r];
      }
      s += __shfl_xor(s, 16);
      s += __shfl_xor(s, 32);
      if (q == 0 && p < NPOS)
        atomicAdd(&out[(size_t)n * (OH * OW) + r0 * OW + p], s);
    }
  }
}

// ---------------- t2: k4 s2 deconv via parity decomposition, bf16 NHWC ------
__global__ __launch_bounds__(256, 3) void deconv_s2_mfma(
    const ushort* __restrict__ in, const ushort* __restrict__ wp2,
    const float* __restrict__ bias, ushort* __restrict__ out) {
  constexpr int NCH = 7;
  constexpr int PITCH = 40;
  const int n = blockIdx.x;
  const int pp = blockIdx.y;
  const int py = pp >> 1, px = pp & 1;
  __shared__ __align__(16) ushort lin[121 * PITCH];
  const int t = threadIdx.x;
  const int wv = t >> 6;
  const int lane = t & 63;
  const int nn = lane & 15;
  const int q = lane >> 4;
  f32x4 acc0[NCH], acc1[NCH];
  int base[NCH];
#pragma unroll
  for (int c = 0; c < NCH; c++) {
    acc0[c] = f32x4{0.f, 0.f, 0.f, 0.f};
    acc1[c] = f32x4{0.f, 0.f, 0.f, 0.f};
    int p = c * 16 + nn;
    int pc = p < 100 ? p : 99;
    base[c] = (pc / 10) * 11 + (pc % 10);
  }
  const int toffs[4] = {12, 11, 1, 0};
  for (int cb = 0; cb < 4; cb++) {
    const int ci0 = cb * 32;
    __syncthreads();
    for (int e = t; e < 121 * 4; e += 256) {
      int sp = e >> 2, j = e & 3;
      int r = sp / 11, c2 = sp - r * 11;
      int ir = r - 1, ic = c2 - 1;
      s16x8 v = {0, 0, 0, 0, 0, 0, 0, 0};
      if (ir >= 0 && ir < 9 && ic >= 0 && ic < 9)
        v = *(const s16x8*)&in[((size_t)n * 81 + ir * 9 + ic) * 128 + ci0 +
                               j * 8];
      *(s16x8*)&lin[sp * PITCH + ((j + (sp >> 3)) & 3) * 8] = v;
    }
    __syncthreads();
    const size_t gA =
        ((size_t)(pp * 4) * 128 + wv * 16 + nn) * 128 + ci0 + q * 8;
    const size_t gB =
        ((size_t)(pp * 4) * 128 + (wv + 4) * 16 + nn) * 128 + ci0 + q * 8;
    s16x8 ca0 = *(const s16x8*)&wp2[gA];
    s16x8 ca1 = *(const s16x8*)&wp2[gB];
    for (int tap = 0; tap < 4; tap++) {
      s16x8 na0 = ca0, na1 = ca1;
      if (tap + 1 < 4) {
        na0 = *(const s16x8*)&wp2[gA + (size_t)(tap + 1) * 16384];
        na1 = *(const s16x8*)&wp2[gB + (size_t)(tap + 1) * 16384];
      }
      const int toff = toffs[tap];
#pragma unroll
      for (int c = 0; c < NCH; c++) {
        int s = base[c] + toff;
        s16x8 b = *(const s16x8*)&lin[s * PITCH + ((q + (s >> 3)) & 3) * 8];
        acc0[c] =
            __builtin_amdgcn_mfma_f32_16x16x32_bf16(ca0, b, acc0[c], 0, 0, 0);
        acc1[c] =
            __builtin_amdgcn_mfma_f32_16x16x32_bf16(ca1, b, acc1[c], 0, 0, 0);
      }
      ca0 = na0; ca1 = na1;
    }
  }
  const int co_a = wv * 16 + q * 4;
  const int co_b = (wv + 4) * 16 + q * 4;
#pragma unroll
  for (int c = 0; c < NCH; c++) {
    int p = c * 16 + nn;
    if (p < 100) {
      int oy = 2 * (p / 10) + py, ox = 2 * (p % 10) + px;
      size_t go = ((size_t)n * 400 + oy * 20 + ox) * 128;
      s16x4 pa, pb;
#pragma unroll
      for (int r = 0; r < 4; r++) {
        pa[r] = (short)f2bf(fmaxf(acc0[c][r] + bias[co_a + r], 0.f));
        pb[r] = (short)f2bf(fmaxf(acc1[c][r] + bias[co_b + r], 0.f));
      }
      *(s16x4*)&out[go + co_a] = pa;
      *(s16x4*)&out[go + co_b] = pb;
    }
  }
}

// ---------------- fused losses: rec ([0,784)) + dict/enc ([784,1936)) -------
__global__ __launch_bounds__(256) void loss_kernel(
    const float* __restrict__ mu, const float* __restrict__ mb,
    const float* __restrict__ x, const float4* __restrict__ val4,
    const float4* __restrict__ z4, float* __restrict__ out) {
  const int b = blockIdx.x, t = threadIdx.x;
  __shared__ float red[256];
  if (b < 784) {
    int i = b * 256 + t;
    float d = mu[i] + mb[0] - x[i];
    red[t] = d * d;
  } else {
    int i = (b - 784) * 256 + t;
    float4 a = val4[i], zz = z4[i];
    float dx = a.x - zz.x, dy = a.y - zz.y, dz = a.z - zz.z, dw = a.w - zz.w;
    red[t] = dx * dx + dy * dy + dz * dz + dw * dw;
  }
  __syncthreads();
  for (int off = 128; off > 0; off >>= 1) {
    if (t < off) red[t] += red[t + off];
    __syncthreads();
  }
  if (t == 0) {
    if (b < 784) {
      atomicAdd(out, red[0] * (1.0f / 200704.f));
    } else {
      atomicAdd(out + 1, red[0] * (5.f / 1179648.f));
      atomicAdd(out + 2, red[0] * (1.25f / 1179648.f));
    }
  }
}

// ---------------------------------------------------------------------------
extern "C" void kernel_launch(void* const* d_in, const int* in_sizes, int n_in,
                              void* d_out, int out_size, void* d_ws,
                              size_t ws_size, hipStream_t stream) {
  const float* x = (const float*)d_in[0];
  const float* w1 = (const float*)d_in[1];
  const float* b1 = (const float*)d_in[2];
  const float* w2 = (const float*)d_in[3];
  const float* b2 = (const float*)d_in[4];
  const float* w3 = (const float*)d_in[5];
  const float* b3 = (const float*)d_in[6];
  const float* t1w = (const float*)d_in[7];
  const float* t1b = (const float*)d_in[8];
  const float* t2w = (const float*)d_in[9];
  const float* t2b = (const float*)d_in[10];
  const float* t3w = (const float*)d_in[11];
  const float* t3b = (const float*)d_in[12];
  const float* t4w = (const float*)d_in[13];
  const float* t4b = (const float*)d_in[14];
  const float* mw = (const float*)d_in[15];
  const float* mb = (const float*)d_in[16];
  const float* dictw = (const float*)d_in[17];
  float* out = (float*)d_out;

  float* p = (float*)d_ws;
  _Float16* h1h = (_Float16*)p; p += 9437184;
  _Float16* h1l = (_Float16*)p; p += 9437184;
  _Float16* p1h = (_Float16*)p; p += 2359296;
  _Float16* p1l = (_Float16*)p; p += 2359296;
  float* z = p; p += 1179648;
  float* val = p; p += 1179648;
  ushort* val_bf = (ushort*)p; p += 589824;
  float* mu = p; p += 200704;
  ushort* wp1 = (ushort*)p; p += 131072;
  ushort* wp3 = (ushort*)p; p += 204800;
  ushort* wp4 = (ushort*)p; p += 204800;
  ushort* wp2 = (ushort*)p; p += 131072;
  _Float16* w2h = (_Float16*)p; p += 204800;
  _Float16* w2l = (_Float16*)p; p += 204800;
  _Float16* w3h = (_Float16*)p; p += 204800;
  _Float16* w3l = (_Float16*)p; p += 204800;
  // aliases (dead buffers reused):
  ushort* f1 = (ushort*)p1h;  // (256,81,128) bf16 <= p1h+p1l region
  ushort* f2 = (ushort*)h1l;  // (256,400,128) bf16 <= h1l region
  ushort* f3 = (ushort*)h1h;  // (256,576,128) bf16 == h1h region

  hipMemsetAsync(d_out, 0, 4 * sizeof(float), stream);
  hipMemsetAsync(mu, 0, 200704 * sizeof(float), stream);

  prep_all<<<8448, 256, 0, stream>>>(t1w, t3w, t4w, t2w, w2, w3, wp1, wp3, wp4,
                                     wp2, w2h, w2l, w3h, w3l);

  conv1_kernel<<<B_, 256, 0, stream>>>(x, w1, b1, h1h, h1l);
  // conv2: 24x24 K5 pad2 relu + pool -> p1 hi/lo NHWC (12x12), TR=4, dbuf
  conv_mfma_pool<24, 5, 2, 4, true, false>
      <<<dim3(B_, 6), 256, 0, stream>>>(h1h, h1l, w2h, w2l, b2, p1h, p1l,
                                        nullptr);
  // conv3: 12x12 K5 pad2 + pool -> z f32 NHWC (6x6), TR=4, dbuf
  conv_mfma_pool<12, 5, 2, 4, false, true>
      <<<dim3(B_, 3), 256, 0, stream>>>(p1h, p1l, w3h, w3l, b3, nullptr,
                                        nullptr, z);
  vq_kernel<<<B_, 256, 0, stream>>>(z, dictw, val, val_bf, out + 4);
  // t1: 6->9, K4 s1, relu  [bf16 NHWC, dbuf]
  deconv_mfma<6, 6, 9, 9, 4, 9, false>
      <<<dim3(B_, 1), 256, 0, stream>>>(val_bf, wp1, t1b, nullptr, f1);
  // t2: 9->20, K4 s2, relu  [bf16 NHWC, parity decomposition]
  deconv_s2_mfma<<<dim3(B_, 4), 256, 0, stream>>>(f1, wp2, t2b, f2);
  // t3: 20->24, K5 s1, relu  [bf16 NHWC, dbuf]
  deconv_mfma<20, 20, 24, 24, 5, 8, false>
      <<<dim3(B_, 3), 256, 0, stream>>>(f2, wp3, t3b, nullptr, f3);
  // t4: 24->28, K5 s1, relu + fused 1x1 mu  [bf16 NHWC, dbuf]
  deconv_mfma<24, 24, 28, 28, 5, 7, true>
      <<<dim3(B_, 4), 256, 0, stream>>>(f3, wp4, t4b, mw, mu);
  loss_kernel<<<1936, 256, 0, stream>>>(mu, mb, x, (const float4*)val,
                                        (const float4*)z, out);
}